// Round 7
// baseline (2736.463 us; speedup 1.0000x reference)
//
#include <hip/hip_runtime.h>

#define H 128
#define Nn 100000
#define Ee 250000
#define N5c 20000
#define N6c 30000
#define Gg 512
#define Ll 3
#define AF 9
#define AV 64
#define BF 3
#define BV 8
#define BN_EPS 1e-5f

typedef __bf16 v8bf __attribute__((ext_vector_type(8)));
typedef float v4f __attribute__((ext_vector_type(4)));

// ---------------- init / embedding kernels ----------------

__global__ void k_atom_enc(const int* __restrict__ xa, const float* __restrict__ emb,
                           __bf16* __restrict__ x) {
    int idx = blockIdx.x * blockDim.x + threadIdx.x;
    if (idx >= Nn * H) return;
    int n = idx >> 7, h = idx & 127;
    float s = 0.f;
#pragma unroll
    for (int f = 0; f < AF; ++f) {
        int a = xa[n * AF + f];
        s += emb[(f * AV + a) * H + h];
    }
    x[idx] = (__bf16)s;
}

__global__ void k_cyc_init(const int* __restrict__ xc, const float* __restrict__ emb,
                           __bf16* __restrict__ xo, int M) {
    int idx = blockIdx.x * blockDim.x + threadIdx.x;
    if (idx >= M * H) return;
    int m = idx >> 7, h = idx & 127;
    xo[idx] = (__bf16)emb[xc[m] * H + h];
}

// weight pre-split: (L,K,N) fp32 row-major -> per-layer transposed [n][k] bf16
__global__ void k_split(const float* __restrict__ src, __bf16* __restrict__ dh,
                        int L, int K, int N) {
    int idx = blockIdx.x * blockDim.x + threadIdx.x;
    int tot = L * K * N;
    if (idx >= tot) return;
    int l = idx / (K * N);
    int r = idx - l * (K * N);
    int k = r / N;
    int n = r - k * N;
    size_t d = (size_t)l * K * N + (size_t)n * K + k;
    dh[d] = (__bf16)src[idx];
}

// ---------------- CSR build helpers ----------------

__global__ void k_degi(const int* __restrict__ row, int* __restrict__ deg, int M) {
    int m = blockIdx.x * blockDim.x + threadIdx.x;
    if (m >= M) return;
    atomicAdd(&deg[row[m]], 1);
}

__global__ void k_scan1(const int* __restrict__ deg, int* __restrict__ rp,
                        int* __restrict__ bsum, int n) {
    __shared__ int s[256];
    int tid = threadIdx.x;
    int base = blockIdx.x * 1024 + tid * 4;
    int v0 = (base < n) ? deg[base] : 0;
    int v1 = (base + 1 < n) ? deg[base + 1] : 0;
    int v2 = (base + 2 < n) ? deg[base + 2] : 0;
    int v3 = (base + 3 < n) ? deg[base + 3] : 0;
    int tsum = v0 + v1 + v2 + v3;
    s[tid] = tsum;
    __syncthreads();
    for (int off = 1; off < 256; off <<= 1) {
        int u = (tid >= off) ? s[tid - off] : 0;
        __syncthreads();
        s[tid] += u;
        __syncthreads();
    }
    int exc = s[tid] - tsum;
    if (base < n) rp[base] = exc;
    if (base + 1 < n) rp[base + 1] = exc + v0;
    if (base + 2 < n) rp[base + 2] = exc + v0 + v1;
    if (base + 3 < n) rp[base + 3] = exc + v0 + v1 + v2;
    if (tid == 255) bsum[blockIdx.x] = s[255];
}

__global__ void k_scan2(const int* __restrict__ bsum, int* __restrict__ boff,
                        int* __restrict__ rp, int nb, int n) {
    __shared__ int s[128];
    int tid = threadIdx.x;
    int v = (tid < nb) ? bsum[tid] : 0;
    s[tid] = v;
    __syncthreads();
    for (int off = 1; off < 128; off <<= 1) {
        int u = (tid >= off) ? s[tid - off] : 0;
        __syncthreads();
        s[tid] += u;
        __syncthreads();
    }
    if (tid < nb) boff[tid] = s[tid] - v;
    if (tid == 127) rp[n] = s[127];
}

__global__ void k_scan3(int* __restrict__ rp, const int* __restrict__ boff, int n) {
    int idx = blockIdx.x * blockDim.x + threadIdx.x;
    if (idx < n) rp[idx] += boff[idx >> 10];
}

__global__ void k_fill(const int* __restrict__ ei, const int* __restrict__ eattr,
                       int* __restrict__ woff, unsigned int* __restrict__ elist) {
    int e = blockIdx.x * blockDim.x + threadIdx.x;
    if (e >= Ee) return;
    int src = ei[e], dst = ei[Ee + e];
    int code = eattr[e * BF + 0] * 64 + eattr[e * BF + 1] * 8 + eattr[e * BF + 2];
    int p = atomicAdd(&woff[dst], 1);
    elist[p] = ((unsigned int)code << 17) | (unsigned int)src;
}

__global__ void k_fill_idx(const int* __restrict__ row, int* __restrict__ woff,
                           int* __restrict__ cidx, int M) {
    int m = blockIdx.x * blockDim.x + threadIdx.x;
    if (m >= M) return;
    int p = atomicAdd(&woff[row[m]], 1);
    cidx[p] = m;
}

__global__ void k_inv_int(const int* __restrict__ deg, float* __restrict__ rscale) {
    int r = blockIdx.x * blockDim.x + threadIdx.x;
    if (r >= Nn) return;
    rscale[r] = 1.f / fmaxf((float)deg[r], 1.f);
}

__global__ void k_ebank(const float* __restrict__ bemb, float* __restrict__ ebank) {
    int idx = blockIdx.x * blockDim.x + threadIdx.x;
    if (idx >= 512 * H) return;
    int code = idx >> 7, h = idx & 127;
    int f0 = code >> 6, f1 = (code >> 3) & 7, f2 = code & 7;
    ebank[idx] = bemb[(0 * BV + f0) * H + h] + bemb[(1 * BV + f1) * H + h]
               + bemb[(2 * BV + f2) * H + h];
}

// GINE aggregation, gather form
__global__ __launch_bounds__(256) void k_agg_csr(
    const __bf16* __restrict__ x, const int* __restrict__ rowptr,
    const unsigned int* __restrict__ elist, const float* __restrict__ ebank,
    const float* __restrict__ eps, int layer, __bf16* __restrict__ agg)
{
    int a = blockIdx.x * 2 + (threadIdx.x >> 7);
    int h = threadIdx.x & 127;
    float acc = (1.f + eps[layer]) * (float)x[(size_t)a * H + h];
    int j0 = rowptr[a], j1 = rowptr[a + 1];
    for (int j = j0; j < j1; ++j) {
        unsigned int u = elist[j];
        int src = u & 0x1FFFF;
        int code = u >> 17;
        acc += fmaxf((float)x[(size_t)src * H + h] + ebank[code * H + h], 0.f);
    }
    agg[(size_t)a * H + h] = (__bf16)acc;
}

// ---------------- cross-block stats reduction ----------------

__global__ __launch_bounds__(256) void k_red(const float* __restrict__ part,
                                             float* __restrict__ out,
                                             int width, int nb)
{
    __shared__ float s[256];
    int t = threadIdx.x;
    int col = blockIdx.x * 64 + (t & 63);
    int pl = t >> 6;
    float acc = 0.f;
    for (int p = blockIdx.y * 4 + pl; p < nb; p += 32)
        acc += part[(size_t)p * width + col];
    s[t] = acc;
    __syncthreads();
    if (pl == 0) {
        float v = s[t] + s[t + 64] + s[t + 128] + s[t + 192];
        atomicAdd(&out[col], v);
    }
}

// ---------------- K=128 GEMM v3: B in regs once, GRID-STRIDE over 64-row tiles ----

template <int BNMODE, bool GRP>
__global__ __launch_bounds__(256) void k_gemm128(
    const __bf16* __restrict__ A, const __bf16* __restrict__ Bth,
    const float* __restrict__ bias, const __bf16* __restrict__ res,
    __bf16* __restrict__ out, const int* __restrict__ rowidx,
    const int* __restrict__ grp, const int* __restrict__ gcol,
    const float* __restrict__ gscale,
    const float* __restrict__ bnstats, const float* __restrict__ bng,
    const float* __restrict__ bnb, int M, int ntiles)
{
    __shared__ __bf16 Ct[64 * 136];
    __shared__ float scB[128], shB[128];

    int t = threadIdx.x;
    int lane = t & 63, q = lane >> 4, lr = lane & 15;
    int w = t >> 6;

    if (BNMODE && t < 128) {
        float mean = bnstats[t] * (1.f / (float)Nn);
        float var = bnstats[128 + t] * (1.f / (float)Nn) - mean * mean;
        float s = bng[t] * rsqrtf(var + BN_EPS);
        scB[t] = s;
        shB[t] = bnb[t] - mean * s;
    }
    if (BNMODE) __syncthreads();

    v8bf bf[8][4];
#pragma unroll
    for (int nt = 0; nt < 8; ++nt) {
        const __bf16* bp = Bth + (size_t)(nt * 16 + lr) * 128 + q * 8;
#pragma unroll
        for (int kt = 0; kt < 4; ++kt)
            bf[nt][kt] = *(const v8bf*)(bp + kt * 32);
    }
    float bcol[8];
#pragma unroll
    for (int nt = 0; nt < 8; ++nt) bcol[nt] = bias[nt * 16 + lr];

    for (int tile = blockIdx.x; tile < ntiles; tile += gridDim.x) {
        int m0 = tile * 64;
        int gm = m0 + w * 16 + lr;
        bool rvalid = (gm < M);

        v8bf af[4];
        if (GRP) {
            float a8[4][8];
#pragma unroll
            for (int kt = 0; kt < 4; ++kt)
#pragma unroll
                for (int i = 0; i < 8; ++i) a8[kt][i] = 0.f;
            float sc = 1.f;
            if (rvalid) {
                int j0 = grp[gm], j1 = grp[gm + 1];
                sc = gscale[gm];
                for (int j = j0; j < j1; ++j) {
                    const __bf16* rp2 = A + (size_t)gcol[j] * H;
#pragma unroll
                    for (int kt = 0; kt < 4; ++kt) {
                        v8bf g = *(const v8bf*)(rp2 + kt * 32 + q * 8);
#pragma unroll
                        for (int i = 0; i < 8; ++i) a8[kt][i] += (float)g[i];
                    }
                }
            }
#pragma unroll
            for (int kt = 0; kt < 4; ++kt)
#pragma unroll
                for (int i = 0; i < 8; ++i) af[kt][i] = (__bf16)(a8[kt][i] * sc);
        } else {
            const __bf16* base = A;
            if (rvalid) base = rowidx ? A + (size_t)rowidx[gm] * H : A + (size_t)gm * H;
#pragma unroll
            for (int kt = 0; kt < 4; ++kt) {
                v8bf hv = {};
                if (rvalid) hv = *(const v8bf*)(base + kt * 32 + q * 8);
                af[kt] = hv;
            }
        }
        if (BNMODE == 1) {
            if (rvalid) {
#pragma unroll
                for (int kt = 0; kt < 4; ++kt) {
                    int kb = kt * 32 + q * 8;
#pragma unroll
                    for (int i = 0; i < 8; ++i)
                        af[kt][i] =
                            (__bf16)fmaxf((float)af[kt][i] * scB[kb + i] + shB[kb + i], 0.f);
                }
            }
        }

        v4f acc[8] = {};
#pragma unroll
        for (int kt = 0; kt < 4; ++kt)
#pragma unroll
            for (int nt = 0; nt < 8; ++nt)
                acc[nt] = __builtin_amdgcn_mfma_f32_16x16x32_bf16(
                    af[kt], bf[nt][kt], acc[nt], 0, 0, 0);

#pragma unroll
        for (int nt = 0; nt < 8; ++nt)
#pragma unroll
            for (int reg = 0; reg < 4; ++reg) {
                int row = w * 16 + q * 4 + reg;
                float v = fmaxf(acc[nt][reg] + bcol[nt], 0.f);
                Ct[row * 136 + nt * 16 + lr] = (__bf16)v;
            }
        {
            int row = t >> 2;
            int c0 = (t & 3) * 32;
            int rm = m0 + row;
            if (rm < M) {
#pragma unroll
                for (int seg = 0; seg < 4; ++seg) {
                    int cc = c0 + seg * 8;
                    v8bf cv = *(v8bf*)&Ct[row * 136 + cc];
                    v8bf rv2 = *(const v8bf*)&res[(size_t)rm * H + cc];
#pragma unroll
                    for (int i = 0; i < 8; ++i) {
                        float rf = (float)rv2[i];
                        if (BNMODE == 2)
                            rf = fmaxf(rf * scB[cc + i] + shB[cc + i], 0.f);
                        cv[i] = (__bf16)((float)cv[i] + rf);
                    }
                    *(v8bf*)&out[(size_t)rm * H + cc] = cv;
                }
            }
        }
    }
}

// ---------------- cyclic path block v2: low-VGPR, mt-outer/plane-inner ----------
// Round-5 version was VGPR=256 -> 2 waves/SIMD -> latency-bound (path5==path6
// time despite 1.8x work). v2: acc[8] only (one m-tile at a time), B fragments
// transient per-nt (reloaded from L2-resident 96KB weight), __launch_bounds__
// (256,4) caps VGPR at 128 -> 4 waves/SIMD. One barrier per m-tile before the
// in-place epilogue (rolled A-reads cross 16-row wave boundaries -> the old
// barrier-free write had a latent cross-wave race).

template <int PK>
__global__ __launch_bounds__(256, 4) void k_path(
    const __bf16* __restrict__ X, const __bf16* __restrict__ Bth,
    const float* __restrict__ bias, __bf16* __restrict__ Xout,
    int M, int nchunks)
{
    __shared__ __bf16 Ct[64 * 136];
    int t = threadIdx.x;
    int lane = t & 63, q = lane >> 4, lr = lane & 15;
    int w = t >> 6;

    float bcol[8];
#pragma unroll
    for (int nt = 0; nt < 8; ++nt) bcol[nt] = bias[nt * 16 + lr];

    for (int ch = blockIdx.x; ch < nchunks; ch += gridDim.x) {
        int tb = ch * 120;
#pragma unroll
        for (int mt = 0; mt < 2; ++mt) {
            int rloc = w * 16 + lr;
            int gm = tb + mt * 60 + rloc;
            bool rv = (rloc < 60) && (gm < M);
            v4f acc[8] = {};
#pragma unroll
            for (int p = 0; p < 3; ++p) {
                // shifted A fragment for this plane (roll within the PK-cycle)
                v8bf af[4];
#pragma unroll
                for (int kt = 0; kt < 4; ++kt) af[kt] = v8bf{};
                if (rv) {
                    int pm = gm % PK;
                    int pp = pm + p - 1;
                    if (pp < 0) pp += PK;
                    if (pp >= PK) pp -= PK;
                    const __bf16* ap = X + (size_t)(gm - pm + pp) * H + q * 8;
#pragma unroll
                    for (int kt = 0; kt < 4; ++kt)
                        af[kt] = *(const v8bf*)(ap + kt * 32);
                }
                // transient B fragments: 4 v8bf per nt, reloaded from L2
#pragma unroll
                for (int nt = 0; nt < 8; ++nt) {
                    const __bf16* bp =
                        Bth + (size_t)(nt * 16 + lr) * 384 + p * 128 + q * 8;
                    v8bf bf[4];
#pragma unroll
                    for (int kt = 0; kt < 4; ++kt)
                        bf[kt] = *(const v8bf*)(bp + kt * 32);
#pragma unroll
                    for (int kt = 0; kt < 4; ++kt)
                        acc[nt] = __builtin_amdgcn_mfma_f32_16x16x32_bf16(
                            af[kt], bf[kt], acc[nt], 0, 0, 0);
                }
            }
            // all waves' rolled A-reads for this mt must complete before the
            // in-place write (reads cross 16-row wave boundaries)
            __syncthreads();
#pragma unroll
            for (int nt = 0; nt < 8; ++nt)
#pragma unroll
                for (int reg = 0; reg < 4; ++reg) {
                    int row = w * 16 + q * 4 + reg;
                    float v = fmaxf(acc[nt][reg] + bcol[nt], 0.f);
                    Ct[row * 136 + nt * 16 + lr] = (__bf16)v;
                }
            {
                int row = t >> 2;
                int c0 = (t & 3) * 32;
                int rm = tb + mt * 60 + row;
                if (row < 60 && rm < M) {
#pragma unroll
                    for (int seg = 0; seg < 4; ++seg) {
                        int cc = c0 + seg * 8;
                        v8bf cv = *(v8bf*)&Ct[row * 136 + cc];
                        v8bf rv2 = *(const v8bf*)&X[(size_t)rm * H + cc];
#pragma unroll
                        for (int i = 0; i < 8; ++i)
                            cv[i] = (__bf16)((float)cv[i] + (float)rv2[i]);
                        *(v8bf*)&Xout[(size_t)rm * H + cc] = cv;
                    }
                }
            }
        }
    }
}

// ---------------- MLP pass A: BN1 column stats only ----------------

__global__ __launch_bounds__(256) void k_mlp_statsA(
    const __bf16* __restrict__ agg, const __bf16* __restrict__ g1h,
    const float* __restrict__ gb1, float* __restrict__ spart, int M)
{
    __shared__ float sS[128], sQ[128];
    int t = threadIdx.x;
    int mc = blockIdx.x >> 1, p = blockIdx.x & 1;
    int lane = t & 63, q = lane >> 4, lr = lane & 15;
    int w = t >> 6;
    if (t < 128) { sS[t] = 0.f; sQ[t] = 0.f; }

    v8bf bf[8][4];
#pragma unroll
    for (int nt = 0; nt < 8; ++nt) {
        const __bf16* bp = g1h + (size_t)(p * 128 + nt * 16 + lr) * 128 + q * 8;
#pragma unroll
        for (int kt = 0; kt < 4; ++kt)
            bf[nt][kt] = *(const v8bf*)(bp + kt * 32);
    }
    float bv[8];
#pragma unroll
    for (int nt = 0; nt < 8; ++nt) bv[nt] = gb1[p * 128 + nt * 16 + lr];

    float sAcc[8], qAcc[8];
#pragma unroll
    for (int nt = 0; nt < 8; ++nt) { sAcc[nt] = 0.f; qAcc[nt] = 0.f; }

#pragma unroll
    for (int mt = 0; mt < 4; ++mt) {
        int rb = mc * 256 + mt * 64 + w * 16;
        int gm = rb + lr;
        bool rv = (gm < M);
        v8bf af[4];
#pragma unroll
        for (int kt = 0; kt < 4; ++kt) {
            v8bf hv = {};
            if (rv) hv = *(const v8bf*)(agg + (size_t)gm * H + kt * 32 + q * 8);
            af[kt] = hv;
        }
        v4f acc[8] = {};
#pragma unroll
        for (int kt = 0; kt < 4; ++kt)
#pragma unroll
            for (int nt = 0; nt < 8; ++nt)
                acc[nt] = __builtin_amdgcn_mfma_f32_16x16x32_bf16(
                    af[kt], bf[nt][kt], acc[nt], 0, 0, 0);
#pragma unroll
        for (int nt = 0; nt < 8; ++nt) {
            float s = 0.f, q2 = 0.f;
#pragma unroll
            for (int reg = 0; reg < 4; ++reg) {
                int rm = rb + q * 4 + reg;
                if (rm < M) {
                    float v = acc[nt][reg] + bv[nt];
                    s += v;
                    q2 += v * v;
                }
            }
            sAcc[nt] += s;
            qAcc[nt] += q2;
        }
    }
#pragma unroll
    for (int nt = 0; nt < 8; ++nt) {
        sAcc[nt] += __shfl_xor(sAcc[nt], 16, 64);
        sAcc[nt] += __shfl_xor(sAcc[nt], 32, 64);
        qAcc[nt] += __shfl_xor(qAcc[nt], 16, 64);
        qAcc[nt] += __shfl_xor(qAcc[nt], 32, 64);
    }
    __syncthreads();
    if (q == 0) {
#pragma unroll
        for (int nt = 0; nt < 8; ++nt) {
            atomicAdd(&sS[nt * 16 + lr], sAcc[nt]);
            atomicAdd(&sQ[nt * 16 + lr], qAcc[nt]);
        }
    }
    __syncthreads();
    if (t < 128) {
        spart[(size_t)mc * 512 + p * 128 + t] = sS[t];
        spart[(size_t)mc * 512 + 256 + p * 128 + t] = sQ[t];
    }
}

// ---------------- MLP fused pass B v3: LDS-resident weights, grid-stride ---------

__global__ __launch_bounds__(256, 1) void k_mlp_fused(
    const __bf16* __restrict__ agg, const __bf16* __restrict__ g1h,
    const float* __restrict__ gb1, const float* __restrict__ statsIn,
    const float* __restrict__ gbn_g, const float* __restrict__ gbn_b,
    const __bf16* __restrict__ g2h, const float* __restrict__ gb2,
    __bf16* __restrict__ outx, float* __restrict__ spart2, int M, int ntiles)
{
    __shared__ __bf16 B1s[256][136];   // 69.6 KB
    __shared__ __bf16 B2s[128][264];   // 67.6 KB
    __shared__ __bf16 Tt[64 * 136];    // 17.4 KB (h1 panel / C transpose)
    __shared__ float scS[256], shS[256];
    __shared__ float sS[128], sQ[128];

    int t = threadIdx.x;
    int lane = t & 63, q = lane >> 4, lr = lane & 15;
    int w = t >> 6;

    {
        float mean = statsIn[t] * (1.f / (float)Nn);
        float var = statsIn[256 + t] * (1.f / (float)Nn) - mean * mean;
        float s = gbn_g[t] * rsqrtf(var + BN_EPS);
        scS[t] = s;
        shS[t] = (gb1[t] - mean) * s + gbn_b[t];
    }
    if (t < 128) { sS[t] = 0.f; sQ[t] = 0.f; }

    {
        const __bf16* src = g1h + (size_t)t * 128;
#pragma unroll
        for (int j = 0; j < 16; ++j)
            *(v8bf*)&B1s[t][j * 8] = *(const v8bf*)(src + j * 8);
    }
    {
        int r = t >> 1, h0 = (t & 1) * 128;
        const __bf16* src = g2h + (size_t)r * 256 + h0;
#pragma unroll
        for (int j = 0; j < 16; ++j)
            *(v8bf*)&B2s[r][h0 + j * 8] = *(const v8bf*)(src + j * 8);
    }
    __syncthreads();  // B1s/B2s/scS/shS/sS/sQ ready

    float bc2[8];
#pragma unroll
    for (int nt = 0; nt < 8; ++nt) bc2[nt] = gb2[nt * 16 + lr];

    float sAcc[8], qAcc[8];
#pragma unroll
    for (int nt = 0; nt < 8; ++nt) { sAcc[nt] = 0.f; qAcc[nt] = 0.f; }

    for (int tile = blockIdx.x; tile < ntiles; tile += gridDim.x) {
        int m0 = tile * 64;
        int gm = m0 + w * 16 + lr;
        bool rv = (gm < M);
        v8bf af[4];
#pragma unroll
        for (int kt = 0; kt < 4; ++kt) {
            v8bf hv = {};
            if (rv) hv = *(const v8bf*)(agg + (size_t)gm * H + kt * 32 + q * 8);
            af[kt] = hv;
        }

        v4f acc2[8] = {};
#pragma unroll
        for (int p = 0; p < 2; ++p) {
            v4f acc1[8] = {};
#pragma unroll
            for (int kt = 0; kt < 4; ++kt)
#pragma unroll
                for (int nt = 0; nt < 8; ++nt) {
                    v8bf bh = *(v8bf*)&B1s[p * 128 + nt * 16 + lr][kt * 32 + q * 8];
                    acc1[nt] = __builtin_amdgcn_mfma_f32_16x16x32_bf16(
                        af[kt], bh, acc1[nt], 0, 0, 0);
                }
#pragma unroll
            for (int nt = 0; nt < 8; ++nt)
#pragma unroll
                for (int reg = 0; reg < 4; ++reg) {
                    int row = w * 16 + q * 4 + reg;
                    int col = p * 128 + nt * 16 + lr;
                    float v = fmaxf(acc1[nt][reg] * scS[col] + shS[col], 0.f);
                    Tt[row * 136 + nt * 16 + lr] = (__bf16)v;
                }
            v8bf a2[4];
#pragma unroll
            for (int kt = 0; kt < 4; ++kt)
                a2[kt] = *(v8bf*)&Tt[(w * 16 + lr) * 136 + kt * 32 + q * 8];
#pragma unroll
            for (int kt = 0; kt < 4; ++kt)
#pragma unroll
                for (int nt = 0; nt < 8; ++nt) {
                    v8bf bh = *(v8bf*)&B2s[nt * 16 + lr][p * 128 + kt * 32 + q * 8];
                    acc2[nt] = __builtin_amdgcn_mfma_f32_16x16x32_bf16(
                        a2[kt], bh, acc2[nt], 0, 0, 0);
                }
        }

#pragma unroll
        for (int nt = 0; nt < 8; ++nt) {
#pragma unroll
            for (int reg = 0; reg < 4; ++reg) {
                int rm = m0 + w * 16 + q * 4 + reg;
                if (rm < M) {
                    float v = acc2[nt][reg] + bc2[nt];
                    sAcc[nt] += v;
                    qAcc[nt] += v * v;
                }
            }
        }
#pragma unroll
        for (int nt = 0; nt < 8; ++nt)
#pragma unroll
            for (int reg = 0; reg < 4; ++reg) {
                int row = w * 16 + q * 4 + reg;
                Tt[row * 136 + nt * 16 + lr] = (__bf16)(acc2[nt][reg] + bc2[nt]);
            }
        {
            int row = t >> 2;
            int c0 = (t & 3) * 32;
            int rm = m0 + row;
            if (rm < M) {
#pragma unroll
                for (int seg = 0; seg < 4; ++seg) {
                    int cc = c0 + seg * 8;
                    *(v8bf*)&outx[(size_t)rm * H + cc] = *(v8bf*)&Tt[row * 136 + cc];
                }
            }
        }
    }

#pragma unroll
    for (int nt = 0; nt < 8; ++nt) {
        sAcc[nt] += __shfl_xor(sAcc[nt], 16, 64);
        sAcc[nt] += __shfl_xor(sAcc[nt], 32, 64);
        qAcc[nt] += __shfl_xor(qAcc[nt], 16, 64);
        qAcc[nt] += __shfl_xor(qAcc[nt], 32, 64);
    }
    if (q == 0) {
#pragma unroll
        for (int nt = 0; nt < 8; ++nt) {
            atomicAdd(&sS[nt * 16 + lr], sAcc[nt]);
            atomicAdd(&sQ[nt * 16 + lr], qAcc[nt]);
        }
    }
    __syncthreads();
    {
        float pv = (t < 128) ? sS[t] : sQ[t - 128];
        spart2[(size_t)blockIdx.x * 256 + t] = pv;
    }
}

// ---------------- readout ----------------

__global__ void k_seg_batch(const __bf16* __restrict__ x, const int* __restrict__ batch,
                            float* __restrict__ xgsum, float* __restrict__ gcnt) {
    int h = threadIdx.x;
    int r0 = blockIdx.x * 256;
    if (r0 >= Nn) return;
    int r1 = min(r0 + 256, Nn);
    int cur = batch[r0];
    float acc = 0.f, c = 0.f;
    for (int r = r0; r < r1; ++r) {
        int b = batch[r];
        if (b != cur) {
            atomicAdd(&xgsum[cur * H + h], acc);
            if (h == 0) atomicAdd(&gcnt[cur], c);
            acc = 0.f;
            c = 0.f;
            cur = b;
        }
        acc += (float)x[(size_t)r * H + h];
        c += 1.f;
    }
    atomicAdd(&xgsum[cur * H + h], acc);
    if (h == 0) atomicAdd(&gcnt[cur], c);
}

__global__ void k_head(const float* __restrict__ xgsum, const float* __restrict__ gcnt,
                       const float* __restrict__ alw, const float* __restrict__ alb,
                       const float* __restrict__ lw, const float* __restrict__ lb,
                       float* __restrict__ out) {
    __shared__ float mean[H];
    __shared__ float red[H];
    int g = blockIdx.x, j = threadIdx.x;
    mean[j] = xgsum[g * H + j] / fmaxf(gcnt[g], 1.f);
    __syncthreads();
    float acc = alb[j];
    for (int k = 0; k < H; ++k) acc += mean[k] * alw[k * H + j];
    acc = fmaxf(acc, 0.f) * lw[j];
    red[j] = acc;
    __syncthreads();
    for (int s = 64; s > 0; s >>= 1) {
        if (j < s) red[j] += red[j + s];
        __syncthreads();
    }
    if (j == 0) out[g] = red[0] + lb[0];
}

// ---------------- host ----------------

extern "C" void kernel_launch(void* const* d_in, const int* in_sizes, int n_in,
                              void* d_out, int out_size, void* d_ws, size_t ws_size,
                              hipStream_t stream) {
    const int* x_atom = (const int*)d_in[0];
    const int* ei = (const int*)d_in[1];
    const int* eattr = (const int*)d_in[2];
    const int* batch = (const int*)d_in[3];
    const int* xc5 = (const int*)d_in[4];
    const int* xc6 = (const int*)d_in[5];
    const int* a2c5_row = (const int*)d_in[6];
    const int* a2c6_row = (const int*)d_in[8];
    const float* atom_emb = (const float*)d_in[10];
    const float* bond_emb = (const float*)d_in[11];
    const float* cyc5 = (const float*)d_in[12];
    const float* cyc6 = (const float*)d_in[13];
    const float* eps = (const float*)d_in[14];
    const float* gw1 = (const float*)d_in[15];
    const float* gb1 = (const float*)d_in[16];
    const float* gbn_g = (const float*)d_in[17];
    const float* gbn_b = (const float*)d_in[18];
    const float* gw2 = (const float*)d_in[19];
    const float* gb2 = (const float*)d_in[20];
    const float* bn_g = (const float*)d_in[21];
    const float* bn_b = (const float*)d_in[22];
    const float* a2c5_w = (const float*)d_in[23];
    const float* a2c5_b = (const float*)d_in[24];
    const float* a2c6_w = (const float*)d_in[25];
    const float* a2c6_b = (const float*)d_in[26];
    const float* c2a5_w = (const float*)d_in[27];
    const float* c2a5_b = (const float*)d_in[28];
    const float* c2a6_w = (const float*)d_in[29];
    const float* c2a6_b = (const float*)d_in[30];
    const float* p5_w = (const float*)d_in[31];
    const float* p5_b = (const float*)d_in[32];
    const float* p6_w = (const float*)d_in[33];
    const float* p6_b = (const float*)d_in[34];
    const float* alw = (const float*)d_in[35];
    const float* alb = (const float*)d_in[36];
    const float* lw = (const float*)d_in[37];
    const float* lb = (const float*)d_in[38];
    float* out = (float*)d_out;

    float* w = (float*)d_ws;
    size_t o = 0;
    auto alloc = [&](size_t nf) {
        float* p = w + o;
        o += (nf + 63) & ~(size_t)63;
        return p;
    };
    auto allocb = [&](size_t nbf) { return (__bf16*)alloc((nbf + 1) / 2); };
    const int TPB = 256;
    auto cdiv = [](int a, int b) { return (a + b - 1) / b; };
    int nblkA = cdiv(Nn, 64);
    int mchunks = cdiv(Nn, 256);

    __bf16* x = allocb((size_t)Nn * H);
    __bf16* x5 = allocb((size_t)N5c * 5 * H);
    __bf16* x6 = allocb((size_t)N6c * 6 * H);
    __bf16* agg = allocb((size_t)Nn * H);
    float* stats = alloc(512);
    float* stats2 = alloc(256);
    float* spart = alloc((size_t)nblkA * 512);
    float* xgsum = alloc((size_t)Gg * H);
    float* gcnt = alloc(Gg);
    float* rscale5 = alloc(Nn);
    float* rscale6 = alloc(Nn);
    int* deg = (int*)alloc(Nn);
    int* rowptr = (int*)alloc(Nn + 1);
    int* rp5c = (int*)alloc(Nn + 1);
    int* rp6c = (int*)alloc(Nn + 1);
    int* woff = (int*)alloc(Nn);
    int* bsum = (int*)alloc(256);
    int* boff = (int*)alloc(256);
    unsigned int* elist = (unsigned int*)alloc(Ee);
    int* cidx5 = (int*)alloc(N5c * 5);
    int* cidx6 = (int*)alloc(N6c * 6);
    float* ebank = alloc(512 * H);
    __bf16* g1h = allocb(3 * 128 * 256);
    __bf16* g2h = allocb(3 * 256 * 128);
    __bf16* a5h = allocb(3 * 128 * 128);
    __bf16* a6h = allocb(3 * 128 * 128);
    __bf16* c5h = allocb(3 * 128 * 128);
    __bf16* c6h = allocb(3 * 128 * 128);
    __bf16* p5h = allocb(3 * 384 * 128);
    __bf16* p6h = allocb(3 * 384 * 128);

    int nsb = cdiv(Nn, 1024);

    // weight pre-split (transposed bf16 planes)
    k_split<<<cdiv(3 * 128 * 256, TPB), TPB, 0, stream>>>(gw1, g1h, 3, 128, 256);
    k_split<<<cdiv(3 * 256 * 128, TPB), TPB, 0, stream>>>(gw2, g2h, 3, 256, 128);
    k_split<<<cdiv(3 * 128 * 128, TPB), TPB, 0, stream>>>(a2c5_w, a5h, 3, 128, 128);
    k_split<<<cdiv(3 * 128 * 128, TPB), TPB, 0, stream>>>(a2c6_w, a6h, 3, 128, 128);
    k_split<<<cdiv(3 * 128 * 128, TPB), TPB, 0, stream>>>(c2a5_w, c5h, 3, 128, 128);
    k_split<<<cdiv(3 * 128 * 128, TPB), TPB, 0, stream>>>(c2a6_w, c6h, 3, 128, 128);
    k_split<<<cdiv(3 * 384 * 128, TPB), TPB, 0, stream>>>(p5_w, p5h, 3, 384, 128);
    k_split<<<cdiv(3 * 384 * 128, TPB), TPB, 0, stream>>>(p6_w, p6h, 3, 384, 128);

    // edge CSR
    hipMemsetAsync(deg, 0, Nn * 4, stream);
    k_degi<<<cdiv(Ee, TPB), TPB, 0, stream>>>(ei + Ee, deg, Ee);
    k_scan1<<<nsb, 256, 0, stream>>>(deg, rowptr, bsum, Nn);
    k_scan2<<<1, 128, 0, stream>>>(bsum, boff, rowptr, nsb, Nn);
    k_scan3<<<cdiv(Nn, TPB), TPB, 0, stream>>>(rowptr, boff, Nn);
    hipMemcpyAsync(woff, rowptr, Nn * 4, hipMemcpyDeviceToDevice, stream);
    k_fill<<<cdiv(Ee, TPB), TPB, 0, stream>>>(ei, eattr, woff, elist);

    // cycle->atom CSRs + mean scales
    hipMemsetAsync(deg, 0, Nn * 4, stream);
    k_degi<<<cdiv(N5c * 5, TPB), TPB, 0, stream>>>(a2c5_row, deg, N5c * 5);
    k_scan1<<<nsb, 256, 0, stream>>>(deg, rp5c, bsum, Nn);
    k_scan2<<<1, 128, 0, stream>>>(bsum, boff, rp5c, nsb, Nn);
    k_scan3<<<cdiv(Nn, TPB), TPB, 0, stream>>>(rp5c, boff, Nn);
    k_inv_int<<<cdiv(Nn, TPB), TPB, 0, stream>>>(deg, rscale5);
    hipMemcpyAsync(woff, rp5c, Nn * 4, hipMemcpyDeviceToDevice, stream);
    k_fill_idx<<<cdiv(N5c * 5, TPB), TPB, 0, stream>>>(a2c5_row, woff, cidx5, N5c * 5);

    hipMemsetAsync(deg, 0, Nn * 4, stream);
    k_degi<<<cdiv(N6c * 6, TPB), TPB, 0, stream>>>(a2c6_row, deg, N6c * 6);
    k_scan1<<<nsb, 256, 0, stream>>>(deg, rp6c, bsum, Nn);
    k_scan2<<<1, 128, 0, stream>>>(bsum, boff, rp6c, nsb, Nn);
    k_scan3<<<cdiv(Nn, TPB), TPB, 0, stream>>>(rp6c, boff, Nn);
    k_inv_int<<<cdiv(Nn, TPB), TPB, 0, stream>>>(deg, rscale6);
    hipMemcpyAsync(woff, rp6c, Nn * 4, hipMemcpyDeviceToDevice, stream);
    k_fill_idx<<<cdiv(N6c * 6, TPB), TPB, 0, stream>>>(a2c6_row, woff, cidx6, N6c * 6);

    k_atom_enc<<<cdiv(Nn * H, TPB), TPB, 0, stream>>>(x_atom, atom_emb, x);
    k_cyc_init<<<cdiv(N5c * 5 * H, TPB), TPB, 0, stream>>>(xc5, cyc5, x5, N5c * 5);
    k_cyc_init<<<cdiv(N6c * 6 * H, TPB), TPB, 0, stream>>>(xc6, cyc6, x6, N6c * 6);

    const int GS = 512;   // grid-stride block count for gemm128/path
    const int GF = 256;   // fused v3: 1 block/CU (157.7 KB LDS)
    for (int i = 0; i < Ll; ++i) {
        // GINE aggregation (gather) -> agg
        k_ebank<<<cdiv(512 * H, TPB), TPB, 0, stream>>>(
            bond_emb + (size_t)i * BF * BV * H, ebank);
        k_agg_csr<<<Nn / 2, 256, 0, stream>>>(x, rowptr, elist, ebank, eps, i, agg);

        // MLP pass A: BN1 stats (barrier-free; partials -> reduce)
        hipMemsetAsync(stats, 0, 512 * 4, stream);
        k_mlp_statsA<<<mchunks * 2, 256, 0, stream>>>(
            agg, g1h + (size_t)i * 128 * 256, gb1 + (size_t)i * 256, spart, Nn);
        k_red<<<dim3(8, 8), 256, 0, stream>>>(spart, stats, 512, mchunks);

        // MLP fused pass B v3 (LDS-resident weights) -> x_raw + BN2 partials
        hipMemsetAsync(stats2, 0, 256 * 4, stream);
        k_mlp_fused<<<GF, 256, 0, stream>>>(
            agg, g1h + (size_t)i * 128 * 256, gb1 + (size_t)i * 256, stats,
            gbn_g + (size_t)i * 256, gbn_b + (size_t)i * 256,
            g2h + (size_t)i * 256 * 128, gb2 + (size_t)i * H, x, spart,
            Nn, nblkA);
        k_red<<<dim3(4, 8), 256, 0, stream>>>(spart, stats2, 256, GF);

        // atoms -> cycles (row-gather, BN2+relu folded on A, in-place residual)
        k_gemm128<1, false><<<GS, 256, 0, stream>>>(
            x, a5h + (size_t)i * 128 * 128, a2c5_b + (size_t)i * H,
            x5, x5, a2c5_row, nullptr, nullptr, nullptr,
            stats2, bn_g + (size_t)i * H, bn_b + (size_t)i * H,
            N5c * 5, cdiv(N5c * 5, 64));
        k_gemm128<1, false><<<GS, 256, 0, stream>>>(
            x, a6h + (size_t)i * 128 * 128, a2c6_b + (size_t)i * H,
            x6, x6, a2c6_row, nullptr, nullptr, nullptr,
            stats2, bn_g + (size_t)i * H, bn_b + (size_t)i * H,
            N6c * 6, cdiv(N6c * 6, 64));

        // cyclic path blocks v2: low-VGPR, grid-stride
        k_path<5><<<GS, 256, 0, stream>>>(
            x5, p5h + (size_t)i * 384 * 128, p5_b + (size_t)i * H, x5,
            N5c * 5, cdiv(N5c * 5, 120));
        k_path<6><<<GS, 256, 0, stream>>>(
            x6, p6h + (size_t)i * 384 * 128, p6_b + (size_t)i * H, x6,
            N6c * 6, cdiv(N6c * 6, 120));

        // cycles -> atoms (CSR mean-gather; c2a5 folds BN2+relu on res side)
        k_gemm128<2, true><<<GS, 256, 0, stream>>>(
            x5, c5h + (size_t)i * 128 * 128, c2a5_b + (size_t)i * H,
            x, x, nullptr, rp5c, cidx5, rscale5,
            stats2, bn_g + (size_t)i * H, bn_b + (size_t)i * H,
            Nn, cdiv(Nn, 64));
        k_gemm128<0, true><<<GS, 256, 0, stream>>>(
            x6, c6h + (size_t)i * 128 * 128, c2a6_b + (size_t)i * H,
            x, x, nullptr, rp6c, cidx6, rscale6,
            nullptr, nullptr, nullptr, Nn, cdiv(Nn, 64));
    }

    // readout
    hipMemsetAsync(xgsum, 0, (size_t)Gg * H * 4, stream);
    hipMemsetAsync(gcnt, 0, (size_t)Gg * 4, stream);
    k_seg_batch<<<cdiv(Nn, 256), H, 0, stream>>>(x, batch, xgsum, gcnt);
    k_head<<<Gg, H, 0, stream>>>(xgsum, gcnt, alw, alb, lw, lb, out);
}

// Round 8
// 1458.265 us; speedup vs baseline: 1.8765x; 1.8765x over previous
//
#include <hip/hip_runtime.h>

#define H 128
#define Nn 100000
#define Ee 250000
#define N5c 20000
#define N6c 30000
#define Gg 512
#define Ll 3
#define AF 9
#define AV 64
#define BF 3
#define BV 8
#define BN_EPS 1e-5f

typedef __bf16 v8bf __attribute__((ext_vector_type(8)));
typedef float v4f __attribute__((ext_vector_type(4)));

// ---------------- init / embedding kernels ----------------

__global__ void k_atom_enc(const int* __restrict__ xa, const float* __restrict__ emb,
                           __bf16* __restrict__ x) {
    int idx = blockIdx.x * blockDim.x + threadIdx.x;
    if (idx >= Nn * H) return;
    int n = idx >> 7, h = idx & 127;
    float s = 0.f;
#pragma unroll
    for (int f = 0; f < AF; ++f) {
        int a = xa[n * AF + f];
        s += emb[(f * AV + a) * H + h];
    }
    x[idx] = (__bf16)s;
}

__global__ void k_cyc_init(const int* __restrict__ xc, const float* __restrict__ emb,
                           __bf16* __restrict__ xo, int M) {
    int idx = blockIdx.x * blockDim.x + threadIdx.x;
    if (idx >= M * H) return;
    int m = idx >> 7, h = idx & 127;
    xo[idx] = (__bf16)emb[xc[m] * H + h];
}

// weight pre-split: (L,K,N) fp32 row-major -> per-layer transposed [n][k] bf16
__global__ void k_split(const float* __restrict__ src, __bf16* __restrict__ dh,
                        int L, int K, int N) {
    int idx = blockIdx.x * blockDim.x + threadIdx.x;
    int tot = L * K * N;
    if (idx >= tot) return;
    int l = idx / (K * N);
    int r = idx - l * (K * N);
    int k = r / N;
    int n = r - k * N;
    size_t d = (size_t)l * K * N + (size_t)n * K + k;
    dh[d] = (__bf16)src[idx];
}

// ---------------- CSR build helpers ----------------

__global__ void k_degi(const int* __restrict__ row, int* __restrict__ deg, int M) {
    int m = blockIdx.x * blockDim.x + threadIdx.x;
    if (m >= M) return;
    atomicAdd(&deg[row[m]], 1);
}

__global__ void k_scan1(const int* __restrict__ deg, int* __restrict__ rp,
                        int* __restrict__ bsum, int n) {
    __shared__ int s[256];
    int tid = threadIdx.x;
    int base = blockIdx.x * 1024 + tid * 4;
    int v0 = (base < n) ? deg[base] : 0;
    int v1 = (base + 1 < n) ? deg[base + 1] : 0;
    int v2 = (base + 2 < n) ? deg[base + 2] : 0;
    int v3 = (base + 3 < n) ? deg[base + 3] : 0;
    int tsum = v0 + v1 + v2 + v3;
    s[tid] = tsum;
    __syncthreads();
    for (int off = 1; off < 256; off <<= 1) {
        int u = (tid >= off) ? s[tid - off] : 0;
        __syncthreads();
        s[tid] += u;
        __syncthreads();
    }
    int exc = s[tid] - tsum;
    if (base < n) rp[base] = exc;
    if (base + 1 < n) rp[base + 1] = exc + v0;
    if (base + 2 < n) rp[base + 2] = exc + v0 + v1;
    if (base + 3 < n) rp[base + 3] = exc + v0 + v1 + v2;
    if (tid == 255) bsum[blockIdx.x] = s[255];
}

__global__ void k_scan2(const int* __restrict__ bsum, int* __restrict__ boff,
                        int* __restrict__ rp, int nb, int n) {
    __shared__ int s[128];
    int tid = threadIdx.x;
    int v = (tid < nb) ? bsum[tid] : 0;
    s[tid] = v;
    __syncthreads();
    for (int off = 1; off < 128; off <<= 1) {
        int u = (tid >= off) ? s[tid - off] : 0;
        __syncthreads();
        s[tid] += u;
        __syncthreads();
    }
    if (tid < nb) boff[tid] = s[tid] - v;
    if (tid == 127) rp[n] = s[127];
}

__global__ void k_scan3(int* __restrict__ rp, const int* __restrict__ boff, int n) {
    int idx = blockIdx.x * blockDim.x + threadIdx.x;
    if (idx < n) rp[idx] += boff[idx >> 10];
}

__global__ void k_fill(const int* __restrict__ ei, const int* __restrict__ eattr,
                       int* __restrict__ woff, unsigned int* __restrict__ elist) {
    int e = blockIdx.x * blockDim.x + threadIdx.x;
    if (e >= Ee) return;
    int src = ei[e], dst = ei[Ee + e];
    int code = eattr[e * BF + 0] * 64 + eattr[e * BF + 1] * 8 + eattr[e * BF + 2];
    int p = atomicAdd(&woff[dst], 1);
    elist[p] = ((unsigned int)code << 17) | (unsigned int)src;
}

__global__ void k_fill_idx(const int* __restrict__ row, int* __restrict__ woff,
                           int* __restrict__ cidx, int M) {
    int m = blockIdx.x * blockDim.x + threadIdx.x;
    if (m >= M) return;
    int p = atomicAdd(&woff[row[m]], 1);
    cidx[p] = m;
}

__global__ void k_inv_int(const int* __restrict__ deg, float* __restrict__ rscale) {
    int r = blockIdx.x * blockDim.x + threadIdx.x;
    if (r >= Nn) return;
    rscale[r] = 1.f / fmaxf((float)deg[r], 1.f);
}

__global__ void k_ebank(const float* __restrict__ bemb, float* __restrict__ ebank) {
    int idx = blockIdx.x * blockDim.x + threadIdx.x;
    if (idx >= 512 * H) return;
    int code = idx >> 7, h = idx & 127;
    int f0 = code >> 6, f1 = (code >> 3) & 7, f2 = code & 7;
    ebank[idx] = bemb[(0 * BV + f0) * H + h] + bemb[(1 * BV + f1) * H + h]
               + bemb[(2 * BV + f2) * H + h];
}

// GINE aggregation, gather form
__global__ __launch_bounds__(256) void k_agg_csr(
    const __bf16* __restrict__ x, const int* __restrict__ rowptr,
    const unsigned int* __restrict__ elist, const float* __restrict__ ebank,
    const float* __restrict__ eps, int layer, __bf16* __restrict__ agg)
{
    int a = blockIdx.x * 2 + (threadIdx.x >> 7);
    int h = threadIdx.x & 127;
    float acc = (1.f + eps[layer]) * (float)x[(size_t)a * H + h];
    int j0 = rowptr[a], j1 = rowptr[a + 1];
    for (int j = j0; j < j1; ++j) {
        unsigned int u = elist[j];
        int src = u & 0x1FFFF;
        int code = u >> 17;
        acc += fmaxf((float)x[(size_t)src * H + h] + ebank[code * H + h], 0.f);
    }
    agg[(size_t)a * H + h] = (__bf16)acc;
}

// ---------------- cross-block stats reduction ----------------

__global__ __launch_bounds__(256) void k_red(const float* __restrict__ part,
                                             float* __restrict__ out,
                                             int width, int nb)
{
    __shared__ float s[256];
    int t = threadIdx.x;
    int col = blockIdx.x * 64 + (t & 63);
    int pl = t >> 6;
    float acc = 0.f;
    for (int p = blockIdx.y * 4 + pl; p < nb; p += 32)
        acc += part[(size_t)p * width + col];
    s[t] = acc;
    __syncthreads();
    if (pl == 0) {
        float v = s[t] + s[t + 64] + s[t + 128] + s[t + 192];
        atomicAdd(&out[col], v);
    }
}

// ---------------- K=128 GEMM v3: B in regs once, GRID-STRIDE over 64-row tiles ----

template <int BNMODE, bool GRP>
__global__ __launch_bounds__(256) void k_gemm128(
    const __bf16* __restrict__ A, const __bf16* __restrict__ Bth,
    const float* __restrict__ bias, const __bf16* __restrict__ res,
    __bf16* __restrict__ out, const int* __restrict__ rowidx,
    const int* __restrict__ grp, const int* __restrict__ gcol,
    const float* __restrict__ gscale,
    const float* __restrict__ bnstats, const float* __restrict__ bng,
    const float* __restrict__ bnb, int M, int ntiles)
{
    __shared__ __bf16 Ct[64 * 136];
    __shared__ float scB[128], shB[128];

    int t = threadIdx.x;
    int lane = t & 63, q = lane >> 4, lr = lane & 15;
    int w = t >> 6;

    if (BNMODE && t < 128) {
        float mean = bnstats[t] * (1.f / (float)Nn);
        float var = bnstats[128 + t] * (1.f / (float)Nn) - mean * mean;
        float s = bng[t] * rsqrtf(var + BN_EPS);
        scB[t] = s;
        shB[t] = bnb[t] - mean * s;
    }
    if (BNMODE) __syncthreads();

    v8bf bf[8][4];
#pragma unroll
    for (int nt = 0; nt < 8; ++nt) {
        const __bf16* bp = Bth + (size_t)(nt * 16 + lr) * 128 + q * 8;
#pragma unroll
        for (int kt = 0; kt < 4; ++kt)
            bf[nt][kt] = *(const v8bf*)(bp + kt * 32);
    }
    float bcol[8];
#pragma unroll
    for (int nt = 0; nt < 8; ++nt) bcol[nt] = bias[nt * 16 + lr];

    for (int tile = blockIdx.x; tile < ntiles; tile += gridDim.x) {
        int m0 = tile * 64;
        int gm = m0 + w * 16 + lr;
        bool rvalid = (gm < M);

        v8bf af[4];
        if (GRP) {
            float a8[4][8];
#pragma unroll
            for (int kt = 0; kt < 4; ++kt)
#pragma unroll
                for (int i = 0; i < 8; ++i) a8[kt][i] = 0.f;
            float sc = 1.f;
            if (rvalid) {
                int j0 = grp[gm], j1 = grp[gm + 1];
                sc = gscale[gm];
                for (int j = j0; j < j1; ++j) {
                    const __bf16* rp2 = A + (size_t)gcol[j] * H;
#pragma unroll
                    for (int kt = 0; kt < 4; ++kt) {
                        v8bf g = *(const v8bf*)(rp2 + kt * 32 + q * 8);
#pragma unroll
                        for (int i = 0; i < 8; ++i) a8[kt][i] += (float)g[i];
                    }
                }
            }
#pragma unroll
            for (int kt = 0; kt < 4; ++kt)
#pragma unroll
                for (int i = 0; i < 8; ++i) af[kt][i] = (__bf16)(a8[kt][i] * sc);
        } else {
            const __bf16* base = A;
            if (rvalid) base = rowidx ? A + (size_t)rowidx[gm] * H : A + (size_t)gm * H;
#pragma unroll
            for (int kt = 0; kt < 4; ++kt) {
                v8bf hv = {};
                if (rvalid) hv = *(const v8bf*)(base + kt * 32 + q * 8);
                af[kt] = hv;
            }
        }
        if (BNMODE == 1) {
            if (rvalid) {
#pragma unroll
                for (int kt = 0; kt < 4; ++kt) {
                    int kb = kt * 32 + q * 8;
#pragma unroll
                    for (int i = 0; i < 8; ++i)
                        af[kt][i] =
                            (__bf16)fmaxf((float)af[kt][i] * scB[kb + i] + shB[kb + i], 0.f);
                }
            }
        }

        v4f acc[8] = {};
#pragma unroll
        for (int kt = 0; kt < 4; ++kt)
#pragma unroll
            for (int nt = 0; nt < 8; ++nt)
                acc[nt] = __builtin_amdgcn_mfma_f32_16x16x32_bf16(
                    af[kt], bf[nt][kt], acc[nt], 0, 0, 0);

#pragma unroll
        for (int nt = 0; nt < 8; ++nt)
#pragma unroll
            for (int reg = 0; reg < 4; ++reg) {
                int row = w * 16 + q * 4 + reg;
                float v = fmaxf(acc[nt][reg] + bcol[nt], 0.f);
                Ct[row * 136 + nt * 16 + lr] = (__bf16)v;
            }
        {
            int row = t >> 2;
            int c0 = (t & 3) * 32;
            int rm = m0 + row;
            if (rm < M) {
#pragma unroll
                for (int seg = 0; seg < 4; ++seg) {
                    int cc = c0 + seg * 8;
                    v8bf cv = *(v8bf*)&Ct[row * 136 + cc];
                    v8bf rv2 = *(const v8bf*)&res[(size_t)rm * H + cc];
#pragma unroll
                    for (int i = 0; i < 8; ++i) {
                        float rf = (float)rv2[i];
                        if (BNMODE == 2)
                            rf = fmaxf(rf * scB[cc + i] + shB[cc + i], 0.f);
                        cv[i] = (__bf16)((float)cv[i] + rf);
                    }
                    *(v8bf*)&out[(size_t)rm * H + cc] = cv;
                }
            }
        }
    }
}

// ---------------- cyclic path block v3: LDS-resident weights (fused-v3 recipe) ----
// B (128 n x 384 k, 96KB) staged into LDS once per block. 512-thread blocks:
// waves 0-3 own mt0 (rows tb..tb+59), waves 4-7 own mt1 (tb+60..tb+119).
// Per chunk: 3 planes x {rolled A-frag -> 32 MFMA, B from LDS}; ONE barrier
// (rolled A reads cross wave boundaries -> must drain before in-place write);
// wave-local Ct transpose epilogue. acc[8]+af only => ~100 VGPR, no cap.

template <int PK>
__global__ __launch_bounds__(512, 1) void k_path(
    const __bf16* __restrict__ X, const __bf16* __restrict__ Bth,
    const float* __restrict__ bias, __bf16* __restrict__ Xout,
    int M, int nchunks)
{
    __shared__ __bf16 Bs[128][392];   // 100.4 KB (pad 8 cols: 4-bank row shift)
    __shared__ __bf16 Ct[128 * 136];  // 34.8 KB
    int t = threadIdx.x;
    int lane = t & 63, q = lane >> 4, lr = lane & 15;
    int w = t >> 6;        // 0..7
    int mt = w >> 2;       // 0 or 1
    int wm = w & 3;        // wave within mt half

    // stage B: thread t stages row t>>2, col-quarter (t&3)*96 (12 v8bf)
    {
        int r = t >> 2, c0 = (t & 3) * 96;
        const __bf16* src = Bth + (size_t)r * 384 + c0;
#pragma unroll
        for (int j = 0; j < 12; ++j)
            *(v8bf*)&Bs[r][c0 + j * 8] = *(const v8bf*)(src + j * 8);
    }
    float bcol[8];
#pragma unroll
    for (int nt = 0; nt < 8; ++nt) bcol[nt] = bias[nt * 16 + lr];
    __syncthreads();  // Bs ready

    for (int ch = blockIdx.x; ch < nchunks; ch += gridDim.x) {
        int tb = ch * 120;
        int rloc = wm * 16 + lr;
        int gm = tb + mt * 60 + rloc;
        bool rv = (rloc < 60) && (gm < M);
        v4f acc[8] = {};
#pragma unroll
        for (int p = 0; p < 3; ++p) {
            v8bf af[4];
#pragma unroll
            for (int kt = 0; kt < 4; ++kt) af[kt] = v8bf{};
            if (rv) {
                int pm = gm % PK;
                int pp = pm + p - 1;
                if (pp < 0) pp += PK;
                if (pp >= PK) pp -= PK;
                const __bf16* ap = X + (size_t)(gm - pm + pp) * H + q * 8;
#pragma unroll
                for (int kt = 0; kt < 4; ++kt)
                    af[kt] = *(const v8bf*)(ap + kt * 32);
            }
#pragma unroll
            for (int nt = 0; nt < 8; ++nt)
#pragma unroll
                for (int kt = 0; kt < 4; ++kt) {
                    v8bf bh = *(v8bf*)&Bs[nt * 16 + lr][p * 128 + kt * 32 + q * 8];
                    acc[nt] = __builtin_amdgcn_mfma_f32_16x16x32_bf16(
                        af[kt], bh, acc[nt], 0, 0, 0);
                }
        }
        // all rolled A reads (which cross wave row-boundaries) must complete
        // before the in-place residual+write below
        __syncthreads();
#pragma unroll
        for (int nt = 0; nt < 8; ++nt)
#pragma unroll
            for (int reg = 0; reg < 4; ++reg) {
                int row = w * 16 + q * 4 + reg;   // 0..127, wave-local
                float v = fmaxf(acc[nt][reg] + bcol[nt], 0.f);
                Ct[row * 136 + nt * 16 + lr] = (__bf16)v;
            }
        {
            int row = t >> 2;                    // 0..127, same wave's rows
            int c0 = (t & 3) * 32;
            int rmloc = row & 63;
            int rm = tb + (row >> 6) * 60 + rmloc;
            if (rmloc < 60 && rm < M) {
#pragma unroll
                for (int seg = 0; seg < 4; ++seg) {
                    int cc = c0 + seg * 8;
                    v8bf cv = *(v8bf*)&Ct[row * 136 + cc];
                    v8bf rv2 = *(const v8bf*)&X[(size_t)rm * H + cc];
#pragma unroll
                    for (int i = 0; i < 8; ++i)
                        cv[i] = (__bf16)((float)cv[i] + (float)rv2[i]);
                    *(v8bf*)&Xout[(size_t)rm * H + cc] = cv;
                }
            }
        }
    }
}

// ---------------- MLP pass A: BN1 column stats only ----------------

__global__ __launch_bounds__(256) void k_mlp_statsA(
    const __bf16* __restrict__ agg, const __bf16* __restrict__ g1h,
    const float* __restrict__ gb1, float* __restrict__ spart, int M)
{
    __shared__ float sS[128], sQ[128];
    int t = threadIdx.x;
    int mc = blockIdx.x >> 1, p = blockIdx.x & 1;
    int lane = t & 63, q = lane >> 4, lr = lane & 15;
    int w = t >> 6;
    if (t < 128) { sS[t] = 0.f; sQ[t] = 0.f; }

    v8bf bf[8][4];
#pragma unroll
    for (int nt = 0; nt < 8; ++nt) {
        const __bf16* bp = g1h + (size_t)(p * 128 + nt * 16 + lr) * 128 + q * 8;
#pragma unroll
        for (int kt = 0; kt < 4; ++kt)
            bf[nt][kt] = *(const v8bf*)(bp + kt * 32);
    }
    float bv[8];
#pragma unroll
    for (int nt = 0; nt < 8; ++nt) bv[nt] = gb1[p * 128 + nt * 16 + lr];

    float sAcc[8], qAcc[8];
#pragma unroll
    for (int nt = 0; nt < 8; ++nt) { sAcc[nt] = 0.f; qAcc[nt] = 0.f; }

#pragma unroll
    for (int mt = 0; mt < 4; ++mt) {
        int rb = mc * 256 + mt * 64 + w * 16;
        int gm = rb + lr;
        bool rv = (gm < M);
        v8bf af[4];
#pragma unroll
        for (int kt = 0; kt < 4; ++kt) {
            v8bf hv = {};
            if (rv) hv = *(const v8bf*)(agg + (size_t)gm * H + kt * 32 + q * 8);
            af[kt] = hv;
        }
        v4f acc[8] = {};
#pragma unroll
        for (int kt = 0; kt < 4; ++kt)
#pragma unroll
            for (int nt = 0; nt < 8; ++nt)
                acc[nt] = __builtin_amdgcn_mfma_f32_16x16x32_bf16(
                    af[kt], bf[nt][kt], acc[nt], 0, 0, 0);
#pragma unroll
        for (int nt = 0; nt < 8; ++nt) {
            float s = 0.f, q2 = 0.f;
#pragma unroll
            for (int reg = 0; reg < 4; ++reg) {
                int rm = rb + q * 4 + reg;
                if (rm < M) {
                    float v = acc[nt][reg] + bv[nt];
                    s += v;
                    q2 += v * v;
                }
            }
            sAcc[nt] += s;
            qAcc[nt] += q2;
        }
    }
#pragma unroll
    for (int nt = 0; nt < 8; ++nt) {
        sAcc[nt] += __shfl_xor(sAcc[nt], 16, 64);
        sAcc[nt] += __shfl_xor(sAcc[nt], 32, 64);
        qAcc[nt] += __shfl_xor(qAcc[nt], 16, 64);
        qAcc[nt] += __shfl_xor(qAcc[nt], 32, 64);
    }
    __syncthreads();
    if (q == 0) {
#pragma unroll
        for (int nt = 0; nt < 8; ++nt) {
            atomicAdd(&sS[nt * 16 + lr], sAcc[nt]);
            atomicAdd(&sQ[nt * 16 + lr], qAcc[nt]);
        }
    }
    __syncthreads();
    if (t < 128) {
        spart[(size_t)mc * 512 + p * 128 + t] = sS[t];
        spart[(size_t)mc * 512 + 256 + p * 128 + t] = sQ[t];
    }
}

// ---------------- MLP fused pass B v3: LDS-resident weights, grid-stride ---------

__global__ __launch_bounds__(256, 1) void k_mlp_fused(
    const __bf16* __restrict__ agg, const __bf16* __restrict__ g1h,
    const float* __restrict__ gb1, const float* __restrict__ statsIn,
    const float* __restrict__ gbn_g, const float* __restrict__ gbn_b,
    const __bf16* __restrict__ g2h, const float* __restrict__ gb2,
    __bf16* __restrict__ outx, float* __restrict__ spart2, int M, int ntiles)
{
    __shared__ __bf16 B1s[256][136];   // 69.6 KB
    __shared__ __bf16 B2s[128][264];   // 67.6 KB
    __shared__ __bf16 Tt[64 * 136];    // 17.4 KB (h1 panel / C transpose)
    __shared__ float scS[256], shS[256];
    __shared__ float sS[128], sQ[128];

    int t = threadIdx.x;
    int lane = t & 63, q = lane >> 4, lr = lane & 15;
    int w = t >> 6;

    {
        float mean = statsIn[t] * (1.f / (float)Nn);
        float var = statsIn[256 + t] * (1.f / (float)Nn) - mean * mean;
        float s = gbn_g[t] * rsqrtf(var + BN_EPS);
        scS[t] = s;
        shS[t] = (gb1[t] - mean) * s + gbn_b[t];
    }
    if (t < 128) { sS[t] = 0.f; sQ[t] = 0.f; }

    {
        const __bf16* src = g1h + (size_t)t * 128;
#pragma unroll
        for (int j = 0; j < 16; ++j)
            *(v8bf*)&B1s[t][j * 8] = *(const v8bf*)(src + j * 8);
    }
    {
        int r = t >> 1, h0 = (t & 1) * 128;
        const __bf16* src = g2h + (size_t)r * 256 + h0;
#pragma unroll
        for (int j = 0; j < 16; ++j)
            *(v8bf*)&B2s[r][h0 + j * 8] = *(const v8bf*)(src + j * 8);
    }
    __syncthreads();  // B1s/B2s/scS/shS/sS/sQ ready

    float bc2[8];
#pragma unroll
    for (int nt = 0; nt < 8; ++nt) bc2[nt] = gb2[nt * 16 + lr];

    float sAcc[8], qAcc[8];
#pragma unroll
    for (int nt = 0; nt < 8; ++nt) { sAcc[nt] = 0.f; qAcc[nt] = 0.f; }

    for (int tile = blockIdx.x; tile < ntiles; tile += gridDim.x) {
        int m0 = tile * 64;
        int gm = m0 + w * 16 + lr;
        bool rv = (gm < M);
        v8bf af[4];
#pragma unroll
        for (int kt = 0; kt < 4; ++kt) {
            v8bf hv = {};
            if (rv) hv = *(const v8bf*)(agg + (size_t)gm * H + kt * 32 + q * 8);
            af[kt] = hv;
        }

        v4f acc2[8] = {};
#pragma unroll
        for (int p = 0; p < 2; ++p) {
            v4f acc1[8] = {};
#pragma unroll
            for (int kt = 0; kt < 4; ++kt)
#pragma unroll
                for (int nt = 0; nt < 8; ++nt) {
                    v8bf bh = *(v8bf*)&B1s[p * 128 + nt * 16 + lr][kt * 32 + q * 8];
                    acc1[nt] = __builtin_amdgcn_mfma_f32_16x16x32_bf16(
                        af[kt], bh, acc1[nt], 0, 0, 0);
                }
#pragma unroll
            for (int nt = 0; nt < 8; ++nt)
#pragma unroll
                for (int reg = 0; reg < 4; ++reg) {
                    int row = w * 16 + q * 4 + reg;
                    int col = p * 128 + nt * 16 + lr;
                    float v = fmaxf(acc1[nt][reg] * scS[col] + shS[col], 0.f);
                    Tt[row * 136 + nt * 16 + lr] = (__bf16)v;
                }
            v8bf a2[4];
#pragma unroll
            for (int kt = 0; kt < 4; ++kt)
                a2[kt] = *(v8bf*)&Tt[(w * 16 + lr) * 136 + kt * 32 + q * 8];
#pragma unroll
            for (int kt = 0; kt < 4; ++kt)
#pragma unroll
                for (int nt = 0; nt < 8; ++nt) {
                    v8bf bh = *(v8bf*)&B2s[nt * 16 + lr][p * 128 + kt * 32 + q * 8];
                    acc2[nt] = __builtin_amdgcn_mfma_f32_16x16x32_bf16(
                        a2[kt], bh, acc2[nt], 0, 0, 0);
                }
        }

#pragma unroll
        for (int nt = 0; nt < 8; ++nt) {
#pragma unroll
            for (int reg = 0; reg < 4; ++reg) {
                int rm = m0 + w * 16 + q * 4 + reg;
                if (rm < M) {
                    float v = acc2[nt][reg] + bc2[nt];
                    sAcc[nt] += v;
                    qAcc[nt] += v * v;
                }
            }
        }
#pragma unroll
        for (int nt = 0; nt < 8; ++nt)
#pragma unroll
            for (int reg = 0; reg < 4; ++reg) {
                int row = w * 16 + q * 4 + reg;
                Tt[row * 136 + nt * 16 + lr] = (__bf16)(acc2[nt][reg] + bc2[nt]);
            }
        {
            int row = t >> 2;
            int c0 = (t & 3) * 32;
            int rm = m0 + row;
            if (rm < M) {
#pragma unroll
                for (int seg = 0; seg < 4; ++seg) {
                    int cc = c0 + seg * 8;
                    *(v8bf*)&outx[(size_t)rm * H + cc] = *(v8bf*)&Tt[row * 136 + cc];
                }
            }
        }
    }

#pragma unroll
    for (int nt = 0; nt < 8; ++nt) {
        sAcc[nt] += __shfl_xor(sAcc[nt], 16, 64);
        sAcc[nt] += __shfl_xor(sAcc[nt], 32, 64);
        qAcc[nt] += __shfl_xor(qAcc[nt], 16, 64);
        qAcc[nt] += __shfl_xor(qAcc[nt], 32, 64);
    }
    if (q == 0) {
#pragma unroll
        for (int nt = 0; nt < 8; ++nt) {
            atomicAdd(&sS[nt * 16 + lr], sAcc[nt]);
            atomicAdd(&sQ[nt * 16 + lr], qAcc[nt]);
        }
    }
    __syncthreads();
    {
        float pv = (t < 128) ? sS[t] : sQ[t - 128];
        spart2[(size_t)blockIdx.x * 256 + t] = pv;
    }
}

// ---------------- readout ----------------

__global__ void k_seg_batch(const __bf16* __restrict__ x, const int* __restrict__ batch,
                            float* __restrict__ xgsum, float* __restrict__ gcnt) {
    int h = threadIdx.x;
    int r0 = blockIdx.x * 256;
    if (r0 >= Nn) return;
    int r1 = min(r0 + 256, Nn);
    int cur = batch[r0];
    float acc = 0.f, c = 0.f;
    for (int r = r0; r < r1; ++r) {
        int b = batch[r];
        if (b != cur) {
            atomicAdd(&xgsum[cur * H + h], acc);
            if (h == 0) atomicAdd(&gcnt[cur], c);
            acc = 0.f;
            c = 0.f;
            cur = b;
        }
        acc += (float)x[(size_t)r * H + h];
        c += 1.f;
    }
    atomicAdd(&xgsum[cur * H + h], acc);
    if (h == 0) atomicAdd(&gcnt[cur], c);
}

__global__ void k_head(const float* __restrict__ xgsum, const float* __restrict__ gcnt,
                       const float* __restrict__ alw, const float* __restrict__ alb,
                       const float* __restrict__ lw, const float* __restrict__ lb,
                       float* __restrict__ out) {
    __shared__ float mean[H];
    __shared__ float red[H];
    int g = blockIdx.x, j = threadIdx.x;
    mean[j] = xgsum[g * H + j] / fmaxf(gcnt[g], 1.f);
    __syncthreads();
    float acc = alb[j];
    for (int k = 0; k < H; ++k) acc += mean[k] * alw[k * H + j];
    acc = fmaxf(acc, 0.f) * lw[j];
    red[j] = acc;
    __syncthreads();
    for (int s = 64; s > 0; s >>= 1) {
        if (j < s) red[j] += red[j + s];
        __syncthreads();
    }
    if (j == 0) out[g] = red[0] + lb[0];
}

// ---------------- host ----------------

extern "C" void kernel_launch(void* const* d_in, const int* in_sizes, int n_in,
                              void* d_out, int out_size, void* d_ws, size_t ws_size,
                              hipStream_t stream) {
    const int* x_atom = (const int*)d_in[0];
    const int* ei = (const int*)d_in[1];
    const int* eattr = (const int*)d_in[2];
    const int* batch = (const int*)d_in[3];
    const int* xc5 = (const int*)d_in[4];
    const int* xc6 = (const int*)d_in[5];
    const int* a2c5_row = (const int*)d_in[6];
    const int* a2c6_row = (const int*)d_in[8];
    const float* atom_emb = (const float*)d_in[10];
    const float* bond_emb = (const float*)d_in[11];
    const float* cyc5 = (const float*)d_in[12];
    const float* cyc6 = (const float*)d_in[13];
    const float* eps = (const float*)d_in[14];
    const float* gw1 = (const float*)d_in[15];
    const float* gb1 = (const float*)d_in[16];
    const float* gbn_g = (const float*)d_in[17];
    const float* gbn_b = (const float*)d_in[18];
    const float* gw2 = (const float*)d_in[19];
    const float* gb2 = (const float*)d_in[20];
    const float* bn_g = (const float*)d_in[21];
    const float* bn_b = (const float*)d_in[22];
    const float* a2c5_w = (const float*)d_in[23];
    const float* a2c5_b = (const float*)d_in[24];
    const float* a2c6_w = (const float*)d_in[25];
    const float* a2c6_b = (const float*)d_in[26];
    const float* c2a5_w = (const float*)d_in[27];
    const float* c2a5_b = (const float*)d_in[28];
    const float* c2a6_w = (const float*)d_in[29];
    const float* c2a6_b = (const float*)d_in[30];
    const float* p5_w = (const float*)d_in[31];
    const float* p5_b = (const float*)d_in[32];
    const float* p6_w = (const float*)d_in[33];
    const float* p6_b = (const float*)d_in[34];
    const float* alw = (const float*)d_in[35];
    const float* alb = (const float*)d_in[36];
    const float* lw = (const float*)d_in[37];
    const float* lb = (const float*)d_in[38];
    float* out = (float*)d_out;

    float* w = (float*)d_ws;
    size_t o = 0;
    auto alloc = [&](size_t nf) {
        float* p = w + o;
        o += (nf + 63) & ~(size_t)63;
        return p;
    };
    auto allocb = [&](size_t nbf) { return (__bf16*)alloc((nbf + 1) / 2); };
    const int TPB = 256;
    auto cdiv = [](int a, int b) { return (a + b - 1) / b; };
    int nblkA = cdiv(Nn, 64);
    int mchunks = cdiv(Nn, 256);

    __bf16* x = allocb((size_t)Nn * H);
    __bf16* x5 = allocb((size_t)N5c * 5 * H);
    __bf16* x6 = allocb((size_t)N6c * 6 * H);
    __bf16* agg = allocb((size_t)Nn * H);
    float* stats = alloc(512);
    float* stats2 = alloc(256);
    float* spart = alloc((size_t)nblkA * 512);
    float* xgsum = alloc((size_t)Gg * H);
    float* gcnt = alloc(Gg);
    float* rscale5 = alloc(Nn);
    float* rscale6 = alloc(Nn);
    int* deg = (int*)alloc(Nn);
    int* rowptr = (int*)alloc(Nn + 1);
    int* rp5c = (int*)alloc(Nn + 1);
    int* rp6c = (int*)alloc(Nn + 1);
    int* woff = (int*)alloc(Nn);
    int* bsum = (int*)alloc(256);
    int* boff = (int*)alloc(256);
    unsigned int* elist = (unsigned int*)alloc(Ee);
    int* cidx5 = (int*)alloc(N5c * 5);
    int* cidx6 = (int*)alloc(N6c * 6);
    float* ebank = alloc(512 * H);
    __bf16* g1h = allocb(3 * 128 * 256);
    __bf16* g2h = allocb(3 * 256 * 128);
    __bf16* a5h = allocb(3 * 128 * 128);
    __bf16* a6h = allocb(3 * 128 * 128);
    __bf16* c5h = allocb(3 * 128 * 128);
    __bf16* c6h = allocb(3 * 128 * 128);
    __bf16* p5h = allocb(3 * 384 * 128);
    __bf16* p6h = allocb(3 * 384 * 128);

    int nsb = cdiv(Nn, 1024);

    // weight pre-split (transposed bf16 planes)
    k_split<<<cdiv(3 * 128 * 256, TPB), TPB, 0, stream>>>(gw1, g1h, 3, 128, 256);
    k_split<<<cdiv(3 * 256 * 128, TPB), TPB, 0, stream>>>(gw2, g2h, 3, 256, 128);
    k_split<<<cdiv(3 * 128 * 128, TPB), TPB, 0, stream>>>(a2c5_w, a5h, 3, 128, 128);
    k_split<<<cdiv(3 * 128 * 128, TPB), TPB, 0, stream>>>(a2c6_w, a6h, 3, 128, 128);
    k_split<<<cdiv(3 * 128 * 128, TPB), TPB, 0, stream>>>(c2a5_w, c5h, 3, 128, 128);
    k_split<<<cdiv(3 * 128 * 128, TPB), TPB, 0, stream>>>(c2a6_w, c6h, 3, 128, 128);
    k_split<<<cdiv(3 * 384 * 128, TPB), TPB, 0, stream>>>(p5_w, p5h, 3, 384, 128);
    k_split<<<cdiv(3 * 384 * 128, TPB), TPB, 0, stream>>>(p6_w, p6h, 3, 384, 128);

    // edge CSR
    hipMemsetAsync(deg, 0, Nn * 4, stream);
    k_degi<<<cdiv(Ee, TPB), TPB, 0, stream>>>(ei + Ee, deg, Ee);
    k_scan1<<<nsb, 256, 0, stream>>>(deg, rowptr, bsum, Nn);
    k_scan2<<<1, 128, 0, stream>>>(bsum, boff, rowptr, nsb, Nn);
    k_scan3<<<cdiv(Nn, TPB), TPB, 0, stream>>>(rowptr, boff, Nn);
    hipMemcpyAsync(woff, rowptr, Nn * 4, hipMemcpyDeviceToDevice, stream);
    k_fill<<<cdiv(Ee, TPB), TPB, 0, stream>>>(ei, eattr, woff, elist);

    // cycle->atom CSRs + mean scales
    hipMemsetAsync(deg, 0, Nn * 4, stream);
    k_degi<<<cdiv(N5c * 5, TPB), TPB, 0, stream>>>(a2c5_row, deg, N5c * 5);
    k_scan1<<<nsb, 256, 0, stream>>>(deg, rp5c, bsum, Nn);
    k_scan2<<<1, 128, 0, stream>>>(bsum, boff, rp5c, nsb, Nn);
    k_scan3<<<cdiv(Nn, TPB), TPB, 0, stream>>>(rp5c, boff, Nn);
    k_inv_int<<<cdiv(Nn, TPB), TPB, 0, stream>>>(deg, rscale5);
    hipMemcpyAsync(woff, rp5c, Nn * 4, hipMemcpyDeviceToDevice, stream);
    k_fill_idx<<<cdiv(N5c * 5, TPB), TPB, 0, stream>>>(a2c5_row, woff, cidx5, N5c * 5);

    hipMemsetAsync(deg, 0, Nn * 4, stream);
    k_degi<<<cdiv(N6c * 6, TPB), TPB, 0, stream>>>(a2c6_row, deg, N6c * 6);
    k_scan1<<<nsb, 256, 0, stream>>>(deg, rp6c, bsum, Nn);
    k_scan2<<<1, 128, 0, stream>>>(bsum, boff, rp6c, nsb, Nn);
    k_scan3<<<cdiv(Nn, TPB), TPB, 0, stream>>>(rp6c, boff, Nn);
    k_inv_int<<<cdiv(Nn, TPB), TPB, 0, stream>>>(deg, rscale6);
    hipMemcpyAsync(woff, rp6c, Nn * 4, hipMemcpyDeviceToDevice, stream);
    k_fill_idx<<<cdiv(N6c * 6, TPB), TPB, 0, stream>>>(a2c6_row, woff, cidx6, N6c * 6);

    k_atom_enc<<<cdiv(Nn * H, TPB), TPB, 0, stream>>>(x_atom, atom_emb, x);
    k_cyc_init<<<cdiv(N5c * 5 * H, TPB), TPB, 0, stream>>>(xc5, cyc5, x5, N5c * 5);
    k_cyc_init<<<cdiv(N6c * 6 * H, TPB), TPB, 0, stream>>>(xc6, cyc6, x6, N6c * 6);

    const int GS = 512;   // grid-stride block count for gemm128
    const int GF = 256;   // 1 block/CU kernels (big-LDS)
    for (int i = 0; i < Ll; ++i) {
        // GINE aggregation (gather) -> agg
        k_ebank<<<cdiv(512 * H, TPB), TPB, 0, stream>>>(
            bond_emb + (size_t)i * BF * BV * H, ebank);
        k_agg_csr<<<Nn / 2, 256, 0, stream>>>(x, rowptr, elist, ebank, eps, i, agg);

        // MLP pass A: BN1 stats (barrier-free; partials -> reduce)
        hipMemsetAsync(stats, 0, 512 * 4, stream);
        k_mlp_statsA<<<mchunks * 2, 256, 0, stream>>>(
            agg, g1h + (size_t)i * 128 * 256, gb1 + (size_t)i * 256, spart, Nn);
        k_red<<<dim3(8, 8), 256, 0, stream>>>(spart, stats, 512, mchunks);

        // MLP fused pass B v3 (LDS-resident weights) -> x_raw + BN2 partials
        hipMemsetAsync(stats2, 0, 256 * 4, stream);
        k_mlp_fused<<<GF, 256, 0, stream>>>(
            agg, g1h + (size_t)i * 128 * 256, gb1 + (size_t)i * 256, stats,
            gbn_g + (size_t)i * 256, gbn_b + (size_t)i * 256,
            g2h + (size_t)i * 256 * 128, gb2 + (size_t)i * H, x, spart,
            Nn, nblkA);
        k_red<<<dim3(4, 8), 256, 0, stream>>>(spart, stats2, 256, GF);

        // atoms -> cycles (row-gather, BN2+relu folded on A, in-place residual)
        k_gemm128<1, false><<<GS, 256, 0, stream>>>(
            x, a5h + (size_t)i * 128 * 128, a2c5_b + (size_t)i * H,
            x5, x5, a2c5_row, nullptr, nullptr, nullptr,
            stats2, bn_g + (size_t)i * H, bn_b + (size_t)i * H,
            N5c * 5, cdiv(N5c * 5, 64));
        k_gemm128<1, false><<<GS, 256, 0, stream>>>(
            x, a6h + (size_t)i * 128 * 128, a2c6_b + (size_t)i * H,
            x6, x6, a2c6_row, nullptr, nullptr, nullptr,
            stats2, bn_g + (size_t)i * H, bn_b + (size_t)i * H,
            N6c * 6, cdiv(N6c * 6, 64));

        // cyclic path blocks v3: LDS-resident weights, 512-thread blocks
        k_path<5><<<GF, 512, 0, stream>>>(
            x5, p5h + (size_t)i * 384 * 128, p5_b + (size_t)i * H, x5,
            N5c * 5, cdiv(N5c * 5, 120));
        k_path<6><<<GF, 512, 0, stream>>>(
            x6, p6h + (size_t)i * 384 * 128, p6_b + (size_t)i * H, x6,
            N6c * 6, cdiv(N6c * 6, 120));

        // cycles -> atoms (CSR mean-gather; c2a5 folds BN2+relu on res side)
        k_gemm128<2, true><<<GS, 256, 0, stream>>>(
            x5, c5h + (size_t)i * 128 * 128, c2a5_b + (size_t)i * H,
            x, x, nullptr, rp5c, cidx5, rscale5,
            stats2, bn_g + (size_t)i * H, bn_b + (size_t)i * H,
            Nn, cdiv(Nn, 64));
        k_gemm128<0, true><<<GS, 256, 0, stream>>>(
            x6, c6h + (size_t)i * 128 * 128, c2a6_b + (size_t)i * H,
            x, x, nullptr, rp6c, cidx6, rscale6,
            nullptr, nullptr, nullptr, Nn, cdiv(Nn, 64));
    }

    // readout
    hipMemsetAsync(xgsum, 0, (size_t)Gg * H * 4, stream);
    hipMemsetAsync(gcnt, 0, (size_t)Gg * 4, stream);
    k_seg_batch<<<cdiv(Nn, 256), H, 0, stream>>>(x, batch, xgsum, gcnt);
    k_head<<<Gg, H, 0, stream>>>(xgsum, gcnt, alw, alb, lw, lb, out);
}

// Round 9
// 1393.844 us; speedup vs baseline: 1.9632x; 1.0462x over previous
//
#include <hip/hip_runtime.h>

#define H 128
#define Nn 100000
#define Ee 250000
#define N5c 20000
#define N6c 30000
#define Gg 512
#define Ll 3
#define AF 9
#define AV 64
#define BF 3
#define BV 8
#define BN_EPS 1e-5f

typedef __bf16 v8bf __attribute__((ext_vector_type(8)));
typedef float v4f __attribute__((ext_vector_type(4)));

// ---------------- init / embedding kernels ----------------

__global__ void k_atom_enc(const int* __restrict__ xa, const float* __restrict__ emb,
                           __bf16* __restrict__ x) {
    int idx = blockIdx.x * blockDim.x + threadIdx.x;
    if (idx >= Nn * H) return;
    int n = idx >> 7, h = idx & 127;
    float s = 0.f;
#pragma unroll
    for (int f = 0; f < AF; ++f) {
        int a = xa[n * AF + f];
        s += emb[(f * AV + a) * H + h];
    }
    x[idx] = (__bf16)s;
}

__global__ void k_cyc_init(const int* __restrict__ xc, const float* __restrict__ emb,
                           __bf16* __restrict__ xo, int M) {
    int idx = blockIdx.x * blockDim.x + threadIdx.x;
    if (idx >= M * H) return;
    int m = idx >> 7, h = idx & 127;
    xo[idx] = (__bf16)emb[xc[m] * H + h];
}

// weight pre-split: (L,K,N) fp32 row-major -> per-layer transposed [n][k] bf16
__global__ void k_split(const float* __restrict__ src, __bf16* __restrict__ dh,
                        int L, int K, int N) {
    int idx = blockIdx.x * blockDim.x + threadIdx.x;
    int tot = L * K * N;
    if (idx >= tot) return;
    int l = idx / (K * N);
    int r = idx - l * (K * N);
    int k = r / N;
    int n = r - k * N;
    size_t d = (size_t)l * K * N + (size_t)n * K + k;
    dh[d] = (__bf16)src[idx];
}

// ---------------- CSR build helpers ----------------

__global__ void k_degi(const int* __restrict__ row, int* __restrict__ deg, int M) {
    int m = blockIdx.x * blockDim.x + threadIdx.x;
    if (m >= M) return;
    atomicAdd(&deg[row[m]], 1);
}

__global__ void k_scan1(const int* __restrict__ deg, int* __restrict__ rp,
                        int* __restrict__ bsum, int n) {
    __shared__ int s[256];
    int tid = threadIdx.x;
    int base = blockIdx.x * 1024 + tid * 4;
    int v0 = (base < n) ? deg[base] : 0;
    int v1 = (base + 1 < n) ? deg[base + 1] : 0;
    int v2 = (base + 2 < n) ? deg[base + 2] : 0;
    int v3 = (base + 3 < n) ? deg[base + 3] : 0;
    int tsum = v0 + v1 + v2 + v3;
    s[tid] = tsum;
    __syncthreads();
    for (int off = 1; off < 256; off <<= 1) {
        int u = (tid >= off) ? s[tid - off] : 0;
        __syncthreads();
        s[tid] += u;
        __syncthreads();
    }
    int exc = s[tid] - tsum;
    if (base < n) rp[base] = exc;
    if (base + 1 < n) rp[base + 1] = exc + v0;
    if (base + 2 < n) rp[base + 2] = exc + v0 + v1;
    if (base + 3 < n) rp[base + 3] = exc + v0 + v1 + v2;
    if (tid == 255) bsum[blockIdx.x] = s[255];
}

__global__ void k_scan2(const int* __restrict__ bsum, int* __restrict__ boff,
                        int* __restrict__ rp, int nb, int n) {
    __shared__ int s[128];
    int tid = threadIdx.x;
    int v = (tid < nb) ? bsum[tid] : 0;
    s[tid] = v;
    __syncthreads();
    for (int off = 1; off < 128; off <<= 1) {
        int u = (tid >= off) ? s[tid - off] : 0;
        __syncthreads();
        s[tid] += u;
        __syncthreads();
    }
    if (tid < nb) boff[tid] = s[tid] - v;
    if (tid == 127) rp[n] = s[127];
}

__global__ void k_scan3(int* __restrict__ rp, const int* __restrict__ boff, int n) {
    int idx = blockIdx.x * blockDim.x + threadIdx.x;
    if (idx < n) rp[idx] += boff[idx >> 10];
}

__global__ void k_fill(const int* __restrict__ ei, const int* __restrict__ eattr,
                       int* __restrict__ woff, unsigned int* __restrict__ elist) {
    int e = blockIdx.x * blockDim.x + threadIdx.x;
    if (e >= Ee) return;
    int src = ei[e], dst = ei[Ee + e];
    int code = eattr[e * BF + 0] * 64 + eattr[e * BF + 1] * 8 + eattr[e * BF + 2];
    int p = atomicAdd(&woff[dst], 1);
    elist[p] = ((unsigned int)code << 17) | (unsigned int)src;
}

__global__ void k_fill_idx(const int* __restrict__ row, int* __restrict__ woff,
                           int* __restrict__ cidx, int M) {
    int m = blockIdx.x * blockDim.x + threadIdx.x;
    if (m >= M) return;
    int p = atomicAdd(&woff[row[m]], 1);
    cidx[p] = m;
}

__global__ void k_inv_int(const int* __restrict__ deg, float* __restrict__ rscale) {
    int r = blockIdx.x * blockDim.x + threadIdx.x;
    if (r >= Nn) return;
    rscale[r] = 1.f / fmaxf((float)deg[r], 1.f);
}

__global__ void k_ebank(const float* __restrict__ bemb, float* __restrict__ ebank) {
    int idx = blockIdx.x * blockDim.x + threadIdx.x;
    if (idx >= 512 * H) return;
    int code = idx >> 7, h = idx & 127;
    int f0 = code >> 6, f1 = (code >> 3) & 7, f2 = code & 7;
    ebank[idx] = bemb[(0 * BV + f0) * H + h] + bemb[(1 * BV + f1) * H + h]
               + bemb[(2 * BV + f2) * H + h];
}

// GINE aggregation, gather form
__global__ __launch_bounds__(256) void k_agg_csr(
    const __bf16* __restrict__ x, const int* __restrict__ rowptr,
    const unsigned int* __restrict__ elist, const float* __restrict__ ebank,
    const float* __restrict__ eps, int layer, __bf16* __restrict__ agg)
{
    int a = blockIdx.x * 2 + (threadIdx.x >> 7);
    int h = threadIdx.x & 127;
    float acc = (1.f + eps[layer]) * (float)x[(size_t)a * H + h];
    int j0 = rowptr[a], j1 = rowptr[a + 1];
    for (int j = j0; j < j1; ++j) {
        unsigned int u = elist[j];
        int src = u & 0x1FFFF;
        int code = u >> 17;
        acc += fmaxf((float)x[(size_t)src * H + h] + ebank[code * H + h], 0.f);
    }
    agg[(size_t)a * H + h] = (__bf16)acc;
}

// ---------------- cross-block stats reduction ----------------

__global__ __launch_bounds__(256) void k_red(const float* __restrict__ part,
                                             float* __restrict__ out,
                                             int width, int nb)
{
    __shared__ float s[256];
    int t = threadIdx.x;
    int col = blockIdx.x * 64 + (t & 63);
    int pl = t >> 6;
    float acc = 0.f;
    for (int p = blockIdx.y * 4 + pl; p < nb; p += 32)
        acc += part[(size_t)p * width + col];
    s[t] = acc;
    __syncthreads();
    if (pl == 0) {
        float v = s[t] + s[t + 64] + s[t + 128] + s[t + 192];
        atomicAdd(&out[col], v);
    }
}

// ---------------- K=128 GEMM v3: B in regs once, GRID-STRIDE over 64-row tiles ----

template <int BNMODE, bool GRP>
__global__ __launch_bounds__(256) void k_gemm128(
    const __bf16* __restrict__ A, const __bf16* __restrict__ Bth,
    const float* __restrict__ bias, const __bf16* __restrict__ res,
    __bf16* __restrict__ out, const int* __restrict__ rowidx,
    const int* __restrict__ grp, const int* __restrict__ gcol,
    const float* __restrict__ gscale,
    const float* __restrict__ bnstats, const float* __restrict__ bng,
    const float* __restrict__ bnb, int M, int ntiles)
{
    __shared__ __bf16 Ct[64 * 136];
    __shared__ float scB[128], shB[128];

    int t = threadIdx.x;
    int lane = t & 63, q = lane >> 4, lr = lane & 15;
    int w = t >> 6;

    if (BNMODE && t < 128) {
        float mean = bnstats[t] * (1.f / (float)Nn);
        float var = bnstats[128 + t] * (1.f / (float)Nn) - mean * mean;
        float s = bng[t] * rsqrtf(var + BN_EPS);
        scB[t] = s;
        shB[t] = bnb[t] - mean * s;
    }
    if (BNMODE) __syncthreads();

    v8bf bf[8][4];
#pragma unroll
    for (int nt = 0; nt < 8; ++nt) {
        const __bf16* bp = Bth + (size_t)(nt * 16 + lr) * 128 + q * 8;
#pragma unroll
        for (int kt = 0; kt < 4; ++kt)
            bf[nt][kt] = *(const v8bf*)(bp + kt * 32);
    }
    float bcol[8];
#pragma unroll
    for (int nt = 0; nt < 8; ++nt) bcol[nt] = bias[nt * 16 + lr];

    for (int tile = blockIdx.x; tile < ntiles; tile += gridDim.x) {
        int m0 = tile * 64;
        int gm = m0 + w * 16 + lr;
        bool rvalid = (gm < M);

        v8bf af[4];
        if (GRP) {
            float a8[4][8];
#pragma unroll
            for (int kt = 0; kt < 4; ++kt)
#pragma unroll
                for (int i = 0; i < 8; ++i) a8[kt][i] = 0.f;
            float sc = 1.f;
            if (rvalid) {
                int j0 = grp[gm], j1 = grp[gm + 1];
                sc = gscale[gm];
                for (int j = j0; j < j1; ++j) {
                    const __bf16* rp2 = A + (size_t)gcol[j] * H;
#pragma unroll
                    for (int kt = 0; kt < 4; ++kt) {
                        v8bf g = *(const v8bf*)(rp2 + kt * 32 + q * 8);
#pragma unroll
                        for (int i = 0; i < 8; ++i) a8[kt][i] += (float)g[i];
                    }
                }
            }
#pragma unroll
            for (int kt = 0; kt < 4; ++kt)
#pragma unroll
                for (int i = 0; i < 8; ++i) af[kt][i] = (__bf16)(a8[kt][i] * sc);
        } else {
            const __bf16* base = A;
            if (rvalid) base = rowidx ? A + (size_t)rowidx[gm] * H : A + (size_t)gm * H;
#pragma unroll
            for (int kt = 0; kt < 4; ++kt) {
                v8bf hv = {};
                if (rvalid) hv = *(const v8bf*)(base + kt * 32 + q * 8);
                af[kt] = hv;
            }
        }
        if (BNMODE == 1) {
            if (rvalid) {
#pragma unroll
                for (int kt = 0; kt < 4; ++kt) {
                    int kb = kt * 32 + q * 8;
#pragma unroll
                    for (int i = 0; i < 8; ++i)
                        af[kt][i] =
                            (__bf16)fmaxf((float)af[kt][i] * scB[kb + i] + shB[kb + i], 0.f);
                }
            }
        }

        v4f acc[8] = {};
#pragma unroll
        for (int kt = 0; kt < 4; ++kt)
#pragma unroll
            for (int nt = 0; nt < 8; ++nt)
                acc[nt] = __builtin_amdgcn_mfma_f32_16x16x32_bf16(
                    af[kt], bf[nt][kt], acc[nt], 0, 0, 0);

#pragma unroll
        for (int nt = 0; nt < 8; ++nt)
#pragma unroll
            for (int reg = 0; reg < 4; ++reg) {
                int row = w * 16 + q * 4 + reg;
                float v = fmaxf(acc[nt][reg] + bcol[nt], 0.f);
                Ct[row * 136 + nt * 16 + lr] = (__bf16)v;
            }
        {
            int row = t >> 2;
            int c0 = (t & 3) * 32;
            int rm = m0 + row;
            if (rm < M) {
#pragma unroll
                for (int seg = 0; seg < 4; ++seg) {
                    int cc = c0 + seg * 8;
                    v8bf cv = *(v8bf*)&Ct[row * 136 + cc];
                    v8bf rv2 = *(const v8bf*)&res[(size_t)rm * H + cc];
#pragma unroll
                    for (int i = 0; i < 8; ++i) {
                        float rf = (float)rv2[i];
                        if (BNMODE == 2)
                            rf = fmaxf(rf * scB[cc + i] + shB[cc + i], 0.f);
                        cv[i] = (__bf16)((float)cv[i] + rf);
                    }
                    *(v8bf*)&out[(size_t)rm * H + cc] = cv;
                }
            }
        }
    }
}

// ---------------- cyclic path block v3: LDS-resident weights ----------------

template <int PK>
__global__ __launch_bounds__(512, 1) void k_path(
    const __bf16* __restrict__ X, const __bf16* __restrict__ Bth,
    const float* __restrict__ bias, __bf16* __restrict__ Xout,
    int M, int nchunks)
{
    __shared__ __bf16 Bs[128][392];   // 100.4 KB (pad 8 cols: 4-bank row shift)
    __shared__ __bf16 Ct[128 * 136];  // 34.8 KB
    int t = threadIdx.x;
    int lane = t & 63, q = lane >> 4, lr = lane & 15;
    int w = t >> 6;        // 0..7
    int mt = w >> 2;       // 0 or 1
    int wm = w & 3;        // wave within mt half

    // stage B: thread t stages row t>>2, col-quarter (t&3)*96 (12 v8bf)
    {
        int r = t >> 2, c0 = (t & 3) * 96;
        const __bf16* src = Bth + (size_t)r * 384 + c0;
#pragma unroll
        for (int j = 0; j < 12; ++j)
            *(v8bf*)&Bs[r][c0 + j * 8] = *(const v8bf*)(src + j * 8);
    }
    float bcol[8];
#pragma unroll
    for (int nt = 0; nt < 8; ++nt) bcol[nt] = bias[nt * 16 + lr];
    __syncthreads();  // Bs ready

    for (int ch = blockIdx.x; ch < nchunks; ch += gridDim.x) {
        int tb = ch * 120;
        int rloc = wm * 16 + lr;
        int gm = tb + mt * 60 + rloc;
        bool rv = (rloc < 60) && (gm < M);
        v4f acc[8] = {};
#pragma unroll
        for (int p = 0; p < 3; ++p) {
            v8bf af[4];
#pragma unroll
            for (int kt = 0; kt < 4; ++kt) af[kt] = v8bf{};
            if (rv) {
                int pm = gm % PK;
                int pp = pm + p - 1;
                if (pp < 0) pp += PK;
                if (pp >= PK) pp -= PK;
                const __bf16* ap = X + (size_t)(gm - pm + pp) * H + q * 8;
#pragma unroll
                for (int kt = 0; kt < 4; ++kt)
                    af[kt] = *(const v8bf*)(ap + kt * 32);
            }
#pragma unroll
            for (int nt = 0; nt < 8; ++nt)
#pragma unroll
                for (int kt = 0; kt < 4; ++kt) {
                    v8bf bh = *(v8bf*)&Bs[nt * 16 + lr][p * 128 + kt * 32 + q * 8];
                    acc[nt] = __builtin_amdgcn_mfma_f32_16x16x32_bf16(
                        af[kt], bh, acc[nt], 0, 0, 0);
                }
        }
        // all rolled A reads (which cross wave row-boundaries) must complete
        // before the in-place residual+write below
        __syncthreads();
#pragma unroll
        for (int nt = 0; nt < 8; ++nt)
#pragma unroll
            for (int reg = 0; reg < 4; ++reg) {
                int row = w * 16 + q * 4 + reg;   // 0..127, wave-local
                float v = fmaxf(acc[nt][reg] + bcol[nt], 0.f);
                Ct[row * 136 + nt * 16 + lr] = (__bf16)v;
            }
        {
            int row = t >> 2;                    // 0..127, same wave's rows
            int c0 = (t & 3) * 32;
            int rmloc = row & 63;
            int rm = tb + (row >> 6) * 60 + rmloc;
            if (rmloc < 60 && rm < M) {
#pragma unroll
                for (int seg = 0; seg < 4; ++seg) {
                    int cc = c0 + seg * 8;
                    v8bf cv = *(v8bf*)&Ct[row * 136 + cc];
                    v8bf rv2 = *(const v8bf*)&X[(size_t)rm * H + cc];
#pragma unroll
                    for (int i = 0; i < 8; ++i)
                        cv[i] = (__bf16)((float)cv[i] + (float)rv2[i]);
                    *(v8bf*)&Xout[(size_t)rm * H + cc] = cv;
                }
            }
        }
    }
}

// ---------------- MLP pass A: BN1 column stats only ----------------

__global__ __launch_bounds__(256) void k_mlp_statsA(
    const __bf16* __restrict__ agg, const __bf16* __restrict__ g1h,
    const float* __restrict__ gb1, float* __restrict__ spart, int M)
{
    __shared__ float sS[128], sQ[128];
    int t = threadIdx.x;
    int mc = blockIdx.x >> 1, p = blockIdx.x & 1;
    int lane = t & 63, q = lane >> 4, lr = lane & 15;
    int w = t >> 6;
    if (t < 128) { sS[t] = 0.f; sQ[t] = 0.f; }

    v8bf bf[8][4];
#pragma unroll
    for (int nt = 0; nt < 8; ++nt) {
        const __bf16* bp = g1h + (size_t)(p * 128 + nt * 16 + lr) * 128 + q * 8;
#pragma unroll
        for (int kt = 0; kt < 4; ++kt)
            bf[nt][kt] = *(const v8bf*)(bp + kt * 32);
    }
    float bv[8];
#pragma unroll
    for (int nt = 0; nt < 8; ++nt) bv[nt] = gb1[p * 128 + nt * 16 + lr];

    float sAcc[8], qAcc[8];
#pragma unroll
    for (int nt = 0; nt < 8; ++nt) { sAcc[nt] = 0.f; qAcc[nt] = 0.f; }

#pragma unroll
    for (int mt = 0; mt < 4; ++mt) {
        int rb = mc * 256 + mt * 64 + w * 16;
        int gm = rb + lr;
        bool rv = (gm < M);
        v8bf af[4];
#pragma unroll
        for (int kt = 0; kt < 4; ++kt) {
            v8bf hv = {};
            if (rv) hv = *(const v8bf*)(agg + (size_t)gm * H + kt * 32 + q * 8);
            af[kt] = hv;
        }
        v4f acc[8] = {};
#pragma unroll
        for (int kt = 0; kt < 4; ++kt)
#pragma unroll
            for (int nt = 0; nt < 8; ++nt)
                acc[nt] = __builtin_amdgcn_mfma_f32_16x16x32_bf16(
                    af[kt], bf[nt][kt], acc[nt], 0, 0, 0);
#pragma unroll
        for (int nt = 0; nt < 8; ++nt) {
            float s = 0.f, q2 = 0.f;
#pragma unroll
            for (int reg = 0; reg < 4; ++reg) {
                int rm = rb + q * 4 + reg;
                if (rm < M) {
                    float v = acc[nt][reg] + bv[nt];
                    s += v;
                    q2 += v * v;
                }
            }
            sAcc[nt] += s;
            qAcc[nt] += q2;
        }
    }
#pragma unroll
    for (int nt = 0; nt < 8; ++nt) {
        sAcc[nt] += __shfl_xor(sAcc[nt], 16, 64);
        sAcc[nt] += __shfl_xor(sAcc[nt], 32, 64);
        qAcc[nt] += __shfl_xor(qAcc[nt], 16, 64);
        qAcc[nt] += __shfl_xor(qAcc[nt], 32, 64);
    }
    __syncthreads();
    if (q == 0) {
#pragma unroll
        for (int nt = 0; nt < 8; ++nt) {
            atomicAdd(&sS[nt * 16 + lr], sAcc[nt]);
            atomicAdd(&sQ[nt * 16 + lr], qAcc[nt]);
        }
    }
    __syncthreads();
    if (t < 128) {
        spart[(size_t)mc * 512 + p * 128 + t] = sS[t];
        spart[(size_t)mc * 512 + 256 + p * 128 + t] = sQ[t];
    }
}

// ---------------- MLP fused pass B v3: LDS-resident weights, grid-stride ---------

__global__ __launch_bounds__(256, 1) void k_mlp_fused(
    const __bf16* __restrict__ agg, const __bf16* __restrict__ g1h,
    const float* __restrict__ gb1, const float* __restrict__ statsIn,
    const float* __restrict__ gbn_g, const float* __restrict__ gbn_b,
    const __bf16* __restrict__ g2h, const float* __restrict__ gb2,
    __bf16* __restrict__ outx, float* __restrict__ spart2, int M, int ntiles)
{
    __shared__ __bf16 B1s[256][136];   // 69.6 KB
    __shared__ __bf16 B2s[128][264];   // 67.6 KB
    __shared__ __bf16 Tt[64 * 136];    // 17.4 KB (h1 panel / C transpose)
    __shared__ float scS[256], shS[256];
    __shared__ float sS[128], sQ[128];

    int t = threadIdx.x;
    int lane = t & 63, q = lane >> 4, lr = lane & 15;
    int w = t >> 6;

    {
        float mean = statsIn[t] * (1.f / (float)Nn);
        float var = statsIn[256 + t] * (1.f / (float)Nn) - mean * mean;
        float s = gbn_g[t] * rsqrtf(var + BN_EPS);
        scS[t] = s;
        shS[t] = (gb1[t] - mean) * s + gbn_b[t];
    }
    if (t < 128) { sS[t] = 0.f; sQ[t] = 0.f; }

    {
        const __bf16* src = g1h + (size_t)t * 128;
#pragma unroll
        for (int j = 0; j < 16; ++j)
            *(v8bf*)&B1s[t][j * 8] = *(const v8bf*)(src + j * 8);
    }
    {
        int r = t >> 1, h0 = (t & 1) * 128;
        const __bf16* src = g2h + (size_t)r * 256 + h0;
#pragma unroll
        for (int j = 0; j < 16; ++j)
            *(v8bf*)&B2s[r][h0 + j * 8] = *(const v8bf*)(src + j * 8);
    }
    __syncthreads();  // B1s/B2s/scS/shS/sS/sQ ready

    float bc2[8];
#pragma unroll
    for (int nt = 0; nt < 8; ++nt) bc2[nt] = gb2[nt * 16 + lr];

    float sAcc[8], qAcc[8];
#pragma unroll
    for (int nt = 0; nt < 8; ++nt) { sAcc[nt] = 0.f; qAcc[nt] = 0.f; }

    for (int tile = blockIdx.x; tile < ntiles; tile += gridDim.x) {
        int m0 = tile * 64;
        int gm = m0 + w * 16 + lr;
        bool rv = (gm < M);
        v8bf af[4];
#pragma unroll
        for (int kt = 0; kt < 4; ++kt) {
            v8bf hv = {};
            if (rv) hv = *(const v8bf*)(agg + (size_t)gm * H + kt * 32 + q * 8);
            af[kt] = hv;
        }

        v4f acc2[8] = {};
#pragma unroll
        for (int p = 0; p < 2; ++p) {
            v4f acc1[8] = {};
#pragma unroll
            for (int kt = 0; kt < 4; ++kt)
#pragma unroll
                for (int nt = 0; nt < 8; ++nt) {
                    v8bf bh = *(v8bf*)&B1s[p * 128 + nt * 16 + lr][kt * 32 + q * 8];
                    acc1[nt] = __builtin_amdgcn_mfma_f32_16x16x32_bf16(
                        af[kt], bh, acc1[nt], 0, 0, 0);
                }
#pragma unroll
            for (int nt = 0; nt < 8; ++nt)
#pragma unroll
                for (int reg = 0; reg < 4; ++reg) {
                    int row = w * 16 + q * 4 + reg;
                    int col = p * 128 + nt * 16 + lr;
                    float v = fmaxf(acc1[nt][reg] * scS[col] + shS[col], 0.f);
                    Tt[row * 136 + nt * 16 + lr] = (__bf16)v;
                }
            v8bf a2[4];
#pragma unroll
            for (int kt = 0; kt < 4; ++kt)
                a2[kt] = *(v8bf*)&Tt[(w * 16 + lr) * 136 + kt * 32 + q * 8];
#pragma unroll
            for (int kt = 0; kt < 4; ++kt)
#pragma unroll
                for (int nt = 0; nt < 8; ++nt) {
                    v8bf bh = *(v8bf*)&B2s[nt * 16 + lr][p * 128 + kt * 32 + q * 8];
                    acc2[nt] = __builtin_amdgcn_mfma_f32_16x16x32_bf16(
                        a2[kt], bh, acc2[nt], 0, 0, 0);
                }
        }

#pragma unroll
        for (int nt = 0; nt < 8; ++nt) {
#pragma unroll
            for (int reg = 0; reg < 4; ++reg) {
                int rm = m0 + w * 16 + q * 4 + reg;
                if (rm < M) {
                    float v = acc2[nt][reg] + bc2[nt];
                    sAcc[nt] += v;
                    qAcc[nt] += v * v;
                }
            }
        }
#pragma unroll
        for (int nt = 0; nt < 8; ++nt)
#pragma unroll
            for (int reg = 0; reg < 4; ++reg) {
                int row = w * 16 + q * 4 + reg;
                Tt[row * 136 + nt * 16 + lr] = (__bf16)(acc2[nt][reg] + bc2[nt]);
            }
        {
            int row = t >> 2;
            int c0 = (t & 3) * 32;
            int rm = m0 + row;
            if (rm < M) {
#pragma unroll
                for (int seg = 0; seg < 4; ++seg) {
                    int cc = c0 + seg * 8;
                    *(v8bf*)&outx[(size_t)rm * H + cc] = *(v8bf*)&Tt[row * 136 + cc];
                }
            }
        }
    }

#pragma unroll
    for (int nt = 0; nt < 8; ++nt) {
        sAcc[nt] += __shfl_xor(sAcc[nt], 16, 64);
        sAcc[nt] += __shfl_xor(sAcc[nt], 32, 64);
        qAcc[nt] += __shfl_xor(qAcc[nt], 16, 64);
        qAcc[nt] += __shfl_xor(qAcc[nt], 32, 64);
    }
    if (q == 0) {
#pragma unroll
        for (int nt = 0; nt < 8; ++nt) {
            atomicAdd(&sS[nt * 16 + lr], sAcc[nt]);
            atomicAdd(&sQ[nt * 16 + lr], qAcc[nt]);
        }
    }
    __syncthreads();
    {
        float pv = (t < 128) ? sS[t] : sQ[t - 128];
        spart2[(size_t)blockIdx.x * 256 + t] = pv;
    }
}

// ---------------- readout (segmented-parallel, replaces serial k_seg_batch) ------
// batch is sorted; detect graph boundaries -> gstart[Gg+1], then one block per
// graph sums its rows with 16 row-lanes x 16 v8bf col-groups (no atomics, no
// serial scan). k_seg_batch was 73us latency-bound (186 GB/s, serial 256-row
// loop); this is ~12 vectorized iters/graph.

__global__ void k_gbound(const int* __restrict__ batch, int* __restrict__ gstart) {
    int r = blockIdx.x * blockDim.x + threadIdx.x;
    if (r >= Nn) return;
    int b = batch[r];
    int prev = (r == 0) ? -1 : batch[r - 1];
    for (int g = prev + 1; g <= b; ++g) gstart[g] = r;
    if (r == Nn - 1) {
        for (int g = b + 1; g <= Gg; ++g) gstart[g] = Nn;
    }
}

__global__ __launch_bounds__(256) void k_seg_sum(
    const __bf16* __restrict__ x, const int* __restrict__ gstart,
    float* __restrict__ xgsum, float* __restrict__ gcnt)
{
    __shared__ float s[16][128];
    int g = blockIdx.x;
    int t = threadIdx.x;
    int rp = t >> 4;            // 16 row-lanes
    int h0 = (t & 15) * 8;      // 16 col-groups of 8
    int r0 = gstart[g], r1 = gstart[g + 1];
    float acc[8];
#pragma unroll
    for (int i = 0; i < 8; ++i) acc[i] = 0.f;
    for (int r = r0 + rp; r < r1; r += 16) {
        v8bf v = *(const v8bf*)&x[(size_t)r * H + h0];
#pragma unroll
        for (int i = 0; i < 8; ++i) acc[i] += (float)v[i];
    }
#pragma unroll
    for (int i = 0; i < 8; ++i) s[rp][h0 + i] = acc[i];
    __syncthreads();
    if (rp == 0) {
#pragma unroll
        for (int i = 0; i < 8; ++i) {
            float v = 0.f;
#pragma unroll
            for (int j = 0; j < 16; ++j) v += s[j][h0 + i];
            xgsum[(size_t)g * H + h0 + i] = v;
        }
    }
    if (t == 0) gcnt[g] = (float)(r1 - r0);
}

__global__ void k_head(const float* __restrict__ xgsum, const float* __restrict__ gcnt,
                       const float* __restrict__ alw, const float* __restrict__ alb,
                       const float* __restrict__ lw, const float* __restrict__ lb,
                       float* __restrict__ out) {
    __shared__ float mean[H];
    __shared__ float red[H];
    int g = blockIdx.x, j = threadIdx.x;
    mean[j] = xgsum[g * H + j] / fmaxf(gcnt[g], 1.f);
    __syncthreads();
    float acc = alb[j];
    for (int k = 0; k < H; ++k) acc += mean[k] * alw[k * H + j];
    acc = fmaxf(acc, 0.f) * lw[j];
    red[j] = acc;
    __syncthreads();
    for (int s = 64; s > 0; s >>= 1) {
        if (j < s) red[j] += red[j + s];
        __syncthreads();
    }
    if (j == 0) out[g] = red[0] + lb[0];
}

// ---------------- host ----------------

extern "C" void kernel_launch(void* const* d_in, const int* in_sizes, int n_in,
                              void* d_out, int out_size, void* d_ws, size_t ws_size,
                              hipStream_t stream) {
    const int* x_atom = (const int*)d_in[0];
    const int* ei = (const int*)d_in[1];
    const int* eattr = (const int*)d_in[2];
    const int* batch = (const int*)d_in[3];
    const int* xc5 = (const int*)d_in[4];
    const int* xc6 = (const int*)d_in[5];
    const int* a2c5_row = (const int*)d_in[6];
    const int* a2c6_row = (const int*)d_in[8];
    const float* atom_emb = (const float*)d_in[10];
    const float* bond_emb = (const float*)d_in[11];
    const float* cyc5 = (const float*)d_in[12];
    const float* cyc6 = (const float*)d_in[13];
    const float* eps = (const float*)d_in[14];
    const float* gw1 = (const float*)d_in[15];
    const float* gb1 = (const float*)d_in[16];
    const float* gbn_g = (const float*)d_in[17];
    const float* gbn_b = (const float*)d_in[18];
    const float* gw2 = (const float*)d_in[19];
    const float* gb2 = (const float*)d_in[20];
    const float* bn_g = (const float*)d_in[21];
    const float* bn_b = (const float*)d_in[22];
    const float* a2c5_w = (const float*)d_in[23];
    const float* a2c5_b = (const float*)d_in[24];
    const float* a2c6_w = (const float*)d_in[25];
    const float* a2c6_b = (const float*)d_in[26];
    const float* c2a5_w = (const float*)d_in[27];
    const float* c2a5_b = (const float*)d_in[28];
    const float* c2a6_w = (const float*)d_in[29];
    const float* c2a6_b = (const float*)d_in[30];
    const float* p5_w = (const float*)d_in[31];
    const float* p5_b = (const float*)d_in[32];
    const float* p6_w = (const float*)d_in[33];
    const float* p6_b = (const float*)d_in[34];
    const float* alw = (const float*)d_in[35];
    const float* alb = (const float*)d_in[36];
    const float* lw = (const float*)d_in[37];
    const float* lb = (const float*)d_in[38];
    float* out = (float*)d_out;

    float* w = (float*)d_ws;
    size_t o = 0;
    auto alloc = [&](size_t nf) {
        float* p = w + o;
        o += (nf + 63) & ~(size_t)63;
        return p;
    };
    auto allocb = [&](size_t nbf) { return (__bf16*)alloc((nbf + 1) / 2); };
    const int TPB = 256;
    auto cdiv = [](int a, int b) { return (a + b - 1) / b; };
    int nblkA = cdiv(Nn, 64);
    int mchunks = cdiv(Nn, 256);

    __bf16* x = allocb((size_t)Nn * H);
    __bf16* x5 = allocb((size_t)N5c * 5 * H);
    __bf16* x6 = allocb((size_t)N6c * 6 * H);
    __bf16* agg = allocb((size_t)Nn * H);
    float* stats = alloc(512);
    float* stats2 = alloc(256);
    float* spart = alloc((size_t)nblkA * 512);
    float* xgsum = alloc((size_t)Gg * H);
    float* gcnt = alloc(Gg);
    float* rscale5 = alloc(Nn);
    float* rscale6 = alloc(Nn);
    int* deg = (int*)alloc(Nn);
    int* rowptr = (int*)alloc(Nn + 1);
    int* rp5c = (int*)alloc(Nn + 1);
    int* rp6c = (int*)alloc(Nn + 1);
    int* gstart = (int*)alloc(Gg + 1);
    int* woff = (int*)alloc(Nn);
    int* bsum = (int*)alloc(256);
    int* boff = (int*)alloc(256);
    unsigned int* elist = (unsigned int*)alloc(Ee);
    int* cidx5 = (int*)alloc(N5c * 5);
    int* cidx6 = (int*)alloc(N6c * 6);
    float* ebank = alloc(512 * H);
    __bf16* g1h = allocb(3 * 128 * 256);
    __bf16* g2h = allocb(3 * 256 * 128);
    __bf16* a5h = allocb(3 * 128 * 128);
    __bf16* a6h = allocb(3 * 128 * 128);
    __bf16* c5h = allocb(3 * 128 * 128);
    __bf16* c6h = allocb(3 * 128 * 128);
    __bf16* p5h = allocb(3 * 384 * 128);
    __bf16* p6h = allocb(3 * 384 * 128);

    int nsb = cdiv(Nn, 1024);

    // weight pre-split (transposed bf16 planes)
    k_split<<<cdiv(3 * 128 * 256, TPB), TPB, 0, stream>>>(gw1, g1h, 3, 128, 256);
    k_split<<<cdiv(3 * 256 * 128, TPB), TPB, 0, stream>>>(gw2, g2h, 3, 256, 128);
    k_split<<<cdiv(3 * 128 * 128, TPB), TPB, 0, stream>>>(a2c5_w, a5h, 3, 128, 128);
    k_split<<<cdiv(3 * 128 * 128, TPB), TPB, 0, stream>>>(a2c6_w, a6h, 3, 128, 128);
    k_split<<<cdiv(3 * 128 * 128, TPB), TPB, 0, stream>>>(c2a5_w, c5h, 3, 128, 128);
    k_split<<<cdiv(3 * 128 * 128, TPB), TPB, 0, stream>>>(c2a6_w, c6h, 3, 128, 128);
    k_split<<<cdiv(3 * 384 * 128, TPB), TPB, 0, stream>>>(p5_w, p5h, 3, 384, 128);
    k_split<<<cdiv(3 * 384 * 128, TPB), TPB, 0, stream>>>(p6_w, p6h, 3, 384, 128);

    // edge CSR
    hipMemsetAsync(deg, 0, Nn * 4, stream);
    k_degi<<<cdiv(Ee, TPB), TPB, 0, stream>>>(ei + Ee, deg, Ee);
    k_scan1<<<nsb, 256, 0, stream>>>(deg, rowptr, bsum, Nn);
    k_scan2<<<1, 128, 0, stream>>>(bsum, boff, rowptr, nsb, Nn);
    k_scan3<<<cdiv(Nn, TPB), TPB, 0, stream>>>(rowptr, boff, Nn);
    hipMemcpyAsync(woff, rowptr, Nn * 4, hipMemcpyDeviceToDevice, stream);
    k_fill<<<cdiv(Ee, TPB), TPB, 0, stream>>>(ei, eattr, woff, elist);

    // cycle->atom CSRs + mean scales
    hipMemsetAsync(deg, 0, Nn * 4, stream);
    k_degi<<<cdiv(N5c * 5, TPB), TPB, 0, stream>>>(a2c5_row, deg, N5c * 5);
    k_scan1<<<nsb, 256, 0, stream>>>(deg, rp5c, bsum, Nn);
    k_scan2<<<1, 128, 0, stream>>>(bsum, boff, rp5c, nsb, Nn);
    k_scan3<<<cdiv(Nn, TPB), TPB, 0, stream>>>(rp5c, boff, Nn);
    k_inv_int<<<cdiv(Nn, TPB), TPB, 0, stream>>>(deg, rscale5);
    hipMemcpyAsync(woff, rp5c, Nn * 4, hipMemcpyDeviceToDevice, stream);
    k_fill_idx<<<cdiv(N5c * 5, TPB), TPB, 0, stream>>>(a2c5_row, woff, cidx5, N5c * 5);

    hipMemsetAsync(deg, 0, Nn * 4, stream);
    k_degi<<<cdiv(N6c * 6, TPB), TPB, 0, stream>>>(a2c6_row, deg, N6c * 6);
    k_scan1<<<nsb, 256, 0, stream>>>(deg, rp6c, bsum, Nn);
    k_scan2<<<1, 128, 0, stream>>>(bsum, boff, rp6c, nsb, Nn);
    k_scan3<<<cdiv(Nn, TPB), TPB, 0, stream>>>(rp6c, boff, Nn);
    k_inv_int<<<cdiv(Nn, TPB), TPB, 0, stream>>>(deg, rscale6);
    hipMemcpyAsync(woff, rp6c, Nn * 4, hipMemcpyDeviceToDevice, stream);
    k_fill_idx<<<cdiv(N6c * 6, TPB), TPB, 0, stream>>>(a2c6_row, woff, cidx6, N6c * 6);

    // graph boundaries for readout
    k_gbound<<<cdiv(Nn, TPB), TPB, 0, stream>>>(batch, gstart);

    k_atom_enc<<<cdiv(Nn * H, TPB), TPB, 0, stream>>>(x_atom, atom_emb, x);
    k_cyc_init<<<cdiv(N5c * 5 * H, TPB), TPB, 0, stream>>>(xc5, cyc5, x5, N5c * 5);
    k_cyc_init<<<cdiv(N6c * 6 * H, TPB), TPB, 0, stream>>>(xc6, cyc6, x6, N6c * 6);

    const int GS = 512;   // grid-stride block count for gemm128
    const int GF = 256;   // 1 block/CU kernels (big-LDS)
    for (int i = 0; i < Ll; ++i) {
        // GINE aggregation (gather) -> agg
        k_ebank<<<cdiv(512 * H, TPB), TPB, 0, stream>>>(
            bond_emb + (size_t)i * BF * BV * H, ebank);
        k_agg_csr<<<Nn / 2, 256, 0, stream>>>(x, rowptr, elist, ebank, eps, i, agg);

        // MLP pass A: BN1 stats (barrier-free; partials -> reduce)
        hipMemsetAsync(stats, 0, 512 * 4, stream);
        k_mlp_statsA<<<mchunks * 2, 256, 0, stream>>>(
            agg, g1h + (size_t)i * 128 * 256, gb1 + (size_t)i * 256, spart, Nn);
        k_red<<<dim3(8, 8), 256, 0, stream>>>(spart, stats, 512, mchunks);

        // MLP fused pass B v3 (LDS-resident weights) -> x_raw + BN2 partials
        hipMemsetAsync(stats2, 0, 256 * 4, stream);
        k_mlp_fused<<<GF, 256, 0, stream>>>(
            agg, g1h + (size_t)i * 128 * 256, gb1 + (size_t)i * 256, stats,
            gbn_g + (size_t)i * 256, gbn_b + (size_t)i * 256,
            g2h + (size_t)i * 256 * 128, gb2 + (size_t)i * H, x, spart,
            Nn, nblkA);
        k_red<<<dim3(4, 8), 256, 0, stream>>>(spart, stats2, 256, GF);

        // atoms -> cycles (row-gather, BN2+relu folded on A, in-place residual)
        k_gemm128<1, false><<<GS, 256, 0, stream>>>(
            x, a5h + (size_t)i * 128 * 128, a2c5_b + (size_t)i * H,
            x5, x5, a2c5_row, nullptr, nullptr, nullptr,
            stats2, bn_g + (size_t)i * H, bn_b + (size_t)i * H,
            N5c * 5, cdiv(N5c * 5, 64));
        k_gemm128<1, false><<<GS, 256, 0, stream>>>(
            x, a6h + (size_t)i * 128 * 128, a2c6_b + (size_t)i * H,
            x6, x6, a2c6_row, nullptr, nullptr, nullptr,
            stats2, bn_g + (size_t)i * H, bn_b + (size_t)i * H,
            N6c * 6, cdiv(N6c * 6, 64));

        // cyclic path blocks v3: LDS-resident weights, 512-thread blocks
        k_path<5><<<GF, 512, 0, stream>>>(
            x5, p5h + (size_t)i * 384 * 128, p5_b + (size_t)i * H, x5,
            N5c * 5, cdiv(N5c * 5, 120));
        k_path<6><<<GF, 512, 0, stream>>>(
            x6, p6h + (size_t)i * 384 * 128, p6_b + (size_t)i * H, x6,
            N6c * 6, cdiv(N6c * 6, 120));

        // cycles -> atoms (CSR mean-gather; c2a5 folds BN2+relu on res side)
        k_gemm128<2, true><<<GS, 256, 0, stream>>>(
            x5, c5h + (size_t)i * 128 * 128, c2a5_b + (size_t)i * H,
            x, x, nullptr, rp5c, cidx5, rscale5,
            stats2, bn_g + (size_t)i * H, bn_b + (size_t)i * H,
            Nn, cdiv(Nn, 64));
        k_gemm128<0, true><<<GS, 256, 0, stream>>>(
            x6, c6h + (size_t)i * 128 * 128, c2a6_b + (size_t)i * H,
            x, x, nullptr, rp6c, cidx6, rscale6,
            nullptr, nullptr, nullptr, Nn, cdiv(Nn, 64));
    }

    // readout (segmented-parallel)
    k_seg_sum<<<Gg, 256, 0, stream>>>(x, gstart, xgsum, gcnt);
    k_head<<<Gg, H, 0, stream>>>(xgsum, gcnt, alw, alb, lw, lb, out);
}

// Round 11
// 1261.703 us; speedup vs baseline: 2.1689x; 1.1047x over previous
//
#include <hip/hip_runtime.h>

#define H 128
#define Nn 100000
#define Ee 250000
#define N5c 20000
#define N6c 30000
#define Gg 512
#define Ll 3
#define AF 9
#define AV 64
#define BF 3
#define BV 8
#define BN_EPS 1e-5f

typedef __bf16 v8bf __attribute__((ext_vector_type(8)));
typedef float v4f __attribute__((ext_vector_type(4)));

// ---------------- init / embedding kernels ----------------

__global__ void k_atom_enc(const int* __restrict__ xa, const float* __restrict__ emb,
                           __bf16* __restrict__ x) {
    int idx = blockIdx.x * blockDim.x + threadIdx.x;
    if (idx >= Nn * H) return;
    int n = idx >> 7, h = idx & 127;
    float s = 0.f;
#pragma unroll
    for (int f = 0; f < AF; ++f) {
        int a = xa[n * AF + f];
        s += emb[(f * AV + a) * H + h];
    }
    x[idx] = (__bf16)s;
}

__global__ void k_cyc_init(const int* __restrict__ xc, const float* __restrict__ emb,
                           __bf16* __restrict__ xo, int M) {
    int idx = blockIdx.x * blockDim.x + threadIdx.x;
    if (idx >= M * H) return;
    int m = idx >> 7, h = idx & 127;
    xo[idx] = (__bf16)emb[xc[m] * H + h];
}

// weight pre-split: (L,K,N) fp32 row-major -> per-layer transposed [n][k] bf16
__global__ void k_split(const float* __restrict__ src, __bf16* __restrict__ dh,
                        int L, int K, int N) {
    int idx = blockIdx.x * blockDim.x + threadIdx.x;
    int tot = L * K * N;
    if (idx >= tot) return;
    int l = idx / (K * N);
    int r = idx - l * (K * N);
    int k = r / N;
    int n = r - k * N;
    size_t d = (size_t)l * K * N + (size_t)n * K + k;
    dh[d] = (__bf16)src[idx];
}

// ---------------- CSR build helpers ----------------

__global__ void k_degi(const int* __restrict__ row, int* __restrict__ deg, int M) {
    int m = blockIdx.x * blockDim.x + threadIdx.x;
    if (m >= M) return;
    atomicAdd(&deg[row[m]], 1);
}

__global__ void k_scan1(const int* __restrict__ deg, int* __restrict__ rp,
                        int* __restrict__ bsum, int n) {
    __shared__ int s[256];
    int tid = threadIdx.x;
    int base = blockIdx.x * 1024 + tid * 4;
    int v0 = (base < n) ? deg[base] : 0;
    int v1 = (base + 1 < n) ? deg[base + 1] : 0;
    int v2 = (base + 2 < n) ? deg[base + 2] : 0;
    int v3 = (base + 3 < n) ? deg[base + 3] : 0;
    int tsum = v0 + v1 + v2 + v3;
    s[tid] = tsum;
    __syncthreads();
    for (int off = 1; off < 256; off <<= 1) {
        int u = (tid >= off) ? s[tid - off] : 0;
        __syncthreads();
        s[tid] += u;
        __syncthreads();
    }
    int exc = s[tid] - tsum;
    if (base < n) rp[base] = exc;
    if (base + 1 < n) rp[base + 1] = exc + v0;
    if (base + 2 < n) rp[base + 2] = exc + v0 + v1;
    if (base + 3 < n) rp[base + 3] = exc + v0 + v1 + v2;
    if (tid == 255) bsum[blockIdx.x] = s[255];
}

__global__ void k_scan2(const int* __restrict__ bsum, int* __restrict__ boff,
                        int* __restrict__ rp, int nb, int n) {
    __shared__ int s[128];
    int tid = threadIdx.x;
    int v = (tid < nb) ? bsum[tid] : 0;
    s[tid] = v;
    __syncthreads();
    for (int off = 1; off < 128; off <<= 1) {
        int u = (tid >= off) ? s[tid - off] : 0;
        __syncthreads();
        s[tid] += u;
        __syncthreads();
    }
    if (tid < nb) boff[tid] = s[tid] - v;
    if (tid == 127) rp[n] = s[127];
}

__global__ void k_scan3(int* __restrict__ rp, const int* __restrict__ boff, int n) {
    int idx = blockIdx.x * blockDim.x + threadIdx.x;
    if (idx < n) rp[idx] += boff[idx >> 10];
}

__global__ void k_fill(const int* __restrict__ ei, const int* __restrict__ eattr,
                       int* __restrict__ woff, unsigned int* __restrict__ elist) {
    int e = blockIdx.x * blockDim.x + threadIdx.x;
    if (e >= Ee) return;
    int src = ei[e], dst = ei[Ee + e];
    int code = eattr[e * BF + 0] * 64 + eattr[e * BF + 1] * 8 + eattr[e * BF + 2];
    int p = atomicAdd(&woff[dst], 1);
    elist[p] = ((unsigned int)code << 17) | (unsigned int)src;
}

__global__ void k_fill_idx(const int* __restrict__ row, int* __restrict__ woff,
                           int* __restrict__ cidx, int M) {
    int m = blockIdx.x * blockDim.x + threadIdx.x;
    if (m >= M) return;
    int p = atomicAdd(&woff[row[m]], 1);
    cidx[p] = m;
}

__global__ void k_inv_int(const int* __restrict__ deg, float* __restrict__ rscale) {
    int r = blockIdx.x * blockDim.x + threadIdx.x;
    if (r >= Nn) return;
    rscale[r] = 1.f / fmaxf((float)deg[r], 1.f);
}

__global__ void k_ebank(const float* __restrict__ bemb, float* __restrict__ ebank) {
    int idx = blockIdx.x * blockDim.x + threadIdx.x;
    if (idx >= 512 * H) return;
    int code = idx >> 7, h = idx & 127;
    int f0 = code >> 6, f1 = (code >> 3) & 7, f2 = code & 7;
    ebank[idx] = bemb[(0 * BV + f0) * H + h] + bemb[(1 * BV + f1) * H + h]
               + bemb[(2 * BV + f2) * H + h];
}

// ---------------- GINE aggregation v2: 16 threads/atom, v8bf, unroll-2 ----------
// Old form (128 thr/atom, scalar 2B loads, serial edge chain) was MLP-bound at
// 1.09 TB/s. v2: wave covers 4 atoms (4 independent row-gathers per load inst),
// 16B/lane, edge loop unrolled x2 -> ~8x memory-level parallelism.

__global__ __launch_bounds__(256) void k_agg_csr(
    const __bf16* __restrict__ x, const int* __restrict__ rowptr,
    const unsigned int* __restrict__ elist, const float* __restrict__ ebank,
    const float* __restrict__ eps, int layer, __bf16* __restrict__ agg)
{
    int t = threadIdx.x;
    int a = blockIdx.x * 16 + (t >> 4);
    if (a >= Nn) return;
    int h0 = (t & 15) * 8;

    float acc[8];
    {
        v8bf xs = *(const v8bf*)&x[(size_t)a * H + h0];
        float e = 1.f + eps[layer];
#pragma unroll
        for (int i = 0; i < 8; ++i) acc[i] = e * (float)xs[i];
    }
    int j0 = rowptr[a], j1 = rowptr[a + 1];
    int j = j0;
    for (; j + 1 < j1; j += 2) {
        unsigned u0 = elist[j], u1 = elist[j + 1];
        int s0 = u0 & 0x1FFFF, c0 = u0 >> 17;
        int s1 = u1 & 0x1FFFF, c1 = u1 >> 17;
        v8bf x0 = *(const v8bf*)&x[(size_t)s0 * H + h0];
        v8bf x1 = *(const v8bf*)&x[(size_t)s1 * H + h0];
        v4f e0a = *(const v4f*)&ebank[c0 * H + h0];
        v4f e0b = *(const v4f*)&ebank[c0 * H + h0 + 4];
        v4f e1a = *(const v4f*)&ebank[c1 * H + h0];
        v4f e1b = *(const v4f*)&ebank[c1 * H + h0 + 4];
#pragma unroll
        for (int i = 0; i < 4; ++i) {
            acc[i]     += fmaxf((float)x0[i]     + e0a[i], 0.f)
                        + fmaxf((float)x1[i]     + e1a[i], 0.f);
            acc[i + 4] += fmaxf((float)x0[i + 4] + e0b[i], 0.f)
                        + fmaxf((float)x1[i + 4] + e1b[i], 0.f);
        }
    }
    if (j < j1) {
        unsigned u = elist[j];
        int s = u & 0x1FFFF, c = u >> 17;
        v8bf xr = *(const v8bf*)&x[(size_t)s * H + h0];
        v4f ea = *(const v4f*)&ebank[c * H + h0];
        v4f eb = *(const v4f*)&ebank[c * H + h0 + 4];
#pragma unroll
        for (int i = 0; i < 4; ++i) {
            acc[i]     += fmaxf((float)xr[i]     + ea[i], 0.f);
            acc[i + 4] += fmaxf((float)xr[i + 4] + eb[i], 0.f);
        }
    }
    v8bf o;
#pragma unroll
    for (int i = 0; i < 8; ++i) o[i] = (__bf16)acc[i];
    *(v8bf*)&agg[(size_t)a * H + h0] = o;
}

// ---------------- cross-block stats reduction ----------------

__global__ __launch_bounds__(256) void k_red(const float* __restrict__ part,
                                             float* __restrict__ out,
                                             int width, int nb)
{
    __shared__ float s[256];
    int t = threadIdx.x;
    int col = blockIdx.x * 64 + (t & 63);
    int pl = t >> 6;
    float acc = 0.f;
    for (int p = blockIdx.y * 4 + pl; p < nb; p += 32)
        acc += part[(size_t)p * width + col];
    s[t] = acc;
    __syncthreads();
    if (pl == 0) {
        float v = s[t] + s[t + 64] + s[t + 128] + s[t + 192];
        atomicAdd(&out[col], v);
    }
}

// ---------------- K=128 GEMM v3: B in regs once, GRID-STRIDE over 64-row tiles ----

template <int BNMODE, bool GRP>
__global__ __launch_bounds__(256) void k_gemm128(
    const __bf16* __restrict__ A, const __bf16* __restrict__ Bth,
    const float* __restrict__ bias, const __bf16* __restrict__ res,
    __bf16* __restrict__ out, const int* __restrict__ rowidx,
    const int* __restrict__ grp, const int* __restrict__ gcol,
    const float* __restrict__ gscale,
    const float* __restrict__ bnstats, const float* __restrict__ bng,
    const float* __restrict__ bnb, int M, int ntiles)
{
    __shared__ __bf16 Ct[64 * 136];
    __shared__ float scB[128], shB[128];

    int t = threadIdx.x;
    int lane = t & 63, q = lane >> 4, lr = lane & 15;
    int w = t >> 6;

    if (BNMODE && t < 128) {
        float mean = bnstats[t] * (1.f / (float)Nn);
        float var = bnstats[128 + t] * (1.f / (float)Nn) - mean * mean;
        float s = bng[t] * rsqrtf(var + BN_EPS);
        scB[t] = s;
        shB[t] = bnb[t] - mean * s;
    }
    if (BNMODE) __syncthreads();

    v8bf bf[8][4];
#pragma unroll
    for (int nt = 0; nt < 8; ++nt) {
        const __bf16* bp = Bth + (size_t)(nt * 16 + lr) * 128 + q * 8;
#pragma unroll
        for (int kt = 0; kt < 4; ++kt)
            bf[nt][kt] = *(const v8bf*)(bp + kt * 32);
    }
    float bcol[8];
#pragma unroll
    for (int nt = 0; nt < 8; ++nt) bcol[nt] = bias[nt * 16 + lr];

    for (int tile = blockIdx.x; tile < ntiles; tile += gridDim.x) {
        int m0 = tile * 64;
        int gm = m0 + w * 16 + lr;
        bool rvalid = (gm < M);

        v8bf af[4];
        if (GRP) {
            float a8[4][8];
#pragma unroll
            for (int kt = 0; kt < 4; ++kt)
#pragma unroll
                for (int i = 0; i < 8; ++i) a8[kt][i] = 0.f;
            float sc = 1.f;
            if (rvalid) {
                int j0 = grp[gm], j1 = grp[gm + 1];
                sc = gscale[gm];
                for (int j = j0; j < j1; ++j) {
                    const __bf16* rp2 = A + (size_t)gcol[j] * H;
#pragma unroll
                    for (int kt = 0; kt < 4; ++kt) {
                        v8bf g = *(const v8bf*)(rp2 + kt * 32 + q * 8);
#pragma unroll
                        for (int i = 0; i < 8; ++i) a8[kt][i] += (float)g[i];
                    }
                }
            }
#pragma unroll
            for (int kt = 0; kt < 4; ++kt)
#pragma unroll
                for (int i = 0; i < 8; ++i) af[kt][i] = (__bf16)(a8[kt][i] * sc);
        } else {
            const __bf16* base = A;
            if (rvalid) base = rowidx ? A + (size_t)rowidx[gm] * H : A + (size_t)gm * H;
#pragma unroll
            for (int kt = 0; kt < 4; ++kt) {
                v8bf hv = {};
                if (rvalid) hv = *(const v8bf*)(base + kt * 32 + q * 8);
                af[kt] = hv;
            }
        }
        if (BNMODE == 1) {
            if (rvalid) {
#pragma unroll
                for (int kt = 0; kt < 4; ++kt) {
                    int kb = kt * 32 + q * 8;
#pragma unroll
                    for (int i = 0; i < 8; ++i)
                        af[kt][i] =
                            (__bf16)fmaxf((float)af[kt][i] * scB[kb + i] + shB[kb + i], 0.f);
                }
            }
        }

        v4f acc[8] = {};
#pragma unroll
        for (int kt = 0; kt < 4; ++kt)
#pragma unroll
            for (int nt = 0; nt < 8; ++nt)
                acc[nt] = __builtin_amdgcn_mfma_f32_16x16x32_bf16(
                    af[kt], bf[nt][kt], acc[nt], 0, 0, 0);

#pragma unroll
        for (int nt = 0; nt < 8; ++nt)
#pragma unroll
            for (int reg = 0; reg < 4; ++reg) {
                int row = w * 16 + q * 4 + reg;
                float v = fmaxf(acc[nt][reg] + bcol[nt], 0.f);
                Ct[row * 136 + nt * 16 + lr] = (__bf16)v;
            }
        {
            int row = t >> 2;
            int c0 = (t & 3) * 32;
            int rm = m0 + row;
            if (rm < M) {
#pragma unroll
                for (int seg = 0; seg < 4; ++seg) {
                    int cc = c0 + seg * 8;
                    v8bf cv = *(v8bf*)&Ct[row * 136 + cc];
                    v8bf rv2 = *(const v8bf*)&res[(size_t)rm * H + cc];
#pragma unroll
                    for (int i = 0; i < 8; ++i) {
                        float rf = (float)rv2[i];
                        if (BNMODE == 2)
                            rf = fmaxf(rf * scB[cc + i] + shB[cc + i], 0.f);
                        cv[i] = (__bf16)((float)cv[i] + rf);
                    }
                    *(v8bf*)&out[(size_t)rm * H + cc] = cv;
                }
            }
        }
    }
}

// ---------------- cyclic path block v3: LDS-resident weights ----------------

template <int PK>
__global__ __launch_bounds__(512, 1) void k_path(
    const __bf16* __restrict__ X, const __bf16* __restrict__ Bth,
    const float* __restrict__ bias, __bf16* __restrict__ Xout,
    int M, int nchunks)
{
    __shared__ __bf16 Bs[128][392];   // 100.4 KB (pad 8 cols: 4-bank row shift)
    __shared__ __bf16 Ct[128 * 136];  // 34.8 KB
    int t = threadIdx.x;
    int lane = t & 63, q = lane >> 4, lr = lane & 15;
    int w = t >> 6;        // 0..7
    int mt = w >> 2;       // 0 or 1
    int wm = w & 3;        // wave within mt half

    // stage B: thread t stages row t>>2, col-quarter (t&3)*96 (12 v8bf)
    {
        int r = t >> 2, c0 = (t & 3) * 96;
        const __bf16* src = Bth + (size_t)r * 384 + c0;
#pragma unroll
        for (int j = 0; j < 12; ++j)
            *(v8bf*)&Bs[r][c0 + j * 8] = *(const v8bf*)(src + j * 8);
    }
    float bcol[8];
#pragma unroll
    for (int nt = 0; nt < 8; ++nt) bcol[nt] = bias[nt * 16 + lr];
    __syncthreads();  // Bs ready

    for (int ch = blockIdx.x; ch < nchunks; ch += gridDim.x) {
        int tb = ch * 120;
        int rloc = wm * 16 + lr;
        int gm = tb + mt * 60 + rloc;
        bool rv = (rloc < 60) && (gm < M);
        v4f acc[8] = {};
#pragma unroll
        for (int p = 0; p < 3; ++p) {
            v8bf af[4];
#pragma unroll
            for (int kt = 0; kt < 4; ++kt) af[kt] = v8bf{};
            if (rv) {
                int pm = gm % PK;
                int pp = pm + p - 1;
                if (pp < 0) pp += PK;
                if (pp >= PK) pp -= PK;
                const __bf16* ap = X + (size_t)(gm - pm + pp) * H + q * 8;
#pragma unroll
                for (int kt = 0; kt < 4; ++kt)
                    af[kt] = *(const v8bf*)(ap + kt * 32);
            }
#pragma unroll
            for (int nt = 0; nt < 8; ++nt)
#pragma unroll
                for (int kt = 0; kt < 4; ++kt) {
                    v8bf bh = *(v8bf*)&Bs[nt * 16 + lr][p * 128 + kt * 32 + q * 8];
                    acc[nt] = __builtin_amdgcn_mfma_f32_16x16x32_bf16(
                        af[kt], bh, acc[nt], 0, 0, 0);
                }
        }
        // all rolled A reads (which cross wave row-boundaries) must complete
        // before the in-place residual+write below
        __syncthreads();
#pragma unroll
        for (int nt = 0; nt < 8; ++nt)
#pragma unroll
            for (int reg = 0; reg < 4; ++reg) {
                int row = w * 16 + q * 4 + reg;   // 0..127, wave-local
                float v = fmaxf(acc[nt][reg] + bcol[nt], 0.f);
                Ct[row * 136 + nt * 16 + lr] = (__bf16)v;
            }
        {
            int row = t >> 2;                    // 0..127, same wave's rows
            int c0 = (t & 3) * 32;
            int rmloc = row & 63;
            int rm = tb + (row >> 6) * 60 + rmloc;
            if (rmloc < 60 && rm < M) {
#pragma unroll
                for (int seg = 0; seg < 4; ++seg) {
                    int cc = c0 + seg * 8;
                    v8bf cv = *(v8bf*)&Ct[row * 136 + cc];
                    v8bf rv2 = *(const v8bf*)&X[(size_t)rm * H + cc];
#pragma unroll
                    for (int i = 0; i < 8; ++i)
                        cv[i] = (__bf16)((float)cv[i] + (float)rv2[i]);
                    *(v8bf*)&Xout[(size_t)rm * H + cc] = cv;
                }
            }
        }
    }
}

// ---------------- MLP pass A: BN1 column stats only ----------------

__global__ __launch_bounds__(256) void k_mlp_statsA(
    const __bf16* __restrict__ agg, const __bf16* __restrict__ g1h,
    const float* __restrict__ gb1, float* __restrict__ spart, int M)
{
    __shared__ float sS[128], sQ[128];
    int t = threadIdx.x;
    int mc = blockIdx.x >> 1, p = blockIdx.x & 1;
    int lane = t & 63, q = lane >> 4, lr = lane & 15;
    int w = t >> 6;
    if (t < 128) { sS[t] = 0.f; sQ[t] = 0.f; }

    v8bf bf[8][4];
#pragma unroll
    for (int nt = 0; nt < 8; ++nt) {
        const __bf16* bp = g1h + (size_t)(p * 128 + nt * 16 + lr) * 128 + q * 8;
#pragma unroll
        for (int kt = 0; kt < 4; ++kt)
            bf[nt][kt] = *(const v8bf*)(bp + kt * 32);
    }
    float bv[8];
#pragma unroll
    for (int nt = 0; nt < 8; ++nt) bv[nt] = gb1[p * 128 + nt * 16 + lr];

    float sAcc[8], qAcc[8];
#pragma unroll
    for (int nt = 0; nt < 8; ++nt) { sAcc[nt] = 0.f; qAcc[nt] = 0.f; }

#pragma unroll
    for (int mt = 0; mt < 4; ++mt) {
        int rb = mc * 256 + mt * 64 + w * 16;
        int gm = rb + lr;
        bool rv = (gm < M);
        v8bf af[4];
#pragma unroll
        for (int kt = 0; kt < 4; ++kt) {
            v8bf hv = {};
            if (rv) hv = *(const v8bf*)(agg + (size_t)gm * H + kt * 32 + q * 8);
            af[kt] = hv;
        }
        v4f acc[8] = {};
#pragma unroll
        for (int kt = 0; kt < 4; ++kt)
#pragma unroll
            for (int nt = 0; nt < 8; ++nt)
                acc[nt] = __builtin_amdgcn_mfma_f32_16x16x32_bf16(
                    af[kt], bf[nt][kt], acc[nt], 0, 0, 0);
#pragma unroll
        for (int nt = 0; nt < 8; ++nt) {
            float s = 0.f, q2 = 0.f;
#pragma unroll
            for (int reg = 0; reg < 4; ++reg) {
                int rm = rb + q * 4 + reg;
                if (rm < M) {
                    float v = acc[nt][reg] + bv[nt];
                    s += v;
                    q2 += v * v;
                }
            }
            sAcc[nt] += s;
            qAcc[nt] += q2;
        }
    }
#pragma unroll
    for (int nt = 0; nt < 8; ++nt) {
        sAcc[nt] += __shfl_xor(sAcc[nt], 16, 64);
        sAcc[nt] += __shfl_xor(sAcc[nt], 32, 64);
        qAcc[nt] += __shfl_xor(qAcc[nt], 16, 64);
        qAcc[nt] += __shfl_xor(qAcc[nt], 32, 64);
    }
    __syncthreads();
    if (q == 0) {
#pragma unroll
        for (int nt = 0; nt < 8; ++nt) {
            atomicAdd(&sS[nt * 16 + lr], sAcc[nt]);
            atomicAdd(&sQ[nt * 16 + lr], qAcc[nt]);
        }
    }
    __syncthreads();
    if (t < 128) {
        spart[(size_t)mc * 512 + p * 128 + t] = sS[t];
        spart[(size_t)mc * 512 + 256 + p * 128 + t] = sQ[t];
    }
}

// ---------------- MLP fused pass B v3: LDS-resident weights, grid-stride ---------

__global__ __launch_bounds__(256, 1) void k_mlp_fused(
    const __bf16* __restrict__ agg, const __bf16* __restrict__ g1h,
    const float* __restrict__ gb1, const float* __restrict__ statsIn,
    const float* __restrict__ gbn_g, const float* __restrict__ gbn_b,
    const __bf16* __restrict__ g2h, const float* __restrict__ gb2,
    __bf16* __restrict__ outx, float* __restrict__ spart2, int M, int ntiles)
{
    __shared__ __bf16 B1s[256][136];   // 69.6 KB
    __shared__ __bf16 B2s[128][264];   // 67.6 KB
    __shared__ __bf16 Tt[64 * 136];    // 17.4 KB (h1 panel / C transpose)
    __shared__ float scS[256], shS[256];
    __shared__ float sS[128], sQ[128];

    int t = threadIdx.x;
    int lane = t & 63, q = lane >> 4, lr = lane & 15;
    int w = t >> 6;

    {
        float mean = statsIn[t] * (1.f / (float)Nn);
        float var = statsIn[256 + t] * (1.f / (float)Nn) - mean * mean;
        float s = gbn_g[t] * rsqrtf(var + BN_EPS);
        scS[t] = s;
        shS[t] = (gb1[t] - mean) * s + gbn_b[t];
    }
    if (t < 128) { sS[t] = 0.f; sQ[t] = 0.f; }

    {
        const __bf16* src = g1h + (size_t)t * 128;
#pragma unroll
        for (int j = 0; j < 16; ++j)
            *(v8bf*)&B1s[t][j * 8] = *(const v8bf*)(src + j * 8);
    }
    {
        int r = t >> 1, h0 = (t & 1) * 128;
        const __bf16* src = g2h + (size_t)r * 256 + h0;
#pragma unroll
        for (int j = 0; j < 16; ++j)
            *(v8bf*)&B2s[r][h0 + j * 8] = *(const v8bf*)(src + j * 8);
    }
    __syncthreads();  // B1s/B2s/scS/shS/sS/sQ ready

    float bc2[8];
#pragma unroll
    for (int nt = 0; nt < 8; ++nt) bc2[nt] = gb2[nt * 16 + lr];

    float sAcc[8], qAcc[8];
#pragma unroll
    for (int nt = 0; nt < 8; ++nt) { sAcc[nt] = 0.f; qAcc[nt] = 0.f; }

    for (int tile = blockIdx.x; tile < ntiles; tile += gridDim.x) {
        int m0 = tile * 64;
        int gm = m0 + w * 16 + lr;
        bool rv = (gm < M);
        v8bf af[4];
#pragma unroll
        for (int kt = 0; kt < 4; ++kt) {
            v8bf hv = {};
            if (rv) hv = *(const v8bf*)(agg + (size_t)gm * H + kt * 32 + q * 8);
            af[kt] = hv;
        }

        v4f acc2[8] = {};
#pragma unroll
        for (int p = 0; p < 2; ++p) {
            v4f acc1[8] = {};
#pragma unroll
            for (int kt = 0; kt < 4; ++kt)
#pragma unroll
                for (int nt = 0; nt < 8; ++nt) {
                    v8bf bh = *(v8bf*)&B1s[p * 128 + nt * 16 + lr][kt * 32 + q * 8];
                    acc1[nt] = __builtin_amdgcn_mfma_f32_16x16x32_bf16(
                        af[kt], bh, acc1[nt], 0, 0, 0);
                }
#pragma unroll
            for (int nt = 0; nt < 8; ++nt)
#pragma unroll
                for (int reg = 0; reg < 4; ++reg) {
                    int row = w * 16 + q * 4 + reg;
                    int col = p * 128 + nt * 16 + lr;
                    float v = fmaxf(acc1[nt][reg] * scS[col] + shS[col], 0.f);
                    Tt[row * 136 + nt * 16 + lr] = (__bf16)v;
                }
            v8bf a2[4];
#pragma unroll
            for (int kt = 0; kt < 4; ++kt)
                a2[kt] = *(v8bf*)&Tt[(w * 16 + lr) * 136 + kt * 32 + q * 8];
#pragma unroll
            for (int kt = 0; kt < 4; ++kt)
#pragma unroll
                for (int nt = 0; nt < 8; ++nt) {
                    v8bf bh = *(v8bf*)&B2s[nt * 16 + lr][p * 128 + kt * 32 + q * 8];
                    acc2[nt] = __builtin_amdgcn_mfma_f32_16x16x32_bf16(
                        a2[kt], bh, acc2[nt], 0, 0, 0);
                }
        }

#pragma unroll
        for (int nt = 0; nt < 8; ++nt) {
#pragma unroll
            for (int reg = 0; reg < 4; ++reg) {
                int rm = m0 + w * 16 + q * 4 + reg;
                if (rm < M) {
                    float v = acc2[nt][reg] + bc2[nt];
                    sAcc[nt] += v;
                    qAcc[nt] += v * v;
                }
            }
        }
#pragma unroll
        for (int nt = 0; nt < 8; ++nt)
#pragma unroll
            for (int reg = 0; reg < 4; ++reg) {
                int row = w * 16 + q * 4 + reg;
                Tt[row * 136 + nt * 16 + lr] = (__bf16)(acc2[nt][reg] + bc2[nt]);
            }
        {
            int row = t >> 2;
            int c0 = (t & 3) * 32;
            int rm = m0 + row;
            if (rm < M) {
#pragma unroll
                for (int seg = 0; seg < 4; ++seg) {
                    int cc = c0 + seg * 8;
                    *(v8bf*)&outx[(size_t)rm * H + cc] = *(v8bf*)&Tt[row * 136 + cc];
                }
            }
        }
    }

#pragma unroll
    for (int nt = 0; nt < 8; ++nt) {
        sAcc[nt] += __shfl_xor(sAcc[nt], 16, 64);
        sAcc[nt] += __shfl_xor(sAcc[nt], 32, 64);
        qAcc[nt] += __shfl_xor(qAcc[nt], 16, 64);
        qAcc[nt] += __shfl_xor(qAcc[nt], 32, 64);
    }
    if (q == 0) {
#pragma unroll
        for (int nt = 0; nt < 8; ++nt) {
            atomicAdd(&sS[nt * 16 + lr], sAcc[nt]);
            atomicAdd(&sQ[nt * 16 + lr], qAcc[nt]);
        }
    }
    __syncthreads();
    {
        float pv = (t < 128) ? sS[t] : sQ[t - 128];
        spart2[(size_t)blockIdx.x * 256 + t] = pv;
    }
}

// ---------------- readout (segmented-parallel) ----------------

__global__ void k_gbound(const int* __restrict__ batch, int* __restrict__ gstart) {
    int r = blockIdx.x * blockDim.x + threadIdx.x;
    if (r >= Nn) return;
    int b = batch[r];
    int prev = (r == 0) ? -1 : batch[r - 1];
    for (int g = prev + 1; g <= b; ++g) gstart[g] = r;
    if (r == Nn - 1) {
        for (int g = b + 1; g <= Gg; ++g) gstart[g] = Nn;
    }
}

__global__ __launch_bounds__(256) void k_seg_sum(
    const __bf16* __restrict__ x, const int* __restrict__ gstart,
    float* __restrict__ xgsum, float* __restrict__ gcnt)
{
    __shared__ float s[16][128];
    int g = blockIdx.x;
    int t = threadIdx.x;
    int rp = t >> 4;            // 16 row-lanes
    int h0 = (t & 15) * 8;      // 16 col-groups of 8
    int r0 = gstart[g], r1 = gstart[g + 1];
    float acc[8];
#pragma unroll
    for (int i = 0; i < 8; ++i) acc[i] = 0.f;
    for (int r = r0 + rp; r < r1; r += 16) {
        v8bf v = *(const v8bf*)&x[(size_t)r * H + h0];
#pragma unroll
        for (int i = 0; i < 8; ++i) acc[i] += (float)v[i];
    }
#pragma unroll
    for (int i = 0; i < 8; ++i) s[rp][h0 + i] = acc[i];
    __syncthreads();
    if (rp == 0) {
#pragma unroll
        for (int i = 0; i < 8; ++i) {
            float v = 0.f;
#pragma unroll
            for (int j = 0; j < 16; ++j) v += s[j][h0 + i];
            xgsum[(size_t)g * H + h0 + i] = v;
        }
    }
    if (t == 0) gcnt[g] = (float)(r1 - r0);
}

__global__ void k_head(const float* __restrict__ xgsum, const float* __restrict__ gcnt,
                       const float* __restrict__ alw, const float* __restrict__ alb,
                       const float* __restrict__ lw, const float* __restrict__ lb,
                       float* __restrict__ out) {
    __shared__ float mean[H];
    __shared__ float red[H];
    int g = blockIdx.x, j = threadIdx.x;
    mean[j] = xgsum[g * H + j] / fmaxf(gcnt[g], 1.f);
    __syncthreads();
    float acc = alb[j];
    for (int k = 0; k < H; ++k) acc += mean[k] * alw[k * H + j];
    acc = fmaxf(acc, 0.f) * lw[j];
    red[j] = acc;
    __syncthreads();
    for (int s = 64; s > 0; s >>= 1) {
        if (j < s) red[j] += red[j + s];
        __syncthreads();
    }
    if (j == 0) out[g] = red[0] + lb[0];
}

// ---------------- host ----------------

extern "C" void kernel_launch(void* const* d_in, const int* in_sizes, int n_in,
                              void* d_out, int out_size, void* d_ws, size_t ws_size,
                              hipStream_t stream) {
    const int* x_atom = (const int*)d_in[0];
    const int* ei = (const int*)d_in[1];
    const int* eattr = (const int*)d_in[2];
    const int* batch = (const int*)d_in[3];
    const int* xc5 = (const int*)d_in[4];
    const int* xc6 = (const int*)d_in[5];
    const int* a2c5_row = (const int*)d_in[6];
    const int* a2c6_row = (const int*)d_in[8];
    const float* atom_emb = (const float*)d_in[10];
    const float* bond_emb = (const float*)d_in[11];
    const float* cyc5 = (const float*)d_in[12];
    const float* cyc6 = (const float*)d_in[13];
    const float* eps = (const float*)d_in[14];
    const float* gw1 = (const float*)d_in[15];
    const float* gb1 = (const float*)d_in[16];
    const float* gbn_g = (const float*)d_in[17];
    const float* gbn_b = (const float*)d_in[18];
    const float* gw2 = (const float*)d_in[19];
    const float* gb2 = (const float*)d_in[20];
    const float* bn_g = (const float*)d_in[21];
    const float* bn_b = (const float*)d_in[22];
    const float* a2c5_w = (const float*)d_in[23];
    const float* a2c5_b = (const float*)d_in[24];
    const float* a2c6_w = (const float*)d_in[25];
    const float* a2c6_b = (const float*)d_in[26];
    const float* c2a5_w = (const float*)d_in[27];
    const float* c2a5_b = (const float*)d_in[28];
    const float* c2a6_w = (const float*)d_in[29];
    const float* c2a6_b = (const float*)d_in[30];
    const float* p5_w = (const float*)d_in[31];
    const float* p5_b = (const float*)d_in[32];
    const float* p6_w = (const float*)d_in[33];
    const float* p6_b = (const float*)d_in[34];
    const float* alw = (const float*)d_in[35];
    const float* alb = (const float*)d_in[36];
    const float* lw = (const float*)d_in[37];
    const float* lb = (const float*)d_in[38];
    float* out = (float*)d_out;

    float* w = (float*)d_ws;
    size_t o = 0;
    auto alloc = [&](size_t nf) {
        float* p = w + o;
        o += (nf + 63) & ~(size_t)63;
        return p;
    };
    auto allocb = [&](size_t nbf) { return (__bf16*)alloc((nbf + 1) / 2); };
    const int TPB = 256;
    auto cdiv = [](int a, int b) { return (a + b - 1) / b; };
    int nblkA = cdiv(Nn, 64);
    int mchunks = cdiv(Nn, 256);

    __bf16* x = allocb((size_t)Nn * H);
    __bf16* x5 = allocb((size_t)N5c * 5 * H);
    __bf16* x6 = allocb((size_t)N6c * 6 * H);
    __bf16* agg = allocb((size_t)Nn * H);
    float* stats = alloc(512);
    float* stats2 = alloc(256);
    float* spart = alloc((size_t)nblkA * 512);
    float* xgsum = alloc((size_t)Gg * H);
    float* gcnt = alloc(Gg);
    float* rscale5 = alloc(Nn);
    float* rscale6 = alloc(Nn);
    int* deg = (int*)alloc(Nn);
    int* rowptr = (int*)alloc(Nn + 1);
    int* rp5c = (int*)alloc(Nn + 1);
    int* rp6c = (int*)alloc(Nn + 1);
    int* gstart = (int*)alloc(Gg + 1);
    int* woff = (int*)alloc(Nn);
    int* bsum = (int*)alloc(256);
    int* boff = (int*)alloc(256);
    unsigned int* elist = (unsigned int*)alloc(Ee);
    int* cidx5 = (int*)alloc(N5c * 5);
    int* cidx6 = (int*)alloc(N6c * 6);
    float* ebank = alloc(512 * H);
    __bf16* g1h = allocb(3 * 128 * 256);
    __bf16* g2h = allocb(3 * 256 * 128);
    __bf16* a5h = allocb(3 * 128 * 128);
    __bf16* a6h = allocb(3 * 128 * 128);
    __bf16* c5h = allocb(3 * 128 * 128);
    __bf16* c6h = allocb(3 * 128 * 128);
    __bf16* p5h = allocb(3 * 384 * 128);
    __bf16* p6h = allocb(3 * 384 * 128);

    int nsb = cdiv(Nn, 1024);

    // weight pre-split (transposed bf16 planes)
    k_split<<<cdiv(3 * 128 * 256, TPB), TPB, 0, stream>>>(gw1, g1h, 3, 128, 256);
    k_split<<<cdiv(3 * 256 * 128, TPB), TPB, 0, stream>>>(gw2, g2h, 3, 256, 128);
    k_split<<<cdiv(3 * 128 * 128, TPB), TPB, 0, stream>>>(a2c5_w, a5h, 3, 128, 128);
    k_split<<<cdiv(3 * 128 * 128, TPB), TPB, 0, stream>>>(a2c6_w, a6h, 3, 128, 128);
    k_split<<<cdiv(3 * 128 * 128, TPB), TPB, 0, stream>>>(c2a5_w, c5h, 3, 128, 128);
    k_split<<<cdiv(3 * 128 * 128, TPB), TPB, 0, stream>>>(c2a6_w, c6h, 3, 128, 128);
    k_split<<<cdiv(3 * 384 * 128, TPB), TPB, 0, stream>>>(p5_w, p5h, 3, 384, 128);
    k_split<<<cdiv(3 * 384 * 128, TPB), TPB, 0, stream>>>(p6_w, p6h, 3, 384, 128);

    // edge CSR
    hipMemsetAsync(deg, 0, Nn * 4, stream);
    k_degi<<<cdiv(Ee, TPB), TPB, 0, stream>>>(ei + Ee, deg, Ee);
    k_scan1<<<nsb, 256, 0, stream>>>(deg, rowptr, bsum, Nn);
    k_scan2<<<1, 128, 0, stream>>>(bsum, boff, rowptr, nsb, Nn);
    k_scan3<<<cdiv(Nn, TPB), TPB, 0, stream>>>(rowptr, boff, Nn);
    hipMemcpyAsync(woff, rowptr, Nn * 4, hipMemcpyDeviceToDevice, stream);
    k_fill<<<cdiv(Ee, TPB), TPB, 0, stream>>>(ei, eattr, woff, elist);

    // cycle->atom CSRs + mean scales
    hipMemsetAsync(deg, 0, Nn * 4, stream);
    k_degi<<<cdiv(N5c * 5, TPB), TPB, 0, stream>>>(a2c5_row, deg, N5c * 5);
    k_scan1<<<nsb, 256, 0, stream>>>(deg, rp5c, bsum, Nn);
    k_scan2<<<1, 128, 0, stream>>>(bsum, boff, rp5c, nsb, Nn);
    k_scan3<<<cdiv(Nn, TPB), TPB, 0, stream>>>(rp5c, boff, Nn);
    k_inv_int<<<cdiv(Nn, TPB), TPB, 0, stream>>>(deg, rscale5);
    hipMemcpyAsync(woff, rp5c, Nn * 4, hipMemcpyDeviceToDevice, stream);
    k_fill_idx<<<cdiv(N5c * 5, TPB), TPB, 0, stream>>>(a2c5_row, woff, cidx5, N5c * 5);

    hipMemsetAsync(deg, 0, Nn * 4, stream);
    k_degi<<<cdiv(N6c * 6, TPB), TPB, 0, stream>>>(a2c6_row, deg, N6c * 6);
    k_scan1<<<nsb, 256, 0, stream>>>(deg, rp6c, bsum, Nn);
    k_scan2<<<1, 128, 0, stream>>>(bsum, boff, rp6c, nsb, Nn);
    k_scan3<<<cdiv(Nn, TPB), TPB, 0, stream>>>(rp6c, boff, Nn);
    k_inv_int<<<cdiv(Nn, TPB), TPB, 0, stream>>>(deg, rscale6);
    hipMemcpyAsync(woff, rp6c, Nn * 4, hipMemcpyDeviceToDevice, stream);
    k_fill_idx<<<cdiv(N6c * 6, TPB), TPB, 0, stream>>>(a2c6_row, woff, cidx6, N6c * 6);

    // graph boundaries for readout
    k_gbound<<<cdiv(Nn, TPB), TPB, 0, stream>>>(batch, gstart);

    k_atom_enc<<<cdiv(Nn * H, TPB), TPB, 0, stream>>>(x_atom, atom_emb, x);
    k_cyc_init<<<cdiv(N5c * 5 * H, TPB), TPB, 0, stream>>>(xc5, cyc5, x5, N5c * 5);
    k_cyc_init<<<cdiv(N6c * 6 * H, TPB), TPB, 0, stream>>>(xc6, cyc6, x6, N6c * 6);

    const int GS = 512;   // grid-stride block count for gemm128
    const int GF = 256;   // 1 block/CU kernels (big-LDS)
    for (int i = 0; i < Ll; ++i) {
        // GINE aggregation v2 (16 thr/atom, v8bf, unroll-2) -> agg
        k_ebank<<<cdiv(512 * H, TPB), TPB, 0, stream>>>(
            bond_emb + (size_t)i * BF * BV * H, ebank);
        k_agg_csr<<<cdiv(Nn, 16), 256, 0, stream>>>(
            x, rowptr, elist, ebank, eps, i, agg);

        // MLP pass A: BN1 stats (barrier-free; partials -> reduce)
        hipMemsetAsync(stats, 0, 512 * 4, stream);
        k_mlp_statsA<<<mchunks * 2, 256, 0, stream>>>(
            agg, g1h + (size_t)i * 128 * 256, gb1 + (size_t)i * 256, spart, Nn);
        k_red<<<dim3(8, 8), 256, 0, stream>>>(spart, stats, 512, mchunks);

        // MLP fused pass B v3 (LDS-resident weights) -> x_raw + BN2 partials
        hipMemsetAsync(stats2, 0, 256 * 4, stream);
        k_mlp_fused<<<GF, 256, 0, stream>>>(
            agg, g1h + (size_t)i * 128 * 256, gb1 + (size_t)i * 256, stats,
            gbn_g + (size_t)i * 256, gbn_b + (size_t)i * 256,
            g2h + (size_t)i * 256 * 128, gb2 + (size_t)i * H, x, spart,
            Nn, nblkA);
        k_red<<<dim3(4, 8), 256, 0, stream>>>(spart, stats2, 256, GF);

        // atoms -> cycles (row-gather, BN2+relu folded on A, in-place residual)
        k_gemm128<1, false><<<GS, 256, 0, stream>>>(
            x, a5h + (size_t)i * 128 * 128, a2c5_b + (size_t)i * H,
            x5, x5, a2c5_row, nullptr, nullptr, nullptr,
            stats2, bn_g + (size_t)i * H, bn_b + (size_t)i * H,
            N5c * 5, cdiv(N5c * 5, 64));
        k_gemm128<1, false><<<GS, 256, 0, stream>>>(
            x, a6h + (size_t)i * 128 * 128, a2c6_b + (size_t)i * H,
            x6, x6, a2c6_row, nullptr, nullptr, nullptr,
            stats2, bn_g + (size_t)i * H, bn_b + (size_t)i * H,
            N6c * 6, cdiv(N6c * 6, 64));

        // cyclic path blocks v3: LDS-resident weights, 512-thread blocks
        k_path<5><<<GF, 512, 0, stream>>>(
            x5, p5h + (size_t)i * 384 * 128, p5_b + (size_t)i * H, x5,
            N5c * 5, cdiv(N5c * 5, 120));
        k_path<6><<<GF, 512, 0, stream>>>(
            x6, p6h + (size_t)i * 384 * 128, p6_b + (size_t)i * H, x6,
            N6c * 6, cdiv(N6c * 6, 120));

        // cycles -> atoms (CSR mean-gather; c2a5 folds BN2+relu on res side)
        k_gemm128<2, true><<<GS, 256, 0, stream>>>(
            x5, c5h + (size_t)i * 128 * 128, c2a5_b + (size_t)i * H,
            x, x, nullptr, rp5c, cidx5, rscale5,
            stats2, bn_g + (size_t)i * H, bn_b + (size_t)i * H,
            Nn, cdiv(Nn, 64));
        k_gemm128<0, true><<<GS, 256, 0, stream>>>(
            x6, c6h + (size_t)i * 128 * 128, c2a6_b + (size_t)i * H,
            x, x, nullptr, rp6c, cidx6, rscale6,
            nullptr, nullptr, nullptr, Nn, cdiv(Nn, 64));
    }

    // readout (segmented-parallel)
    k_seg_sum<<<Gg, 256, 0, stream>>>(x, gstart, xgsum, gcnt);
    k_head<<<Gg, H, 0, stream>>>(xgsum, gcnt, alw, alb, lw, lb, out);
}

// Round 12
// 1254.614 us; speedup vs baseline: 2.1811x; 1.0057x over previous
//
#include <hip/hip_runtime.h>

#define H 128
#define Nn 100000
#define Ee 250000
#define N5c 20000
#define N6c 30000
#define Gg 512
#define Ll 3
#define AF 9
#define AV 64
#define BF 3
#define BV 8
#define BN_EPS 1e-5f

typedef __bf16 v8bf __attribute__((ext_vector_type(8)));
typedef float v4f __attribute__((ext_vector_type(4)));

// ---------------- init / embedding kernels ----------------

__global__ void k_atom_enc(const int* __restrict__ xa, const float* __restrict__ emb,
                           __bf16* __restrict__ x) {
    int idx = blockIdx.x * blockDim.x + threadIdx.x;
    if (idx >= Nn * H) return;
    int n = idx >> 7, h = idx & 127;
    float s = 0.f;
#pragma unroll
    for (int f = 0; f < AF; ++f) {
        int a = xa[n * AF + f];
        s += emb[(f * AV + a) * H + h];
    }
    x[idx] = (__bf16)s;
}

__global__ void k_cyc_init(const int* __restrict__ xc, const float* __restrict__ emb,
                           __bf16* __restrict__ xo, int M) {
    int idx = blockIdx.x * blockDim.x + threadIdx.x;
    if (idx >= M * H) return;
    int m = idx >> 7, h = idx & 127;
    xo[idx] = (__bf16)emb[xc[m] * H + h];
}

// weight pre-split: (L,K,N) fp32 row-major -> per-layer transposed [n][k] bf16
__global__ void k_split(const float* __restrict__ src, __bf16* __restrict__ dh,
                        int L, int K, int N) {
    int idx = blockIdx.x * blockDim.x + threadIdx.x;
    int tot = L * K * N;
    if (idx >= tot) return;
    int l = idx / (K * N);
    int r = idx - l * (K * N);
    int k = r / N;
    int n = r - k * N;
    size_t d = (size_t)l * K * N + (size_t)n * K + k;
    dh[d] = (__bf16)src[idx];
}

// ---------------- CSR build helpers ----------------

__global__ void k_degi(const int* __restrict__ row, int* __restrict__ deg, int M) {
    int m = blockIdx.x * blockDim.x + threadIdx.x;
    if (m >= M) return;
    atomicAdd(&deg[row[m]], 1);
}

__global__ void k_scan1(const int* __restrict__ deg, int* __restrict__ rp,
                        int* __restrict__ bsum, int n) {
    __shared__ int s[256];
    int tid = threadIdx.x;
    int base = blockIdx.x * 1024 + tid * 4;
    int v0 = (base < n) ? deg[base] : 0;
    int v1 = (base + 1 < n) ? deg[base + 1] : 0;
    int v2 = (base + 2 < n) ? deg[base + 2] : 0;
    int v3 = (base + 3 < n) ? deg[base + 3] : 0;
    int tsum = v0 + v1 + v2 + v3;
    s[tid] = tsum;
    __syncthreads();
    for (int off = 1; off < 256; off <<= 1) {
        int u = (tid >= off) ? s[tid - off] : 0;
        __syncthreads();
        s[tid] += u;
        __syncthreads();
    }
    int exc = s[tid] - tsum;
    if (base < n) rp[base] = exc;
    if (base + 1 < n) rp[base + 1] = exc + v0;
    if (base + 2 < n) rp[base + 2] = exc + v0 + v1;
    if (base + 3 < n) rp[base + 3] = exc + v0 + v1 + v2;
    if (tid == 255) bsum[blockIdx.x] = s[255];
}

__global__ void k_scan2(const int* __restrict__ bsum, int* __restrict__ boff,
                        int* __restrict__ rp, int nb, int n) {
    __shared__ int s[128];
    int tid = threadIdx.x;
    int v = (tid < nb) ? bsum[tid] : 0;
    s[tid] = v;
    __syncthreads();
    for (int off = 1; off < 128; off <<= 1) {
        int u = (tid >= off) ? s[tid - off] : 0;
        __syncthreads();
        s[tid] += u;
        __syncthreads();
    }
    if (tid < nb) boff[tid] = s[tid] - v;
    if (tid == 127) rp[n] = s[127];
}

__global__ void k_scan3(int* __restrict__ rp, const int* __restrict__ boff, int n) {
    int idx = blockIdx.x * blockDim.x + threadIdx.x;
    if (idx < n) rp[idx] += boff[idx >> 10];
}

__global__ void k_fill(const int* __restrict__ ei, const int* __restrict__ eattr,
                       int* __restrict__ woff, unsigned int* __restrict__ elist) {
    int e = blockIdx.x * blockDim.x + threadIdx.x;
    if (e >= Ee) return;
    int src = ei[e], dst = ei[Ee + e];
    int code = eattr[e * BF + 0] * 64 + eattr[e * BF + 1] * 8 + eattr[e * BF + 2];
    int p = atomicAdd(&woff[dst], 1);
    elist[p] = ((unsigned int)code << 17) | (unsigned int)src;
}

__global__ void k_fill_idx(const int* __restrict__ row, int* __restrict__ woff,
                           int* __restrict__ cidx, int M) {
    int m = blockIdx.x * blockDim.x + threadIdx.x;
    if (m >= M) return;
    int p = atomicAdd(&woff[row[m]], 1);
    cidx[p] = m;
}

__global__ void k_inv_int(const int* __restrict__ deg, float* __restrict__ rscale) {
    int r = blockIdx.x * blockDim.x + threadIdx.x;
    if (r >= Nn) return;
    rscale[r] = 1.f / fmaxf((float)deg[r], 1.f);
}

__global__ void k_ebank(const float* __restrict__ bemb, float* __restrict__ ebank) {
    int idx = blockIdx.x * blockDim.x + threadIdx.x;
    if (idx >= 512 * H) return;
    int code = idx >> 7, h = idx & 127;
    int f0 = code >> 6, f1 = (code >> 3) & 7, f2 = code & 7;
    ebank[idx] = bemb[(0 * BV + f0) * H + h] + bemb[(1 * BV + f1) * H + h]
               + bemb[(2 * BV + f2) * H + h];
}

// ---------------- GINE aggregation v2: 16 threads/atom, v8bf, unroll-2 ----------

__global__ __launch_bounds__(256) void k_agg_csr(
    const __bf16* __restrict__ x, const int* __restrict__ rowptr,
    const unsigned int* __restrict__ elist, const float* __restrict__ ebank,
    const float* __restrict__ eps, int layer, __bf16* __restrict__ agg)
{
    int t = threadIdx.x;
    int a = blockIdx.x * 16 + (t >> 4);
    if (a >= Nn) return;
    int h0 = (t & 15) * 8;

    float acc[8];
    {
        v8bf xs = *(const v8bf*)&x[(size_t)a * H + h0];
        float e = 1.f + eps[layer];
#pragma unroll
        for (int i = 0; i < 8; ++i) acc[i] = e * (float)xs[i];
    }
    int j0 = rowptr[a], j1 = rowptr[a + 1];
    int j = j0;
    for (; j + 1 < j1; j += 2) {
        unsigned u0 = elist[j], u1 = elist[j + 1];
        int s0 = u0 & 0x1FFFF, c0 = u0 >> 17;
        int s1 = u1 & 0x1FFFF, c1 = u1 >> 17;
        v8bf x0 = *(const v8bf*)&x[(size_t)s0 * H + h0];
        v8bf x1 = *(const v8bf*)&x[(size_t)s1 * H + h0];
        v4f e0a = *(const v4f*)&ebank[c0 * H + h0];
        v4f e0b = *(const v4f*)&ebank[c0 * H + h0 + 4];
        v4f e1a = *(const v4f*)&ebank[c1 * H + h0];
        v4f e1b = *(const v4f*)&ebank[c1 * H + h0 + 4];
#pragma unroll
        for (int i = 0; i < 4; ++i) {
            acc[i]     += fmaxf((float)x0[i]     + e0a[i], 0.f)
                        + fmaxf((float)x1[i]     + e1a[i], 0.f);
            acc[i + 4] += fmaxf((float)x0[i + 4] + e0b[i], 0.f)
                        + fmaxf((float)x1[i + 4] + e1b[i], 0.f);
        }
    }
    if (j < j1) {
        unsigned u = elist[j];
        int s = u & 0x1FFFF, c = u >> 17;
        v8bf xr = *(const v8bf*)&x[(size_t)s * H + h0];
        v4f ea = *(const v4f*)&ebank[c * H + h0];
        v4f eb = *(const v4f*)&ebank[c * H + h0 + 4];
#pragma unroll
        for (int i = 0; i < 4; ++i) {
            acc[i]     += fmaxf((float)xr[i]     + ea[i], 0.f);
            acc[i + 4] += fmaxf((float)xr[i + 4] + eb[i], 0.f);
        }
    }
    v8bf o;
#pragma unroll
    for (int i = 0; i < 8; ++i) o[i] = (__bf16)acc[i];
    *(v8bf*)&agg[(size_t)a * H + h0] = o;
}

// ---------------- cross-block stats reduction ----------------

__global__ __launch_bounds__(256) void k_red(const float* __restrict__ part,
                                             float* __restrict__ out,
                                             int width, int nb)
{
    __shared__ float s[256];
    int t = threadIdx.x;
    int col = blockIdx.x * 64 + (t & 63);
    int pl = t >> 6;
    float acc = 0.f;
    for (int p = blockIdx.y * 4 + pl; p < nb; p += 32)
        acc += part[(size_t)p * width + col];
    s[t] = acc;
    __syncthreads();
    if (pl == 0) {
        float v = s[t] + s[t + 64] + s[t + 128] + s[t + 192];
        atomicAdd(&out[col], v);
    }
}

// ---------------- K=128 GEMM v3: B in regs once, GRID-STRIDE over 64-row tiles ----

template <int BNMODE, bool GRP>
__global__ __launch_bounds__(256) void k_gemm128(
    const __bf16* __restrict__ A, const __bf16* __restrict__ Bth,
    const float* __restrict__ bias, const __bf16* __restrict__ res,
    __bf16* __restrict__ out, const int* __restrict__ rowidx,
    const int* __restrict__ grp, const int* __restrict__ gcol,
    const float* __restrict__ gscale,
    const float* __restrict__ bnstats, const float* __restrict__ bng,
    const float* __restrict__ bnb, int M, int ntiles)
{
    __shared__ __bf16 Ct[64 * 136];
    __shared__ float scB[128], shB[128];

    int t = threadIdx.x;
    int lane = t & 63, q = lane >> 4, lr = lane & 15;
    int w = t >> 6;

    if (BNMODE && t < 128) {
        float mean = bnstats[t] * (1.f / (float)Nn);
        float var = bnstats[128 + t] * (1.f / (float)Nn) - mean * mean;
        float s = bng[t] * rsqrtf(var + BN_EPS);
        scB[t] = s;
        shB[t] = bnb[t] - mean * s;
    }
    if (BNMODE) __syncthreads();

    v8bf bf[8][4];
#pragma unroll
    for (int nt = 0; nt < 8; ++nt) {
        const __bf16* bp = Bth + (size_t)(nt * 16 + lr) * 128 + q * 8;
#pragma unroll
        for (int kt = 0; kt < 4; ++kt)
            bf[nt][kt] = *(const v8bf*)(bp + kt * 32);
    }
    float bcol[8];
#pragma unroll
    for (int nt = 0; nt < 8; ++nt) bcol[nt] = bias[nt * 16 + lr];

    for (int tile = blockIdx.x; tile < ntiles; tile += gridDim.x) {
        int m0 = tile * 64;
        int gm = m0 + w * 16 + lr;
        bool rvalid = (gm < M);

        v8bf af[4];
        if (GRP) {
            float a8[4][8];
#pragma unroll
            for (int kt = 0; kt < 4; ++kt)
#pragma unroll
                for (int i = 0; i < 8; ++i) a8[kt][i] = 0.f;
            float sc = 1.f;
            if (rvalid) {
                int j0 = grp[gm], j1 = grp[gm + 1];
                sc = gscale[gm];
                for (int j = j0; j < j1; ++j) {
                    const __bf16* rp2 = A + (size_t)gcol[j] * H;
#pragma unroll
                    for (int kt = 0; kt < 4; ++kt) {
                        v8bf g = *(const v8bf*)(rp2 + kt * 32 + q * 8);
#pragma unroll
                        for (int i = 0; i < 8; ++i) a8[kt][i] += (float)g[i];
                    }
                }
            }
#pragma unroll
            for (int kt = 0; kt < 4; ++kt)
#pragma unroll
                for (int i = 0; i < 8; ++i) af[kt][i] = (__bf16)(a8[kt][i] * sc);
        } else {
            const __bf16* base = A;
            if (rvalid) base = rowidx ? A + (size_t)rowidx[gm] * H : A + (size_t)gm * H;
#pragma unroll
            for (int kt = 0; kt < 4; ++kt) {
                v8bf hv = {};
                if (rvalid) hv = *(const v8bf*)(base + kt * 32 + q * 8);
                af[kt] = hv;
            }
        }
        if (BNMODE == 1) {
            if (rvalid) {
#pragma unroll
                for (int kt = 0; kt < 4; ++kt) {
                    int kb = kt * 32 + q * 8;
#pragma unroll
                    for (int i = 0; i < 8; ++i)
                        af[kt][i] =
                            (__bf16)fmaxf((float)af[kt][i] * scB[kb + i] + shB[kb + i], 0.f);
                }
            }
        }

        v4f acc[8] = {};
#pragma unroll
        for (int kt = 0; kt < 4; ++kt)
#pragma unroll
            for (int nt = 0; nt < 8; ++nt)
                acc[nt] = __builtin_amdgcn_mfma_f32_16x16x32_bf16(
                    af[kt], bf[nt][kt], acc[nt], 0, 0, 0);

#pragma unroll
        for (int nt = 0; nt < 8; ++nt)
#pragma unroll
            for (int reg = 0; reg < 4; ++reg) {
                int row = w * 16 + q * 4 + reg;
                float v = fmaxf(acc[nt][reg] + bcol[nt], 0.f);
                Ct[row * 136 + nt * 16 + lr] = (__bf16)v;
            }
        {
            int row = t >> 2;
            int c0 = (t & 3) * 32;
            int rm = m0 + row;
            if (rm < M) {
#pragma unroll
                for (int seg = 0; seg < 4; ++seg) {
                    int cc = c0 + seg * 8;
                    v8bf cv = *(v8bf*)&Ct[row * 136 + cc];
                    v8bf rv2 = *(const v8bf*)&res[(size_t)rm * H + cc];
#pragma unroll
                    for (int i = 0; i < 8; ++i) {
                        float rf = (float)rv2[i];
                        if (BNMODE == 2)
                            rf = fmaxf(rf * scB[cc + i] + shB[cc + i], 0.f);
                        cv[i] = (__bf16)((float)cv[i] + rf);
                    }
                    *(v8bf*)&out[(size_t)rm * H + cc] = cv;
                }
            }
        }
    }
}

// ---------------- cyclic path block v3: LDS-resident weights ----------------

template <int PK>
__global__ __launch_bounds__(512, 1) void k_path(
    const __bf16* __restrict__ X, const __bf16* __restrict__ Bth,
    const float* __restrict__ bias, __bf16* __restrict__ Xout,
    int M, int nchunks)
{
    __shared__ __bf16 Bs[128][392];   // 100.4 KB (pad 8 cols: 4-bank row shift)
    __shared__ __bf16 Ct[128 * 136];  // 34.8 KB
    int t = threadIdx.x;
    int lane = t & 63, q = lane >> 4, lr = lane & 15;
    int w = t >> 6;        // 0..7
    int mt = w >> 2;       // 0 or 1
    int wm = w & 3;        // wave within mt half

    // stage B: thread t stages row t>>2, col-quarter (t&3)*96 (12 v8bf)
    {
        int r = t >> 2, c0 = (t & 3) * 96;
        const __bf16* src = Bth + (size_t)r * 384 + c0;
#pragma unroll
        for (int j = 0; j < 12; ++j)
            *(v8bf*)&Bs[r][c0 + j * 8] = *(const v8bf*)(src + j * 8);
    }
    float bcol[8];
#pragma unroll
    for (int nt = 0; nt < 8; ++nt) bcol[nt] = bias[nt * 16 + lr];
    __syncthreads();  // Bs ready

    for (int ch = blockIdx.x; ch < nchunks; ch += gridDim.x) {
        int tb = ch * 120;
        int rloc = wm * 16 + lr;
        int gm = tb + mt * 60 + rloc;
        bool rv = (rloc < 60) && (gm < M);
        v4f acc[8] = {};
#pragma unroll
        for (int p = 0; p < 3; ++p) {
            v8bf af[4];
#pragma unroll
            for (int kt = 0; kt < 4; ++kt) af[kt] = v8bf{};
            if (rv) {
                int pm = gm % PK;
                int pp = pm + p - 1;
                if (pp < 0) pp += PK;
                if (pp >= PK) pp -= PK;
                const __bf16* ap = X + (size_t)(gm - pm + pp) * H + q * 8;
#pragma unroll
                for (int kt = 0; kt < 4; ++kt)
                    af[kt] = *(const v8bf*)(ap + kt * 32);
            }
#pragma unroll
            for (int nt = 0; nt < 8; ++nt)
#pragma unroll
                for (int kt = 0; kt < 4; ++kt) {
                    v8bf bh = *(v8bf*)&Bs[nt * 16 + lr][p * 128 + kt * 32 + q * 8];
                    acc[nt] = __builtin_amdgcn_mfma_f32_16x16x32_bf16(
                        af[kt], bh, acc[nt], 0, 0, 0);
                }
        }
        // all rolled A reads (which cross wave row-boundaries) must complete
        // before the in-place residual+write below
        __syncthreads();
#pragma unroll
        for (int nt = 0; nt < 8; ++nt)
#pragma unroll
            for (int reg = 0; reg < 4; ++reg) {
                int row = w * 16 + q * 4 + reg;   // 0..127, wave-local
                float v = fmaxf(acc[nt][reg] + bcol[nt], 0.f);
                Ct[row * 136 + nt * 16 + lr] = (__bf16)v;
            }
        {
            int row = t >> 2;                    // 0..127, same wave's rows
            int c0 = (t & 3) * 32;
            int rmloc = row & 63;
            int rm = tb + (row >> 6) * 60 + rmloc;
            if (rmloc < 60 && rm < M) {
#pragma unroll
                for (int seg = 0; seg < 4; ++seg) {
                    int cc = c0 + seg * 8;
                    v8bf cv = *(v8bf*)&Ct[row * 136 + cc];
                    v8bf rv2 = *(const v8bf*)&X[(size_t)rm * H + cc];
#pragma unroll
                    for (int i = 0; i < 8; ++i)
                        cv[i] = (__bf16)((float)cv[i] + (float)rv2[i]);
                    *(v8bf*)&Xout[(size_t)rm * H + cc] = cv;
                }
            }
        }
    }
}

// ---------------- MLP pass A: BN1 column stats only ----------------

__global__ __launch_bounds__(256) void k_mlp_statsA(
    const __bf16* __restrict__ agg, const __bf16* __restrict__ g1h,
    const float* __restrict__ gb1, float* __restrict__ spart, int M)
{
    __shared__ float sS[128], sQ[128];
    int t = threadIdx.x;
    int mc = blockIdx.x >> 1, p = blockIdx.x & 1;
    int lane = t & 63, q = lane >> 4, lr = lane & 15;
    int w = t >> 6;
    if (t < 128) { sS[t] = 0.f; sQ[t] = 0.f; }

    v8bf bf[8][4];
#pragma unroll
    for (int nt = 0; nt < 8; ++nt) {
        const __bf16* bp = g1h + (size_t)(p * 128 + nt * 16 + lr) * 128 + q * 8;
#pragma unroll
        for (int kt = 0; kt < 4; ++kt)
            bf[nt][kt] = *(const v8bf*)(bp + kt * 32);
    }
    float bv[8];
#pragma unroll
    for (int nt = 0; nt < 8; ++nt) bv[nt] = gb1[p * 128 + nt * 16 + lr];

    float sAcc[8], qAcc[8];
#pragma unroll
    for (int nt = 0; nt < 8; ++nt) { sAcc[nt] = 0.f; qAcc[nt] = 0.f; }

#pragma unroll
    for (int mt = 0; mt < 4; ++mt) {
        int rb = mc * 256 + mt * 64 + w * 16;
        int gm = rb + lr;
        bool rv = (gm < M);
        v8bf af[4];
#pragma unroll
        for (int kt = 0; kt < 4; ++kt) {
            v8bf hv = {};
            if (rv) hv = *(const v8bf*)(agg + (size_t)gm * H + kt * 32 + q * 8);
            af[kt] = hv;
        }
        v4f acc[8] = {};
#pragma unroll
        for (int kt = 0; kt < 4; ++kt)
#pragma unroll
            for (int nt = 0; nt < 8; ++nt)
                acc[nt] = __builtin_amdgcn_mfma_f32_16x16x32_bf16(
                    af[kt], bf[nt][kt], acc[nt], 0, 0, 0);
#pragma unroll
        for (int nt = 0; nt < 8; ++nt) {
            float s = 0.f, q2 = 0.f;
#pragma unroll
            for (int reg = 0; reg < 4; ++reg) {
                int rm = rb + q * 4 + reg;
                if (rm < M) {
                    float v = acc[nt][reg] + bv[nt];
                    s += v;
                    q2 += v * v;
                }
            }
            sAcc[nt] += s;
            qAcc[nt] += q2;
        }
    }
#pragma unroll
    for (int nt = 0; nt < 8; ++nt) {
        sAcc[nt] += __shfl_xor(sAcc[nt], 16, 64);
        sAcc[nt] += __shfl_xor(sAcc[nt], 32, 64);
        qAcc[nt] += __shfl_xor(qAcc[nt], 16, 64);
        qAcc[nt] += __shfl_xor(qAcc[nt], 32, 64);
    }
    __syncthreads();
    if (q == 0) {
#pragma unroll
        for (int nt = 0; nt < 8; ++nt) {
            atomicAdd(&sS[nt * 16 + lr], sAcc[nt]);
            atomicAdd(&sQ[nt * 16 + lr], qAcc[nt]);
        }
    }
    __syncthreads();
    if (t < 128) {
        spart[(size_t)mc * 512 + p * 128 + t] = sS[t];
        spart[(size_t)mc * 512 + 256 + p * 128 + t] = sQ[t];
    }
}

// ---------------- MLP fused pass B v4: LDS weights + DOUBLE-TILE ILP ------------
// v3 was 1 wave/SIMD (157.7KB LDS, occupancy 8.6%) and latency-bound (MfmaUtil
// 10%). v4: each grid-stride iteration processes TWO 64-row tiles; every LDS
// B-read (bh) feeds BOTH tiles' MFMAs -> halves ds_read traffic and gives
// 16 independent MFMA chains so the single wave hides its own latency.
// Tt is time-shared A-then-B (wave-local write->read, program order). VGPR ~240.

__global__ __launch_bounds__(256, 1) void k_mlp_fused(
    const __bf16* __restrict__ agg, const __bf16* __restrict__ g1h,
    const float* __restrict__ gb1, const float* __restrict__ statsIn,
    const float* __restrict__ gbn_g, const float* __restrict__ gbn_b,
    const __bf16* __restrict__ g2h, const float* __restrict__ gb2,
    __bf16* __restrict__ outx, float* __restrict__ spart2, int M, int ntiles)
{
    __shared__ __bf16 B1s[256][136];   // 69.6 KB
    __shared__ __bf16 B2s[128][264];   // 67.6 KB
    __shared__ __bf16 Tt[64 * 136];    // 17.4 KB (h1 panel / C transpose)
    __shared__ float scS[256], shS[256];
    __shared__ float sS[128], sQ[128];

    int t = threadIdx.x;
    int lane = t & 63, q = lane >> 4, lr = lane & 15;
    int w = t >> 6;

    {
        float mean = statsIn[t] * (1.f / (float)Nn);
        float var = statsIn[256 + t] * (1.f / (float)Nn) - mean * mean;
        float s = gbn_g[t] * rsqrtf(var + BN_EPS);
        scS[t] = s;
        shS[t] = (gb1[t] - mean) * s + gbn_b[t];
    }
    if (t < 128) { sS[t] = 0.f; sQ[t] = 0.f; }

    {
        const __bf16* src = g1h + (size_t)t * 128;
#pragma unroll
        for (int j = 0; j < 16; ++j)
            *(v8bf*)&B1s[t][j * 8] = *(const v8bf*)(src + j * 8);
    }
    {
        int r = t >> 1, h0 = (t & 1) * 128;
        const __bf16* src = g2h + (size_t)r * 256 + h0;
#pragma unroll
        for (int j = 0; j < 16; ++j)
            *(v8bf*)&B2s[r][h0 + j * 8] = *(const v8bf*)(src + j * 8);
    }
    __syncthreads();  // B1s/B2s/scS/shS/sS/sQ ready

    float bc2[8];
#pragma unroll
    for (int nt = 0; nt < 8; ++nt) bc2[nt] = gb2[nt * 16 + lr];

    float sAcc[8], qAcc[8];
#pragma unroll
    for (int nt = 0; nt < 8; ++nt) { sAcc[nt] = 0.f; qAcc[nt] = 0.f; }

    for (int tile = blockIdx.x * 2; tile < ntiles; tile += gridDim.x * 2) {
        int m0a = tile * 64;
        int m0b = m0a + 64;
        int gma = m0a + w * 16 + lr;
        int gmb = m0b + w * 16 + lr;
        bool rva = (gma < M);
        bool rvb = (tile + 1 < ntiles) && (gmb < M);
        v8bf afA[4], afB[4];
#pragma unroll
        for (int kt = 0; kt < 4; ++kt) {
            v8bf ha = {}, hb = {};
            if (rva) ha = *(const v8bf*)(agg + (size_t)gma * H + kt * 32 + q * 8);
            if (rvb) hb = *(const v8bf*)(agg + (size_t)gmb * H + kt * 32 + q * 8);
            afA[kt] = ha;
            afB[kt] = hb;
        }

        v4f acc2A[8] = {}, acc2B[8] = {};
#pragma unroll
        for (int p = 0; p < 2; ++p) {
            // ---- stage 1, both tiles share each B1 read ----
            v4f acc1A[8] = {}, acc1B[8] = {};
#pragma unroll
            for (int kt = 0; kt < 4; ++kt)
#pragma unroll
                for (int nt = 0; nt < 8; ++nt) {
                    v8bf bh = *(v8bf*)&B1s[p * 128 + nt * 16 + lr][kt * 32 + q * 8];
                    acc1A[nt] = __builtin_amdgcn_mfma_f32_16x16x32_bf16(
                        afA[kt], bh, acc1A[nt], 0, 0, 0);
                    acc1B[nt] = __builtin_amdgcn_mfma_f32_16x16x32_bf16(
                        afB[kt], bh, acc1B[nt], 0, 0, 0);
                }
            // BN1+relu -> Tt (tile A), read a2A (wave-local program order)
            v8bf a2A[4], a2B[4];
#pragma unroll
            for (int nt = 0; nt < 8; ++nt)
#pragma unroll
                for (int reg = 0; reg < 4; ++reg) {
                    int row = w * 16 + q * 4 + reg;
                    int col = p * 128 + nt * 16 + lr;
                    float v = fmaxf(acc1A[nt][reg] * scS[col] + shS[col], 0.f);
                    Tt[row * 136 + nt * 16 + lr] = (__bf16)v;
                }
#pragma unroll
            for (int kt = 0; kt < 4; ++kt)
                a2A[kt] = *(v8bf*)&Tt[(w * 16 + lr) * 136 + kt * 32 + q * 8];
            // BN1+relu -> Tt (tile B, overwrite), read a2B
#pragma unroll
            for (int nt = 0; nt < 8; ++nt)
#pragma unroll
                for (int reg = 0; reg < 4; ++reg) {
                    int row = w * 16 + q * 4 + reg;
                    int col = p * 128 + nt * 16 + lr;
                    float v = fmaxf(acc1B[nt][reg] * scS[col] + shS[col], 0.f);
                    Tt[row * 136 + nt * 16 + lr] = (__bf16)v;
                }
#pragma unroll
            for (int kt = 0; kt < 4; ++kt)
                a2B[kt] = *(v8bf*)&Tt[(w * 16 + lr) * 136 + kt * 32 + q * 8];
            // ---- stage 2, both tiles share each B2 read ----
#pragma unroll
            for (int kt = 0; kt < 4; ++kt)
#pragma unroll
                for (int nt = 0; nt < 8; ++nt) {
                    v8bf bh = *(v8bf*)&B2s[nt * 16 + lr][p * 128 + kt * 32 + q * 8];
                    acc2A[nt] = __builtin_amdgcn_mfma_f32_16x16x32_bf16(
                        a2A[kt], bh, acc2A[nt], 0, 0, 0);
                    acc2B[nt] = __builtin_amdgcn_mfma_f32_16x16x32_bf16(
                        a2B[kt], bh, acc2B[nt], 0, 0, 0);
                }
        }

        // ---- stats + output, tile A then tile B (Tt time-shared) ----
#pragma unroll
        for (int nt = 0; nt < 8; ++nt) {
#pragma unroll
            for (int reg = 0; reg < 4; ++reg) {
                int rma = m0a + w * 16 + q * 4 + reg;
                if (rma < M) {
                    float v = acc2A[nt][reg] + bc2[nt];
                    sAcc[nt] += v;
                    qAcc[nt] += v * v;
                }
                int rmb = m0b + w * 16 + q * 4 + reg;
                if (rvb && rmb < M) {
                    float v = acc2B[nt][reg] + bc2[nt];
                    sAcc[nt] += v;
                    qAcc[nt] += v * v;
                }
            }
        }
#pragma unroll
        for (int nt = 0; nt < 8; ++nt)
#pragma unroll
            for (int reg = 0; reg < 4; ++reg) {
                int row = w * 16 + q * 4 + reg;
                Tt[row * 136 + nt * 16 + lr] = (__bf16)(acc2A[nt][reg] + bc2[nt]);
            }
        {
            int row = t >> 2;
            int c0 = (t & 3) * 32;
            int rm = m0a + row;
            if (rm < M) {
#pragma unroll
                for (int seg = 0; seg < 4; ++seg) {
                    int cc = c0 + seg * 8;
                    *(v8bf*)&outx[(size_t)rm * H + cc] = *(v8bf*)&Tt[row * 136 + cc];
                }
            }
        }
        if (tile + 1 < ntiles) {
#pragma unroll
            for (int nt = 0; nt < 8; ++nt)
#pragma unroll
                for (int reg = 0; reg < 4; ++reg) {
                    int row = w * 16 + q * 4 + reg;
                    Tt[row * 136 + nt * 16 + lr] = (__bf16)(acc2B[nt][reg] + bc2[nt]);
                }
            int row = t >> 2;
            int c0 = (t & 3) * 32;
            int rm = m0b + row;
            if (rm < M) {
#pragma unroll
                for (int seg = 0; seg < 4; ++seg) {
                    int cc = c0 + seg * 8;
                    *(v8bf*)&outx[(size_t)rm * H + cc] = *(v8bf*)&Tt[row * 136 + cc];
                }
            }
        }
    }

#pragma unroll
    for (int nt = 0; nt < 8; ++nt) {
        sAcc[nt] += __shfl_xor(sAcc[nt], 16, 64);
        sAcc[nt] += __shfl_xor(sAcc[nt], 32, 64);
        qAcc[nt] += __shfl_xor(qAcc[nt], 16, 64);
        qAcc[nt] += __shfl_xor(qAcc[nt], 32, 64);
    }
    if (q == 0) {
#pragma unroll
        for (int nt = 0; nt < 8; ++nt) {
            atomicAdd(&sS[nt * 16 + lr], sAcc[nt]);
            atomicAdd(&sQ[nt * 16 + lr], qAcc[nt]);
        }
    }
    __syncthreads();
    {
        float pv = (t < 128) ? sS[t] : sQ[t - 128];
        spart2[(size_t)blockIdx.x * 256 + t] = pv;
    }
}

// ---------------- readout (segmented-parallel) ----------------

__global__ void k_gbound(const int* __restrict__ batch, int* __restrict__ gstart) {
    int r = blockIdx.x * blockDim.x + threadIdx.x;
    if (r >= Nn) return;
    int b = batch[r];
    int prev = (r == 0) ? -1 : batch[r - 1];
    for (int g = prev + 1; g <= b; ++g) gstart[g] = r;
    if (r == Nn - 1) {
        for (int g = b + 1; g <= Gg; ++g) gstart[g] = Nn;
    }
}

__global__ __launch_bounds__(256) void k_seg_sum(
    const __bf16* __restrict__ x, const int* __restrict__ gstart,
    float* __restrict__ xgsum, float* __restrict__ gcnt)
{
    __shared__ float s[16][128];
    int g = blockIdx.x;
    int t = threadIdx.x;
    int rp = t >> 4;            // 16 row-lanes
    int h0 = (t & 15) * 8;      // 16 col-groups of 8
    int r0 = gstart[g], r1 = gstart[g + 1];
    float acc[8];
#pragma unroll
    for (int i = 0; i < 8; ++i) acc[i] = 0.f;
    for (int r = r0 + rp; r < r1; r += 16) {
        v8bf v = *(const v8bf*)&x[(size_t)r * H + h0];
#pragma unroll
        for (int i = 0; i < 8; ++i) acc[i] += (float)v[i];
    }
#pragma unroll
    for (int i = 0; i < 8; ++i) s[rp][h0 + i] = acc[i];
    __syncthreads();
    if (rp == 0) {
#pragma unroll
        for (int i = 0; i < 8; ++i) {
            float v = 0.f;
#pragma unroll
            for (int j = 0; j < 16; ++j) v += s[j][h0 + i];
            xgsum[(size_t)g * H + h0 + i] = v;
        }
    }
    if (t == 0) gcnt[g] = (float)(r1 - r0);
}

__global__ void k_head(const float* __restrict__ xgsum, const float* __restrict__ gcnt,
                       const float* __restrict__ alw, const float* __restrict__ alb,
                       const float* __restrict__ lw, const float* __restrict__ lb,
                       float* __restrict__ out) {
    __shared__ float mean[H];
    __shared__ float red[H];
    int g = blockIdx.x, j = threadIdx.x;
    mean[j] = xgsum[g * H + j] / fmaxf(gcnt[g], 1.f);
    __syncthreads();
    float acc = alb[j];
    for (int k = 0; k < H; ++k) acc += mean[k] * alw[k * H + j];
    acc = fmaxf(acc, 0.f) * lw[j];
    red[j] = acc;
    __syncthreads();
    for (int s = 64; s > 0; s >>= 1) {
        if (j < s) red[j] += red[j + s];
        __syncthreads();
    }
    if (j == 0) out[g] = red[0] + lb[0];
}

// ---------------- host ----------------

extern "C" void kernel_launch(void* const* d_in, const int* in_sizes, int n_in,
                              void* d_out, int out_size, void* d_ws, size_t ws_size,
                              hipStream_t stream) {
    const int* x_atom = (const int*)d_in[0];
    const int* ei = (const int*)d_in[1];
    const int* eattr = (const int*)d_in[2];
    const int* batch = (const int*)d_in[3];
    const int* xc5 = (const int*)d_in[4];
    const int* xc6 = (const int*)d_in[5];
    const int* a2c5_row = (const int*)d_in[6];
    const int* a2c6_row = (const int*)d_in[8];
    const float* atom_emb = (const float*)d_in[10];
    const float* bond_emb = (const float*)d_in[11];
    const float* cyc5 = (const float*)d_in[12];
    const float* cyc6 = (const float*)d_in[13];
    const float* eps = (const float*)d_in[14];
    const float* gw1 = (const float*)d_in[15];
    const float* gb1 = (const float*)d_in[16];
    const float* gbn_g = (const float*)d_in[17];
    const float* gbn_b = (const float*)d_in[18];
    const float* gw2 = (const float*)d_in[19];
    const float* gb2 = (const float*)d_in[20];
    const float* bn_g = (const float*)d_in[21];
    const float* bn_b = (const float*)d_in[22];
    const float* a2c5_w = (const float*)d_in[23];
    const float* a2c5_b = (const float*)d_in[24];
    const float* a2c6_w = (const float*)d_in[25];
    const float* a2c6_b = (const float*)d_in[26];
    const float* c2a5_w = (const float*)d_in[27];
    const float* c2a5_b = (const float*)d_in[28];
    const float* c2a6_w = (const float*)d_in[29];
    const float* c2a6_b = (const float*)d_in[30];
    const float* p5_w = (const float*)d_in[31];
    const float* p5_b = (const float*)d_in[32];
    const float* p6_w = (const float*)d_in[33];
    const float* p6_b = (const float*)d_in[34];
    const float* alw = (const float*)d_in[35];
    const float* alb = (const float*)d_in[36];
    const float* lw = (const float*)d_in[37];
    const float* lb = (const float*)d_in[38];
    float* out = (float*)d_out;

    float* w = (float*)d_ws;
    size_t o = 0;
    auto alloc = [&](size_t nf) {
        float* p = w + o;
        o += (nf + 63) & ~(size_t)63;
        return p;
    };
    auto allocb = [&](size_t nbf) { return (__bf16*)alloc((nbf + 1) / 2); };
    const int TPB = 256;
    auto cdiv = [](int a, int b) { return (a + b - 1) / b; };
    int nblkA = cdiv(Nn, 64);
    int mchunks = cdiv(Nn, 256);

    __bf16* x = allocb((size_t)Nn * H);
    __bf16* x5 = allocb((size_t)N5c * 5 * H);
    __bf16* x6 = allocb((size_t)N6c * 6 * H);
    __bf16* agg = allocb((size_t)Nn * H);
    float* stats = alloc(512);
    float* stats2 = alloc(256);
    float* spart = alloc((size_t)nblkA * 512);
    float* xgsum = alloc((size_t)Gg * H);
    float* gcnt = alloc(Gg);
    float* rscale5 = alloc(Nn);
    float* rscale6 = alloc(Nn);
    int* deg = (int*)alloc(Nn);
    int* rowptr = (int*)alloc(Nn + 1);
    int* rp5c = (int*)alloc(Nn + 1);
    int* rp6c = (int*)alloc(Nn + 1);
    int* gstart = (int*)alloc(Gg + 1);
    int* woff = (int*)alloc(Nn);
    int* bsum = (int*)alloc(256);
    int* boff = (int*)alloc(256);
    unsigned int* elist = (unsigned int*)alloc(Ee);
    int* cidx5 = (int*)alloc(N5c * 5);
    int* cidx6 = (int*)alloc(N6c * 6);
    float* ebank = alloc(512 * H);
    __bf16* g1h = allocb(3 * 128 * 256);
    __bf16* g2h = allocb(3 * 256 * 128);
    __bf16* a5h = allocb(3 * 128 * 128);
    __bf16* a6h = allocb(3 * 128 * 128);
    __bf16* c5h = allocb(3 * 128 * 128);
    __bf16* c6h = allocb(3 * 128 * 128);
    __bf16* p5h = allocb(3 * 384 * 128);
    __bf16* p6h = allocb(3 * 384 * 128);

    int nsb = cdiv(Nn, 1024);

    // weight pre-split (transposed bf16 planes)
    k_split<<<cdiv(3 * 128 * 256, TPB), TPB, 0, stream>>>(gw1, g1h, 3, 128, 256);
    k_split<<<cdiv(3 * 256 * 128, TPB), TPB, 0, stream>>>(gw2, g2h, 3, 256, 128);
    k_split<<<cdiv(3 * 128 * 128, TPB), TPB, 0, stream>>>(a2c5_w, a5h, 3, 128, 128);
    k_split<<<cdiv(3 * 128 * 128, TPB), TPB, 0, stream>>>(a2c6_w, a6h, 3, 128, 128);
    k_split<<<cdiv(3 * 128 * 128, TPB), TPB, 0, stream>>>(c2a5_w, c5h, 3, 128, 128);
    k_split<<<cdiv(3 * 128 * 128, TPB), TPB, 0, stream>>>(c2a6_w, c6h, 3, 128, 128);
    k_split<<<cdiv(3 * 384 * 128, TPB), TPB, 0, stream>>>(p5_w, p5h, 3, 384, 128);
    k_split<<<cdiv(3 * 384 * 128, TPB), TPB, 0, stream>>>(p6_w, p6h, 3, 384, 128);

    // edge CSR
    hipMemsetAsync(deg, 0, Nn * 4, stream);
    k_degi<<<cdiv(Ee, TPB), TPB, 0, stream>>>(ei + Ee, deg, Ee);
    k_scan1<<<nsb, 256, 0, stream>>>(deg, rowptr, bsum, Nn);
    k_scan2<<<1, 128, 0, stream>>>(bsum, boff, rowptr, nsb, Nn);
    k_scan3<<<cdiv(Nn, TPB), TPB, 0, stream>>>(rowptr, boff, Nn);
    hipMemcpyAsync(woff, rowptr, Nn * 4, hipMemcpyDeviceToDevice, stream);
    k_fill<<<cdiv(Ee, TPB), TPB, 0, stream>>>(ei, eattr, woff, elist);

    // cycle->atom CSRs + mean scales
    hipMemsetAsync(deg, 0, Nn * 4, stream);
    k_degi<<<cdiv(N5c * 5, TPB), TPB, 0, stream>>>(a2c5_row, deg, N5c * 5);
    k_scan1<<<nsb, 256, 0, stream>>>(deg, rp5c, bsum, Nn);
    k_scan2<<<1, 128, 0, stream>>>(bsum, boff, rp5c, nsb, Nn);
    k_scan3<<<cdiv(Nn, TPB), TPB, 0, stream>>>(rp5c, boff, Nn);
    k_inv_int<<<cdiv(Nn, TPB), TPB, 0, stream>>>(deg, rscale5);
    hipMemcpyAsync(woff, rp5c, Nn * 4, hipMemcpyDeviceToDevice, stream);
    k_fill_idx<<<cdiv(N5c * 5, TPB), TPB, 0, stream>>>(a2c5_row, woff, cidx5, N5c * 5);

    hipMemsetAsync(deg, 0, Nn * 4, stream);
    k_degi<<<cdiv(N6c * 6, TPB), TPB, 0, stream>>>(a2c6_row, deg, N6c * 6);
    k_scan1<<<nsb, 256, 0, stream>>>(deg, rp6c, bsum, Nn);
    k_scan2<<<1, 128, 0, stream>>>(bsum, boff, rp6c, nsb, Nn);
    k_scan3<<<cdiv(Nn, TPB), TPB, 0, stream>>>(rp6c, boff, Nn);
    k_inv_int<<<cdiv(Nn, TPB), TPB, 0, stream>>>(deg, rscale6);
    hipMemcpyAsync(woff, rp6c, Nn * 4, hipMemcpyDeviceToDevice, stream);
    k_fill_idx<<<cdiv(N6c * 6, TPB), TPB, 0, stream>>>(a2c6_row, woff, cidx6, N6c * 6);

    // graph boundaries for readout
    k_gbound<<<cdiv(Nn, TPB), TPB, 0, stream>>>(batch, gstart);

    k_atom_enc<<<cdiv(Nn * H, TPB), TPB, 0, stream>>>(x_atom, atom_emb, x);
    k_cyc_init<<<cdiv(N5c * 5 * H, TPB), TPB, 0, stream>>>(xc5, cyc5, x5, N5c * 5);
    k_cyc_init<<<cdiv(N6c * 6 * H, TPB), TPB, 0, stream>>>(xc6, cyc6, x6, N6c * 6);

    const int GS = 512;   // grid-stride block count for gemm128
    const int GF = 256;   // 1 block/CU kernels (big-LDS)
    for (int i = 0; i < Ll; ++i) {
        // GINE aggregation v2 (16 thr/atom, v8bf, unroll-2) -> agg
        k_ebank<<<cdiv(512 * H, TPB), TPB, 0, stream>>>(
            bond_emb + (size_t)i * BF * BV * H, ebank);
        k_agg_csr<<<cdiv(Nn, 16), 256, 0, stream>>>(
            x, rowptr, elist, ebank, eps, i, agg);

        // MLP pass A: BN1 stats (barrier-free; partials -> reduce)
        hipMemsetAsync(stats, 0, 512 * 4, stream);
        k_mlp_statsA<<<mchunks * 2, 256, 0, stream>>>(
            agg, g1h + (size_t)i * 128 * 256, gb1 + (size_t)i * 256, spart, Nn);
        k_red<<<dim3(8, 8), 256, 0, stream>>>(spart, stats, 512, mchunks);

        // MLP fused pass B v4 (LDS weights + double-tile) -> x_raw + BN2 partials
        hipMemsetAsync(stats2, 0, 256 * 4, stream);
        k_mlp_fused<<<GF, 256, 0, stream>>>(
            agg, g1h + (size_t)i * 128 * 256, gb1 + (size_t)i * 256, stats,
            gbn_g + (size_t)i * 256, gbn_b + (size_t)i * 256,
            g2h + (size_t)i * 256 * 128, gb2 + (size_t)i * H, x, spart,
            Nn, nblkA);
        k_red<<<dim3(4, 8), 256, 0, stream>>>(spart, stats2, 256, GF);

        // atoms -> cycles (row-gather, BN2+relu folded on A, in-place residual)
        k_gemm128<1, false><<<GS, 256, 0, stream>>>(
            x, a5h + (size_t)i * 128 * 128, a2c5_b + (size_t)i * H,
            x5, x5, a2c5_row, nullptr, nullptr, nullptr,
            stats2, bn_g + (size_t)i * H, bn_b + (size_t)i * H,
            N5c * 5, cdiv(N5c * 5, 64));
        k_gemm128<1, false><<<GS, 256, 0, stream>>>(
            x, a6h + (size_t)i * 128 * 128, a2c6_b + (size_t)i * H,
            x6, x6, a2c6_row, nullptr, nullptr, nullptr,
            stats2, bn_g + (size_t)i * H, bn_b + (size_t)i * H,
            N6c * 6, cdiv(N6c * 6, 64));

        // cyclic path blocks v3: LDS-resident weights, 512-thread blocks
        k_path<5><<<GF, 512, 0, stream>>>(
            x5, p5h + (size_t)i * 384 * 128, p5_b + (size_t)i * H, x5,
            N5c * 5, cdiv(N5c * 5, 120));
        k_path<6><<<GF, 512, 0, stream>>>(
            x6, p6h + (size_t)i * 384 * 128, p6_b + (size_t)i * H, x6,
            N6c * 6, cdiv(N6c * 6, 120));

        // cycles -> atoms (CSR mean-gather; c2a5 folds BN2+relu on res side)
        k_gemm128<2, true><<<GS, 256, 0, stream>>>(
            x5, c5h + (size_t)i * 128 * 128, c2a5_b + (size_t)i * H,
            x, x, nullptr, rp5c, cidx5, rscale5,
            stats2, bn_g + (size_t)i * H, bn_b + (size_t)i * H,
            Nn, cdiv(Nn, 64));
        k_gemm128<0, true><<<GS, 256, 0, stream>>>(
            x6, c6h + (size_t)i * 128 * 128, c2a6_b + (size_t)i * H,
            x, x, nullptr, rp6c, cidx6, rscale6,
            nullptr, nullptr, nullptr, Nn, cdiv(Nn, 64));
    }

    // readout (segmented-parallel)
    k_seg_sum<<<Gg, 256, 0, stream>>>(x, gstart, xgsum, gcnt);
    k_head<<<Gg, H, 0, stream>>>(xgsum, gcnt, alw, alb, lw, lb, out);
}